// Round 9
// baseline (2909.437 us; speedup 1.0000x reference)
//
#include <hip/hip_runtime.h>
#include <hip/hip_bf16.h>
#include <math.h>

typedef __hip_bfloat16 bf16;
typedef __attribute__((ext_vector_type(8))) short short8;
typedef __attribute__((ext_vector_type(4))) float f32x4;

#define T_TOK 196608   // B*N = 1024*192
#define NSEQ  192
#define DMODEL 256
#define CHUNKS 4
#define CHUNKM (T_TOK/CHUNKS)   // 49152 tokens = 256 sequences

__device__ __forceinline__ float cvt(float v){ return v; }
__device__ __forceinline__ float cvt(bf16 v){ return __bfloat162float(v); }
__device__ __forceinline__ short bfbits(float f){
  bf16 h = __float2bfloat16(f); return *reinterpret_cast<short*>(&h);
}
__device__ __forceinline__ float bfu(unsigned short v){ return __uint_as_float(((unsigned)v) << 16); }

// gelu(tanh approx) == x * sigmoid(2u), u = k0(x+0.044715x^3).
// Uses HW v_exp_f32 instead of libm tanhf (~30 VALU ops -> ~8).
__device__ __forceinline__ float gelu_f(float x){
  const float k0 = 0.7978845608028654f; // sqrt(2/pi)
  float u = k0*(x + 0.044715f*x*x*x);
  return x / (1.f + __expf(-2.f*u));
}

// lgkm-only barrier: ds ops drained, global loads stay IN FLIGHT across it.
// (__syncthreads would emit s_waitcnt vmcnt(0) and kill the A-prefetch.)
__device__ __forceinline__ void barrier_lgkm(){
  asm volatile("s_waitcnt lgkmcnt(0)" ::: "memory");
  __builtin_amdgcn_s_barrier();
  asm volatile("" ::: "memory");
}

// ---- pos-embed table: PE[n][d], n<192 ------------------------------------
__global__ __launch_bounds__(256) void pe_kernel(float* __restrict__ PE){
  int n = blockIdx.x, d = threadIdx.x;
  float e = (float)(2*(d>>1)) / 256.f;
  float ang = (float)n * powf(10000.f, -e);
  PE[n*DMODEL + d] = (d & 1) ? cosf(ang) : sinf(ang);
}

// ---- weight convert+transpose into segment: dst[n*dstStride+kOff+k] ------
// optional scale[k] multiplied in (for LN-fold W' = diag(lnS) @ W)
__global__ __launch_bounds__(256) void w2b_kernel(
    const float* __restrict__ src, bf16* __restrict__ dst,
    int K, int N, int KL, int dstStride, int kOff, const float* __restrict__ scale)
{
  int idx = blockIdx.x*256 + threadIdx.x;
  if (idx >= N*KL) return;
  int n = idx / KL, k = idx - n*KL;
  float v = 0.f;
  if (k < K){
    v = src[(size_t)k*N + n];
    if (scale) v *= scale[k];
  }
  dst[(size_t)n*dstStride + kOff + k] = __float2bfloat16(v);
}

// ---- u[n] = sum_k bf16(lnS[k]*W[k,n]);  wB[n] = sum_k lnB[k]*W[k,n]+bias[n]
// ONE BLOCK PER OUTPUT n (grid=N): wave+LDS reduce over K=256.
__global__ __launch_bounds__(256) void ucalc_kernel(
    const float* __restrict__ W, const float* __restrict__ lnS,
    const float* __restrict__ lnB, const float* __restrict__ bias,
    float* __restrict__ u, float* __restrict__ wB, int K, int N)
{
  __shared__ float pu[4], pb[4];
  const int n = blockIdx.x;
  const int k = threadIdx.x;
  float su = 0.f, sb = 0.f;
  if (k < K){
    float w = W[(size_t)k*N + n];
    su = cvt(__float2bfloat16(lnS[k]*w));   // match MFMA's rounded W'
    sb = lnB[k]*w;
  }
  #pragma unroll
  for (int off = 32; off; off >>= 1){
    su += __shfl_xor(su, off, 64);
    sb += __shfl_xor(sb, off, 64);
  }
  int lane = k & 63, wv = k >> 6;
  if (lane == 0){ pu[wv] = su; pb[wv] = sb; }
  __syncthreads();
  if (k == 0){
    u[n]  = pu[0]+pu[1]+pu[2]+pu[3];
    wB[n] = pb[0]+pb[1]+pb[2]+pb[3] + bias[n];
  }
}

// ---- pts -> bf16 [T][64] zero-padded --------------------------------------
__global__ __launch_bounds__(256) void pts2b_kernel(
    const float* __restrict__ src, bf16* __restrict__ dst)
{
  int idx = blockIdx.x*256 + threadIdx.x;   // T*64
  int t = idx >> 6, k = idx & 63;
  dst[idx] = __float2bfloat16(k < 63 ? src[(size_t)t*63 + k] : 0.f);
}

// ---- views -> bf16 [1024][32] zero-padded ---------------------------------
__global__ __launch_bounds__(256) void views2b_kernel(
    const float* __restrict__ src, bf16* __restrict__ dst)
{
  int idx = blockIdx.x*256 + threadIdx.x;   // 1024*32
  int t = idx >> 5, k = idx & 31;
  dst[idx] = __float2bfloat16(k < 27 ? src[(size_t)t*27 + k] : 0.f);
}

// ---- wave-per-token: x = ln(x)*s+b + PE[n]; writes raw stats (s1=Σy,s2=Σy²)
__global__ __launch_bounds__(256) void ln_pe_kernel(
    bf16* __restrict__ X, const float* __restrict__ s, const float* __restrict__ b,
    const float* __restrict__ PE, float* __restrict__ s1o, float* __restrict__ s2o)
{
  const int lane = threadIdx.x & 63, w = threadIdx.x >> 6;
  const size_t t = (size_t)blockIdx.x * 4 + w;
  const int n = (int)(t % NSEQ);
  const int c = lane * 4;

  ushort4 u = *reinterpret_cast<const ushort4*>(X + t*DMODEL + c);
  float x0 = bfu(u.x), x1 = bfu(u.y), x2 = bfu(u.z), x3 = bfu(u.w);

  float sx = x0 + x1 + x2 + x3;
  float sq = x0*x0 + x1*x1 + x2*x2 + x3*x3;
  #pragma unroll
  for (int off = 32; off; off >>= 1){
    sx += __shfl_xor(sx, off, 64);
    sq += __shfl_xor(sq, off, 64);
  }
  float mean = sx * (1.f/256.f);
  float var  = sq * (1.f/256.f) - mean*mean;
  float rstd = rsqrtf(var + 1e-6f);

  float4 sv = *reinterpret_cast<const float4*>(s + c);
  float4 bv = *reinterpret_cast<const float4*>(b + c);
  float4 pv = *reinterpret_cast<const float4*>(PE + n*DMODEL + c);

  float y0 = (x0 - mean)*rstd*sv.x + bv.x + pv.x;
  float y1 = (x1 - mean)*rstd*sv.y + bv.y + pv.y;
  float y2 = (x2 - mean)*rstd*sv.z + bv.z + pv.z;
  float y3 = (x3 - mean)*rstd*sv.w + bv.w + pv.w;

  ushort4 o;
  o.x = (unsigned short)bfbits(y0);
  o.y = (unsigned short)bfbits(y1);
  o.z = (unsigned short)bfbits(y2);
  o.w = (unsigned short)bfbits(y3);
  *reinterpret_cast<ushort4*>(X + t*DMODEL + c) = o;

  float sy  = y0 + y1 + y2 + y3;
  float syq = y0*y0 + y1*y1 + y2*y2 + y3*y3;
  #pragma unroll
  for (int off = 32; off; off >>= 1){
    sy  += __shfl_xor(sy,  off, 64);
    syq += __shfl_xor(syq, off, 64);
  }
  if (lane == 0){ s1o[t] = sy; s2o[t] = syq; }
}

// ---- MFMA GEMM: C = A @ W, 128x128 tile, 4 waves (pipelined, deep) --------
// A: LDS double-buffer, 3-deep register prefetch (w = tile t+1 pending
//    write, q = tile t+2 in flight, tile t+3 issued each step).
// B: register ping-pong (B(k+32) issued before MFMA(k) - hides L2 latency).
// ONE lgkm-only barrier per k-step; global loads stay in flight across it.
// Cs reuses As LDS after the K-loop (2x5120 < 17408 shorts = 34.8 KB).
// MODE 0: plain bf16 A1 (rollShift supported)
// MODE 2: concat: k<SB -> A1[arow][k], else A2[arow][k-SB]    (SB%16==0)
// MODE 3: concat: k<SB -> A1[arow][k], else A2[arow/192][k-SB]
// LNF: C = rstd[m]*acc + (-mu[m]*rstd[m])*u[n] + wB[n]  (weights pre-scaled)
// C cols >=256 map to segment buffers: dst += (n0>>8)*segStride.
// STATS: per-row Σ and Σ² of final C values atomically added to s1o/s2o.
template<int MODE, bool LNF, bool ADD, bool GELU, bool STATS>
__global__ __launch_bounds__(256) void gemm_mfma(
    const bf16* __restrict__ A1, int lda1,
    const bf16* __restrict__ A2, int lda2, int SB, int aOff,
    const float* __restrict__ s1i, const float* __restrict__ s2i,
    const float* __restrict__ uvec,
    const bf16* __restrict__ WT, int Kpad, const float* __restrict__ bias,
    bf16* __restrict__ C, int ldc, size_t segStride, int cOff, int rollShift,
    float* __restrict__ s1o, float* __restrict__ s2o)
{
  __shared__ short buf[17408];    // As0|As1 (2x5120) ∪ Cs (17408) = 34816 B
  short* As0 = buf;
  short* As1 = buf + 5120;
  short* Cs  = buf;
  __shared__ float sScale[128], sAlpha[128];

  const int tid = threadIdx.x;
  const int lane = tid & 63, wid = tid >> 6;
  const int wm = wid >> 1, wn = wid & 1;
  const int col16 = lane & 15, quad = lane >> 4;
  const int sm = tid >> 1, half = tid & 1;   // staging: row, k-half
  const int m0 = blockIdx.y * 128, n0 = blockIdx.x * 128;

  f32x4 acc[4][4];
  #pragma unroll
  for (int i = 0; i < 4; i++)
    #pragma unroll
    for (int j = 0; j < 4; j++) acc[i][j] = (f32x4){0.f,0.f,0.f,0.f};

  // staging source row (rolled)
  int row = m0 + sm;
  if (MODE == 0 && rollShift){
    int bb = row / NSEQ;
    int n  = row - bb*NSEQ;
    n += rollShift; if (n >= NSEQ) n -= NSEQ;
    row = bb*NSEQ + n;
  }
  const size_t arow = (size_t)aOff + row;
  const size_t arow2 = (MODE == 3) ? (arow / NSEQ) : arow;

  // ---- LN-fold per-row scale/alpha (from rolled source row) ----
  if (LNF && tid < 128){
    int r2 = m0 + tid;
    if (rollShift){
      int bb = r2 / NSEQ, n = r2 - bb*NSEQ;
      n += rollShift; if (n >= NSEQ) n -= NSEQ;
      r2 = bb*NSEQ + n;
    }
    size_t r = (size_t)aOff + r2;
    float m1 = s1i[r] * (1.f/256.f);
    float m2 = s2i[r] * (1.f/256.f);
    float rs = rsqrtf(m2 - m1*m1 + 1e-6f);
    sScale[tid] = rs;
    sAlpha[tid] = -m1*rs;
  }

  auto loadA = [&](int k0, uint4& u0, uint4& u1){
    const int gk = k0 + half*16;
    const bf16* src;
    if (MODE == 0) src = A1 + arow*(size_t)lda1 + gk;
    else src = (gk < SB) ? (A1 + arow*(size_t)lda1 + gk)
                         : (A2 + arow2*(size_t)lda2 + (gk - SB));
    u0 = *(const uint4*)(src);
    u1 = *(const uint4*)(src + 8);
  };
  auto writeA = [&](short* dst, const uint4& u0, const uint4& u1){
    *(uint4*)&dst[sm*40 + half*16]     = u0;
    *(uint4*)&dst[sm*40 + half*16 + 8] = u1;
  };

  const short* bp[4];
  #pragma unroll
  for (int ni = 0; ni < 4; ni++)
    bp[ni] = (const short*)WT + (size_t)(n0 + wn*64 + ni*16 + col16)*Kpad + quad*8;

  auto loadB = [&](int k0, short8* bf){
    #pragma unroll
    for (int ni = 0; ni < 4; ni++) bf[ni] = *(const short8*)(bp[ni] + k0);
  };
  auto domfma = [&](const short* Asc, short8* bfr){
    short8 afr[4];
    #pragma unroll
    for (int mi = 0; mi < 4; mi++)
      afr[mi] = *(const short8*)&Asc[(wm*64 + mi*16 + col16)*40 + quad*8];
    #pragma unroll
    for (int mi = 0; mi < 4; mi++)
      #pragma unroll
      for (int ni = 0; ni < 4; ni++)
        acc[mi][ni] = __builtin_amdgcn_mfma_f32_16x16x32_bf16(
            afr[mi], bfr[ni], acc[mi][ni], 0, 0, 0);
  };

  // ---- prologue: tile0 -> As0; tiles 1,2 in regs; B(0) issued ----
  uint4 t0a, t0b, w0, w1, q0, q1;
  loadA(0, t0a, t0b);
  writeA(As0, t0a, t0b);
  if (Kpad > 32) loadA(32, w0, w1);
  if (Kpad > 64) loadA(64, q0, q1);
  short8 bA[4], bB[4];
  loadB(0, bA);
  barrier_lgkm();

  // ---- pipelined K-loop: pair-unrolled, one lgkm barrier per step ----
  for (int k0 = 0; k0 < Kpad; k0 += 64){
    // even step (tile k0 in As0, B in bA)
    if (k0 + 32 < Kpad) loadB(k0 + 32, bB);      // prefetch next B
    domfma(As0, bA);
    if (k0 + 32 < Kpad){
      writeA(As1, w0, w1);                       // tile k0+32 -> As1
      w0 = q0; w1 = q1;
      if (k0 + 96 < Kpad) loadA(k0 + 96, q0, q1);
    }
    barrier_lgkm();
    if (k0 + 32 >= Kpad) break;
    // odd step (tile k0+32 in As1, B in bB)
    if (k0 + 64 < Kpad) loadB(k0 + 64, bA);
    domfma(As1, bB);
    if (k0 + 64 < Kpad){
      writeA(As0, w0, w1);                       // tile k0+64 -> As0
      w0 = q0; w1 = q1;
      if (k0 + 128 < Kpad) loadA(k0 + 128, q0, q1);
    }
    barrier_lgkm();
  }

  // ---- epilogue phase 1: acc -> affine/bias (+gelu) -> Cs bf16 ----
  // (last barrier drained all ds reads; As region safe to reuse as Cs)
  #pragma unroll
  for (int ni = 0; ni < 4; ni++){
    int ncol = wn*64 + ni*16 + col16;
    float bv = bias[n0 + ncol];
    float uv = LNF ? uvec[n0 + ncol] : 0.f;
    #pragma unroll
    for (int mi = 0; mi < 4; mi++){
      f32x4 a = acc[mi][ni];
      #pragma unroll
      for (int r = 0; r < 4; r++){
        int lrow = wm*64 + mi*16 + quad*4 + r;
        float val;
        if (LNF) val = sScale[lrow]*a[r] + sAlpha[lrow]*uv + bv;
        else     val = a[r] + bv;
        if (GELU) val = gelu_f(val);
        Cs[lrow*136 + ncol] = bfbits(val);
      }
    }
  }
  __syncthreads();

  // ---- epilogue phase 2: coalesced 16B stores (+ADD) (+STATS) ----
  const int seg = n0 >> 8;
  const int nb  = n0 & 255;
  const int orow = tid >> 4;         // 0..15
  const int ocol = (tid & 15) * 8;   // 0..120
  #pragma unroll
  for (int p = 0; p < 8; p++){
    int lrow = p*16 + orow;
    size_t mrow = (size_t)cOff + m0 + lrow;
    short8 v = *(const short8*)&Cs[lrow*136 + ocol];
    bf16* dst = C + (size_t)seg*segStride + mrow*ldc + nb + ocol;
    float rowSum = 0.f, rowSq = 0.f;
    if (ADD){
      short8 c = *(const short8*)dst;
      short8 o;
      #pragma unroll
      for (int e = 0; e < 8; e++){
        bf16 va, ca;
        *reinterpret_cast<short*>(&va) = v[e];
        *reinterpret_cast<short*>(&ca) = c[e];
        float f = cvt(va) + cvt(ca);
        o[e] = bfbits(f);
        if (STATS){ rowSum += f; rowSq += f*f; }
      }
      *(short8*)dst = o;
    } else {
      if (STATS){
        #pragma unroll
        for (int e = 0; e < 8; e++){
          bf16 va; *reinterpret_cast<short*>(&va) = v[e];
          float f = cvt(va);
          rowSum += f; rowSq += f*f;
        }
      }
      *(short8*)dst = v;
    }
    if (STATS){
      #pragma unroll
      for (int mk = 1; mk <= 8; mk <<= 1){
        rowSum += __shfl_xor(rowSum, mk, 64);
        rowSq  += __shfl_xor(rowSq,  mk, 64);
      }
      if ((tid & 15) == 0){
        atomicAdd(&s1o[mrow], rowSum);
        atomicAdd(&s2o[mrow], rowSq);
      }
    }
  }
}

// ---- lightweight windowed attention: softmax(QK^T/sqrt(hd)) @ V -----------
__global__ __launch_bounds__(256) void attn_lite(
    bf16* __restrict__ Qg, const bf16* __restrict__ Kg, const bf16* __restrict__ Vg)
{
  __shared__ float qs[8][257], ks[8][257], vs[8][257];
  __shared__ float sc[8][8][8];   // [h][q][k]
  const int c = threadIdx.x;
  const size_t base = (size_t)blockIdx.x * 8 * 256;
  #pragma unroll
  for (int j = 0; j < 8; j++){
    qs[j][c] = cvt(Qg[base + j*256 + c]);
    ks[j][c] = cvt(Kg[base + j*256 + c]);
    vs[j][c] = cvt(Vg[base + j*256 + c]);
  }
  __syncthreads();

  const float scale = 0.17677669529663687f; // 1/sqrt(32)
  #pragma unroll
  for (int r = 0; r < 2; r++){
    int idx = r*256 + c;
    int h = idx >> 6, qi = (idx >> 3) & 7, ki = idx & 7;
    float s = 0.f;
    #pragma unroll
    for (int d = 0; d < 32; d++) s += qs[qi][h*32+d] * ks[ki][h*32+d];
    sc[h][qi][ki] = s * scale;
  }
  __syncthreads();

  if (c < 64){
    int h = c >> 3, qi = c & 7;
    float mx = -1e30f;
    #pragma unroll
    for (int u = 0; u < 8; u++) mx = fmaxf(mx, sc[h][qi][u]);
    float e[8], sum = 0.f;
    #pragma unroll
    for (int u = 0; u < 8; u++){ e[u] = __expf(sc[h][qi][u] - mx); sum += e[u]; }
    float inv = 1.f / sum;
    #pragma unroll
    for (int u = 0; u < 8; u++) sc[h][qi][u] = e[u] * inv;
  }
  __syncthreads();

  {
    int h = c >> 5;
    #pragma unroll
    for (int j = 0; j < 8; j++){
      float o = 0.f;
      #pragma unroll
      for (int u = 0; u < 8; u++) o += sc[h][j][u] * vs[u][c];
      Qg[base + j*256 + c] = __float2bfloat16(o);
    }
  }
}

// ---- alpha head with fused ln_f (raw sums): one wave per token ------------
__global__ __launch_bounds__(256) void alpha_kernel(
    const bf16* __restrict__ X, const float* __restrict__ s1,
    const float* __restrict__ s2, const float* __restrict__ s,
    const float* __restrict__ b, const float* __restrict__ wa,
    const float* __restrict__ ba, float* __restrict__ out)
{
  int lane = threadIdx.x & 63, w = threadIdx.x >> 6;
  size_t t = (size_t)blockIdx.x * 4 + w;
  float m = s1[t] * (1.f/256.f);
  float q = s2[t] * (1.f/256.f);
  float r = rsqrtf(q - m*m + 1e-6f);
  float acc = 0.f;
  #pragma unroll
  for (int j = 0; j < 4; j++){
    int c = lane + 64*j;
    float y = (cvt(X[t*DMODEL + c]) - m) * r * s[c] + b[c];
    acc += y * wa[c];
  }
  #pragma unroll
  for (int off = 32; off; off >>= 1) acc += __shfl_down(acc, off, 64);
  if (lane == 0) out[t] = acc + ba[0];
}

// ---- rgb2: t1 stored with ld=256 (cols 0..127), @ (128,3) + b (f32 out) ---
__global__ __launch_bounds__(256) void rgb2_kernel(
    const bf16* __restrict__ T1, const float* __restrict__ w2,
    const float* __restrict__ b2, float* __restrict__ out)
{
  int lane = threadIdx.x & 63, w = threadIdx.x >> 6;
  size_t t = (size_t)blockIdx.x * 4 + w;
  float h0 = cvt(T1[t*256 + lane]);
  float h1 = cvt(T1[t*256 + 64 + lane]);
  float a0 = h0*w2[lane*3+0] + h1*w2[(lane+64)*3+0];
  float a1 = h0*w2[lane*3+1] + h1*w2[(lane+64)*3+1];
  float a2 = h0*w2[lane*3+2] + h1*w2[(lane+64)*3+2];
  #pragma unroll
  for (int off = 32; off; off >>= 1){
    a0 += __shfl_down(a0, off, 64);
    a1 += __shfl_down(a1, off, 64);
    a2 += __shfl_down(a2, off, 64);
  }
  if (lane == 0){
    out[t*3+0] = a0 + b2[0];
    out[t*3+1] = a1 + b2[1];
    out[t*3+2] = a2 + b2[2];
  }
}

extern "C" void kernel_launch(void* const* d_in, const int* in_sizes, int n_in,
                              void* d_out, int out_size, void* d_ws, size_t ws_size,
                              hipStream_t stream)
{
  (void)in_sizes; (void)n_in; (void)out_size;
  const float* pts     = (const float*)d_in[0];
  const float* views   = (const float*)d_in[1];
  const float* w_in    = (const float*)d_in[2];
  const float* b_in    = (const float*)d_in[3];
  const float* ln_in_s = (const float*)d_in[4];
  const float* ln_in_b = (const float*)d_in[5];
  const float* ln1_s   = (const float*)d_in[6];
  const float* ln1_b   = (const float*)d_in[7];
  const float* wq      = (const float*)d_in[8];
  const float* bq      = (const float*)d_in[9];
  const float* wk      = (const float*)d_in[10];
  const float* bk      = (const float*)d_in[11];
  const float* wv      = (const float*)d_in[12];
  const float* bv      = (const float*)d_in[13];
  const float* wo      = (const float*)d_in[14];
  const float* bo      = (const float*)d_in[15];
  const float* ln2_s   = (const float*)d_in[16];
  const float* ln2_b   = (const float*)d_in[17];
  const float* w_mlp1  = (const float*)d_in[18];
  const float* b_mlp1  = (const float*)d_in[19];
  const float* w_mlp2  = (const float*)d_in[20];
  const float* b_mlp2  = (const float*)d_in[21];
  const float* w_skip  = (const float*)d_in[22];
  const float* b_skip  = (const float*)d_in[23];
  const float* ln_f_s  = (const float*)d_in[24];
  const float* ln_f_b  = (const float*)d_in[25];
  const float* w_alpha = (const float*)d_in[26];
  const float* b_alpha = (const float*)d_in[27];
  const float* w_feat  = (const float*)d_in[28];
  const float* b_feat  = (const float*)d_in[29];
  const float* w_rgb1  = (const float*)d_in[30];
  const float* b_rgb1  = (const float*)d_in[31];
  const float* w_rgb2  = (const float*)d_in[32];
  const float* b_rgb2  = (const float*)d_in[33];

  const size_t SZ = (size_t)T_TOK * DMODEL * 2;        // 100,663,296 B
  const size_t WT_ELEMS = 16384 + 2*(196608 + 3*65536 + 81920) + 65536 + 36864;
  const size_t UV_FLOATS = 2*768*2 + 2*256*2 + 2*256;  // u/wB buffers = 4608
  const size_t NEED = 2*SZ + (size_t)4*T_TOK*4 + NSEQ*DMODEL*4 + UV_FLOATS*4
                    + WT_ELEMS*2 + (size_t)T_TOK*64*2 + 1024*32*2;
  if (ws_size < NEED) return;

  char* wsp = (char*)d_ws;
  bf16* xr = (bf16*)(wsp);
  bf16* x2 = (bf16*)(wsp + SZ);
  float* s1A = (float*)(wsp + 2*SZ);
  float* s2A = s1A + T_TOK;
  float* s1B = s2A + T_TOK;
  float* s2B = s1B + T_TOK;
  float* PE  = s2B + T_TOK;                  // 192*256 floats
  float* uvp = PE + NSEQ*DMODEL;
  float* uqkv[2], *wBqkv[2], *um1[2], *wBm1[2];
  {
    float* q = uvp;
    for (int i = 0; i < 2; i++){ uqkv[i] = q; q += 768; }
    for (int i = 0; i < 2; i++){ wBqkv[i] = q; q += 768; }
    for (int i = 0; i < 2; i++){ um1[i] = q; q += 256; }
    for (int i = 0; i < 2; i++){ wBm1[i] = q; q += 256; }
  }
  float* ufeat  = uvp + 2*768*2 + 2*256*2;
  float* wBfeat = ufeat + 256;
  bf16* wtp = (bf16*)(uvp + UV_FLOATS);

  bf16* wt_in = wtp;                         // 256 x 64
  bf16* wt_qkv[2], *wt_o[2], *wt_m1[2], *wt_m2[2], *wt_sk[2];
  bf16* p = wt_in + 16384;
  for (int i = 0; i < 2; i++){
    wt_qkv[i] = p; p += 196608;              // 768 x 256
    wt_o[i]   = p; p += 65536;
    wt_m1[i]  = p; p += 65536;
    wt_m2[i]  = p; p += 65536;
    wt_sk[i]  = p; p += 81920;               // 256 x 320
  }
  bf16* wt_feat = p; p += 65536;
  bf16* wt_rgb1 = p; p += 36864;             // 128 x 288
  bf16* pts_b   = p; p += (size_t)T_TOK*64;  // T x 64
  bf16* views_b = p; p += 1024*32;

  float* out_rgb   = (float*)d_out;
  float* out_alpha = out_rgb + (size_t)T_TOK * 3;

  dim3 blk(256);
  dim3 g256(2, T_TOK/128);       // full-T, Nc=256
  dim3 gQKV(6, CHUNKM/128);      // chunk, Nc=768
  dim3 gC(2, CHUNKM/128);        // chunk, Nc=256
  dim3 g128(1, T_TOK/128);       // full-T, Nc=128
  dim3 gLN(T_TOK/4);             // wave-per-token LN+PE
  dim3 gStat(T_TOK/4);
  dim3 gAttn(CHUNKM/8);

  const float* NF = nullptr;
  const bf16*  NB = nullptr;
  float* NFW = nullptr;

  // ---- setup: PE table, pre-convert inputs & weights to bf16, u/wB ----
  pe_kernel<<<dim3(NSEQ), blk, 0, stream>>>(PE);
  pts2b_kernel<<<dim3(T_TOK*64/256), blk, 0, stream>>>(pts, pts_b);
  views2b_kernel<<<dim3(1024*32/256), blk, 0, stream>>>(views, views_b);
  #define W2B(src, dst, K_, N_, KL_, ST_, KO_, SC_) \
    w2b_kernel<<<dim3(((N_)*(KL_)+255)/256), blk, 0, stream>>>(src, dst, K_, N_, KL_, ST_, KO_, SC_)
  W2B(w_in, wt_in, 63, 256, 64, 64, 0, NF);
  for (int i = 0; i < 2; i++){
    const float* s1 = ln1_s + i*256;
    const float* b1 = ln1_b + i*256;
    W2B(wq + (size_t)i*65536, wt_qkv[i],            256, 256, 256, 256, 0, s1);
    W2B(wk + (size_t)i*65536, wt_qkv[i] + 65536,    256, 256, 256, 256, 0, s1);
    W2B(wv + (size_t)i*65536, wt_qkv[i] + 131072,   256, 256, 256, 256, 0, s1);
    ucalc_kernel<<<dim3(256), blk, 0, stream>>>(wq + (size_t)i*65536, s1, b1,
        bq + i*256, uqkv[i],       wBqkv[i],       256, 256);
    ucalc_kernel<<<dim3(256), blk, 0, stream>>>(wk + (size_t)i*65536, s1, b1,
        bk + i*256, uqkv[i] + 256, wBqkv[i] + 256, 256, 256);
    ucalc_kernel<<<dim3(256), blk, 0, stream>>>(wv + (size_t)i*65536, s1, b1,
        bv + i*256, uqkv[i] + 512, wBqkv[i] + 512, 256, 256);
    W2B(wo + (size_t)i*65536, wt_o[i],  256, 256, 256, 256, 0, NF);
    W2B(w_mlp1 + (size_t)i*65536, wt_m1[i], 256, 256, 256, 256, 0, ln2_s + i*256);
    ucalc_kernel<<<dim3(256), blk, 0, stream>>>(w_mlp1 + (size_t)i*65536,
        ln2_s + i*256, ln2_b + i*256, b_mlp1 + i*256, um1[i], wBm1[i], 256, 256);
    W2B(w_mlp2 + (size_t)i*65536, wt_m2[i], 256, 256, 256, 256, 0, NF);
    W2B(w_skip + (size_t)i*81664,            wt_sk[i], 63, 256, 64, 320, 0, NF);
    W2B(w_skip + (size_t)i*81664 + 63*256,   wt_sk[i], 256, 256, 256, 320, 64, NF);
  }
  W2B(w_feat, wt_feat, 256, 256, 256, 256, 0, ln_f_s);
  ucalc_kernel<<<dim3(256), blk, 0, stream>>>(w_feat, ln_f_s, ln_f_b, b_feat,
      ufeat, wBfeat, 256, 256);
  W2B(w_rgb1,                wt_rgb1, 256, 128, 256, 288, 0, NF);
  W2B(w_rgb1 + 256*128,      wt_rgb1, 27, 128, 32, 288, 256, NF);
  #undef W2B

  // x = pts @ w_in + b_in -> xr ; x = ln(x) + pe (in place, stats -> A)
  gemm_mfma<0,false,false,false,false><<<g256, blk, 0, stream>>>(pts_b, 64,
      NB, 0, 0, 0, NF, NF, NF, wt_in, 64, b_in,
      xr, 256, 0, 0, 0, NFW, NFW);
  ln_pe_kernel<<<gLN, blk, 0, stream>>>(xr, ln_in_s, ln_in_b, PE, s1A, s2A);

  for (int i = 0; i < 2; i++){
    const int shift = (i == 1) ? 4 : 0;
    const int shiftBack = (i == 1) ? (NSEQ - 4) : 0;

    // zero ln2-stats accumulators
    hipMemsetAsync(s1B, 0, (size_t)2*T_TOK*4, stream);

    // attention, chunked: Q/K/V buffers live inside x2 (3 x 24 MB)
    bf16* qb = x2;
    bf16* kb = x2 + (size_t)CHUNKM * 256;
    bf16* vb = x2 + (size_t)2 * CHUNKM * 256;
    for (int cch = 0; cch < CHUNKS; cch++){
      int base = cch * CHUNKM;
      // fused q|k|v = ln1(roll(x_chunk)) @ wqkv' + wB  (LN folded)
      gemm_mfma<0,true,false,false,false><<<gQKV, blk, 0, stream>>>(xr, 256,
          NB, 0, 0, base, s1A, s2A, uqkv[i], wt_qkv[i], 256, wBqkv[i],
          x2, 256, (size_t)CHUNKM*256, 0, shift, NFW, NFW);
      attn_lite<<<gAttn, blk, 0, stream>>>(qb, kb, vb);
      // x_chunk += roll_back(O) @ wo + bo   (stats -> B)
      gemm_mfma<0,false,true,false,true><<<gC, blk, 0, stream>>>(qb, 256,
          NB, 0, 0, 0, NF, NF, NF, wt_o[i], 256, bo + i*256,
          xr, 256, 0, base, shiftBack, s1B, s2B);
    }

    // mlp (ln2 folded, stats B)
    gemm_mfma<0,true,false,true,false><<<g256, blk, 0, stream>>>(xr, 256,
        NB, 0, 0, 0, s1B, s2B, um1[i], wt_m1[i], 256, wBm1[i],
        x2, 256, 0, 0, 0, NFW, NFW);
    gemm_mfma<0,false,true,false,false><<<g256, blk, 0, stream>>>(x2, 256,
        NB, 0, 0, 0, NF, NF, NF, wt_m2[i], 256, b_mlp2 + i*256,
        xr, 256, 0, 0, 0, NFW, NFW);
    // x = gelu(concat(pts, x) @ w_skip + b_skip) -> x2 (stats -> A), swap
    hipMemsetAsync(s1A, 0, (size_t)2*T_TOK*4, stream);
    gemm_mfma<2,false,false,true,true><<<g256, blk, 0, stream>>>(pts_b, 64,
        xr, 256, 64, 0, NF, NF, NF, wt_sk[i], 320, b_skip + i*256,
        x2, 256, 0, 0, 0, s1A, s2A);
    bf16* tmp = xr; xr = x2; x2 = tmp;
  }

  // head (ln_f from stats A)
  alpha_kernel<<<gStat, blk, 0, stream>>>(xr, s1A, s2A, ln_f_s, ln_f_b,
      w_alpha, b_alpha, out_alpha);
  // feature = ln_f(x) @ w_feat + b_feat -> x2  (LN folded)
  gemm_mfma<0,true,false,false,false><<<g256, blk, 0, stream>>>(xr, 256,
      NB, 0, 0, 0, s1A, s2A, ufeat, wt_feat, 256, wBfeat,
      x2, 256, 0, 0, 0, NFW, NFW);
  // t1 = gelu(concat(feature, views) @ w_rgb1 + b_rgb1) -> xr cols 0..127
  gemm_mfma<3,false,false,true,false><<<g128, blk, 0, stream>>>(x2, 256,
      views_b, 32, 256, 0, NF, NF, NF, wt_rgb1, 288, b_rgb1,
      xr, 256, 0, 0, 0, NFW, NFW);
  rgb2_kernel<<<gStat, blk, 0, stream>>>(xr, w_rgb2, b_rgb2, out_rgb);
}

// Round 10
// 2895.126 us; speedup vs baseline: 1.0049x; 1.0049x over previous
//
#include <hip/hip_runtime.h>
#include <hip/hip_bf16.h>
#include <math.h>

typedef __hip_bfloat16 bf16;
typedef __attribute__((ext_vector_type(8))) short short8;
typedef __attribute__((ext_vector_type(4))) float f32x4;

#define T_TOK 196608   // B*N = 1024*192
#define NSEQ  192
#define DMODEL 256
#define CHUNKS 4
#define CHUNKM (T_TOK/CHUNKS)   // 49152 tokens = 256 sequences

__device__ __forceinline__ float cvt(float v){ return v; }
__device__ __forceinline__ float cvt(bf16 v){ return __bfloat162float(v); }
__device__ __forceinline__ short bfbits(float f){
  bf16 h = __float2bfloat16(f); return *reinterpret_cast<short*>(&h);
}
__device__ __forceinline__ float bfu(unsigned short v){ return __uint_as_float(((unsigned)v) << 16); }

// gelu(tanh approx) == x * sigmoid(2u), u = k0(x+0.044715x^3).
// Uses HW v_exp_f32 instead of libm tanhf (~30 VALU ops -> ~8).
__device__ __forceinline__ float gelu_f(float x){
  const float k0 = 0.7978845608028654f; // sqrt(2/pi)
  float u = k0*(x + 0.044715f*x*x*x);
  return x / (1.f + __expf(-2.f*u));
}

// lgkm-only barrier: ds ops drained, global loads stay IN FLIGHT across it.
// (__syncthreads would emit s_waitcnt vmcnt(0) and kill the A-prefetch.)
__device__ __forceinline__ void barrier_lgkm(){
  asm volatile("s_waitcnt lgkmcnt(0)" ::: "memory");
  __builtin_amdgcn_s_barrier();
  asm volatile("" ::: "memory");
}

// ---- pos-embed table: PE[n][d], n<192 ------------------------------------
__global__ __launch_bounds__(256) void pe_kernel(float* __restrict__ PE){
  int n = blockIdx.x, d = threadIdx.x;
  float e = (float)(2*(d>>1)) / 256.f;
  float ang = (float)n * powf(10000.f, -e);
  PE[n*DMODEL + d] = (d & 1) ? cosf(ang) : sinf(ang);
}

// ---- weight convert+transpose into segment: dst[n*dstStride+kOff+k] ------
// optional scale[k] multiplied in (for LN-fold W' = diag(lnS) @ W)
__global__ __launch_bounds__(256) void w2b_kernel(
    const float* __restrict__ src, bf16* __restrict__ dst,
    int K, int N, int KL, int dstStride, int kOff, const float* __restrict__ scale)
{
  int idx = blockIdx.x*256 + threadIdx.x;
  if (idx >= N*KL) return;
  int n = idx / KL, k = idx - n*KL;
  float v = 0.f;
  if (k < K){
    v = src[(size_t)k*N + n];
    if (scale) v *= scale[k];
  }
  dst[(size_t)n*dstStride + kOff + k] = __float2bfloat16(v);
}

// ---- u[n] = sum_k bf16(lnS[k]*W[k,n]);  wB[n] = sum_k lnB[k]*W[k,n]+bias[n]
// ONE BLOCK PER OUTPUT n (grid=N): wave+LDS reduce over K=256.
__global__ __launch_bounds__(256) void ucalc_kernel(
    const float* __restrict__ W, const float* __restrict__ lnS,
    const float* __restrict__ lnB, const float* __restrict__ bias,
    float* __restrict__ u, float* __restrict__ wB, int K, int N)
{
  __shared__ float pu[4], pb[4];
  const int n = blockIdx.x;
  const int k = threadIdx.x;
  float su = 0.f, sb = 0.f;
  if (k < K){
    float w = W[(size_t)k*N + n];
    su = cvt(__float2bfloat16(lnS[k]*w));   // match MFMA's rounded W'
    sb = lnB[k]*w;
  }
  #pragma unroll
  for (int off = 32; off; off >>= 1){
    su += __shfl_xor(su, off, 64);
    sb += __shfl_xor(sb, off, 64);
  }
  int lane = k & 63, wv = k >> 6;
  if (lane == 0){ pu[wv] = su; pb[wv] = sb; }
  __syncthreads();
  if (k == 0){
    u[n]  = pu[0]+pu[1]+pu[2]+pu[3];
    wB[n] = pb[0]+pb[1]+pb[2]+pb[3] + bias[n];
  }
}

// ---- pts -> bf16 [T][64] zero-padded --------------------------------------
__global__ __launch_bounds__(256) void pts2b_kernel(
    const float* __restrict__ src, bf16* __restrict__ dst)
{
  int idx = blockIdx.x*256 + threadIdx.x;   // T*64
  int t = idx >> 6, k = idx & 63;
  dst[idx] = __float2bfloat16(k < 63 ? src[(size_t)t*63 + k] : 0.f);
}

// ---- views -> bf16 [1024][32] zero-padded ---------------------------------
__global__ __launch_bounds__(256) void views2b_kernel(
    const float* __restrict__ src, bf16* __restrict__ dst)
{
  int idx = blockIdx.x*256 + threadIdx.x;   // 1024*32
  int t = idx >> 5, k = idx & 31;
  dst[idx] = __float2bfloat16(k < 27 ? src[(size_t)t*27 + k] : 0.f);
}

// ---- wave-per-token: x = ln(x)*s+b + PE[n]; writes raw stats (s1=Σy,s2=Σy²)
__global__ __launch_bounds__(256) void ln_pe_kernel(
    bf16* __restrict__ X, const float* __restrict__ s, const float* __restrict__ b,
    const float* __restrict__ PE, float* __restrict__ s1o, float* __restrict__ s2o)
{
  const int lane = threadIdx.x & 63, w = threadIdx.x >> 6;
  const size_t t = (size_t)blockIdx.x * 4 + w;
  const int n = (int)(t % NSEQ);
  const int c = lane * 4;

  ushort4 u = *reinterpret_cast<const ushort4*>(X + t*DMODEL + c);
  float x0 = bfu(u.x), x1 = bfu(u.y), x2 = bfu(u.z), x3 = bfu(u.w);

  float sx = x0 + x1 + x2 + x3;
  float sq = x0*x0 + x1*x1 + x2*x2 + x3*x3;
  #pragma unroll
  for (int off = 32; off; off >>= 1){
    sx += __shfl_xor(sx, off, 64);
    sq += __shfl_xor(sq, off, 64);
  }
  float mean = sx * (1.f/256.f);
  float var  = sq * (1.f/256.f) - mean*mean;
  float rstd = rsqrtf(var + 1e-6f);

  float4 sv = *reinterpret_cast<const float4*>(s + c);
  float4 bv = *reinterpret_cast<const float4*>(b + c);
  float4 pv = *reinterpret_cast<const float4*>(PE + n*DMODEL + c);

  float y0 = (x0 - mean)*rstd*sv.x + bv.x + pv.x;
  float y1 = (x1 - mean)*rstd*sv.y + bv.y + pv.y;
  float y2 = (x2 - mean)*rstd*sv.z + bv.z + pv.z;
  float y3 = (x3 - mean)*rstd*sv.w + bv.w + pv.w;

  ushort4 o;
  o.x = (unsigned short)bfbits(y0);
  o.y = (unsigned short)bfbits(y1);
  o.z = (unsigned short)bfbits(y2);
  o.w = (unsigned short)bfbits(y3);
  *reinterpret_cast<ushort4*>(X + t*DMODEL + c) = o;

  float sy  = y0 + y1 + y2 + y3;
  float syq = y0*y0 + y1*y1 + y2*y2 + y3*y3;
  #pragma unroll
  for (int off = 32; off; off >>= 1){
    sy  += __shfl_xor(sy,  off, 64);
    syq += __shfl_xor(syq, off, 64);
  }
  if (lane == 0){ s1o[t] = sy; s2o[t] = syq; }
}

// ---- MFMA GEMM: C = A @ W, 128x128 tile, 4 waves (R8 base + B ping-pong) --
// A: LDS double-buffer, 2-deep register prefetch (R8 structure; R9's 3-deep
//    variant hit 140 VGPR -> 11% occupancy -> 199us. REVERTED.)
// B: register ping-pong only - loadB(k+32) issued before MFMA(k).
// ONE lgkm-only barrier per k-step; global loads stay in flight across it.
// Cs reuses As LDS after the K-loop (2x5120 < 17408 shorts = 34.8 KB).
// MODE 0: plain bf16 A1 (rollShift supported)
// MODE 2: concat: k<SB -> A1[arow][k], else A2[arow][k-SB]    (SB%16==0)
// MODE 3: concat: k<SB -> A1[arow][k], else A2[arow/192][k-SB]
// LNF: C = rstd[m]*acc + (-mu[m]*rstd[m])*u[n] + wB[n]  (weights pre-scaled)
// C cols >=256 map to segment buffers: dst += (n0>>8)*segStride.
// STATS: per-row Σ and Σ² of final C values atomically added to s1o/s2o.
template<int MODE, bool LNF, bool ADD, bool GELU, bool STATS>
__global__ __launch_bounds__(256) void gemm_mfma(
    const bf16* __restrict__ A1, int lda1,
    const bf16* __restrict__ A2, int lda2, int SB, int aOff,
    const float* __restrict__ s1i, const float* __restrict__ s2i,
    const float* __restrict__ uvec,
    const bf16* __restrict__ WT, int Kpad, const float* __restrict__ bias,
    bf16* __restrict__ C, int ldc, size_t segStride, int cOff, int rollShift,
    float* __restrict__ s1o, float* __restrict__ s2o)
{
  __shared__ short buf[17408];    // As0|As1 (2x5120) ∪ Cs (17408) = 34816 B
  short* As0 = buf;
  short* As1 = buf + 5120;
  short* Cs  = buf;
  __shared__ float sScale[128], sAlpha[128];

  const int tid = threadIdx.x;
  const int lane = tid & 63, wid = tid >> 6;
  const int wm = wid >> 1, wn = wid & 1;
  const int col16 = lane & 15, quad = lane >> 4;
  const int sm = tid >> 1, half = tid & 1;   // staging: row, k-half
  const int m0 = blockIdx.y * 128, n0 = blockIdx.x * 128;

  f32x4 acc[4][4];
  #pragma unroll
  for (int i = 0; i < 4; i++)
    #pragma unroll
    for (int j = 0; j < 4; j++) acc[i][j] = (f32x4){0.f,0.f,0.f,0.f};

  // staging source row (rolled)
  int row = m0 + sm;
  if (MODE == 0 && rollShift){
    int bb = row / NSEQ;
    int n  = row - bb*NSEQ;
    n += rollShift; if (n >= NSEQ) n -= NSEQ;
    row = bb*NSEQ + n;
  }
  const size_t arow = (size_t)aOff + row;
  const size_t arow2 = (MODE == 3) ? (arow / NSEQ) : arow;

  // ---- LN-fold per-row scale/alpha (from rolled source row) ----
  if (LNF && tid < 128){
    int r2 = m0 + tid;
    if (rollShift){
      int bb = r2 / NSEQ, n = r2 - bb*NSEQ;
      n += rollShift; if (n >= NSEQ) n -= NSEQ;
      r2 = bb*NSEQ + n;
    }
    size_t r = (size_t)aOff + r2;
    float m1 = s1i[r] * (1.f/256.f);
    float m2 = s2i[r] * (1.f/256.f);
    float rs = rsqrtf(m2 - m1*m1 + 1e-6f);
    sScale[tid] = rs;
    sAlpha[tid] = -m1*rs;
  }

  auto loadA = [&](int k0, uint4& u0, uint4& u1){
    const int gk = k0 + half*16;
    const bf16* src;
    if (MODE == 0) src = A1 + arow*(size_t)lda1 + gk;
    else src = (gk < SB) ? (A1 + arow*(size_t)lda1 + gk)
                         : (A2 + arow2*(size_t)lda2 + (gk - SB));
    u0 = *(const uint4*)(src);
    u1 = *(const uint4*)(src + 8);
  };
  auto writeA = [&](short* dst, const uint4& u0, const uint4& u1){
    *(uint4*)&dst[sm*40 + half*16]     = u0;
    *(uint4*)&dst[sm*40 + half*16 + 8] = u1;
  };

  const short* bp[4];
  #pragma unroll
  for (int ni = 0; ni < 4; ni++)
    bp[ni] = (const short*)WT + (size_t)(n0 + wn*64 + ni*16 + col16)*Kpad + quad*8;

  auto loadB = [&](int k0, short8* bf){
    #pragma unroll
    for (int ni = 0; ni < 4; ni++) bf[ni] = *(const short8*)(bp[ni] + k0);
  };
  auto domfma = [&](const short* Asc, short8* bfr){
    short8 afr[4];
    #pragma unroll
    for (int mi = 0; mi < 4; mi++)
      afr[mi] = *(const short8*)&Asc[(wm*64 + mi*16 + col16)*40 + quad*8];
    #pragma unroll
    for (int mi = 0; mi < 4; mi++)
      #pragma unroll
      for (int ni = 0; ni < 4; ni++)
        acc[mi][ni] = __builtin_amdgcn_mfma_f32_16x16x32_bf16(
            afr[mi], bfr[ni], acc[mi][ni], 0, 0, 0);
  };

  // ---- prologue: tile0 -> As0; tile1 in regs; B(0) issued ----
  uint4 p0, p1;
  loadA(0, p0, p1);
  writeA(As0, p0, p1);
  if (Kpad > 32) loadA(32, p0, p1);
  short8 bA[4], bB[4];
  loadB(0, bA);
  barrier_lgkm();

  // ---- pipelined K-loop: pair-unrolled, B ping-pong, one barrier/step ----
  for (int k0 = 0; k0 < Kpad; k0 += 64){
    // even step (tile k0 in As0, B in bA)
    if (k0 + 32 < Kpad) loadB(k0 + 32, bB);      // prefetch next B
    domfma(As0, bA);
    if (k0 + 32 < Kpad){
      writeA(As1, p0, p1);                       // tile k0+32 -> As1
      if (k0 + 64 < Kpad) loadA(k0 + 64, p0, p1);
    }
    barrier_lgkm();
    if (k0 + 32 >= Kpad) break;
    // odd step (tile k0+32 in As1, B in bB)
    if (k0 + 64 < Kpad) loadB(k0 + 64, bA);
    domfma(As1, bB);
    if (k0 + 64 < Kpad){
      writeA(As0, p0, p1);                       // tile k0+64 -> As0
      if (k0 + 96 < Kpad) loadA(k0 + 96, p0, p1);
    }
    barrier_lgkm();
  }

  // ---- epilogue phase 1: acc -> affine/bias (+gelu) -> Cs bf16 ----
  // (last barrier drained all ds reads; As region safe to reuse as Cs)
  #pragma unroll
  for (int ni = 0; ni < 4; ni++){
    int ncol = wn*64 + ni*16 + col16;
    float bv = bias[n0 + ncol];
    float uv = LNF ? uvec[n0 + ncol] : 0.f;
    #pragma unroll
    for (int mi = 0; mi < 4; mi++){
      f32x4 a = acc[mi][ni];
      #pragma unroll
      for (int r = 0; r < 4; r++){
        int lrow = wm*64 + mi*16 + quad*4 + r;
        float val;
        if (LNF) val = sScale[lrow]*a[r] + sAlpha[lrow]*uv + bv;
        else     val = a[r] + bv;
        if (GELU) val = gelu_f(val);
        Cs[lrow*136 + ncol] = bfbits(val);
      }
    }
  }
  __syncthreads();

  // ---- epilogue phase 2: coalesced 16B stores (+ADD) (+STATS) ----
  const int seg = n0 >> 8;
  const int nb  = n0 & 255;
  const int orow = tid >> 4;         // 0..15
  const int ocol = (tid & 15) * 8;   // 0..120
  #pragma unroll
  for (int p = 0; p < 8; p++){
    int lrow = p*16 + orow;
    size_t mrow = (size_t)cOff + m0 + lrow;
    short8 v = *(const short8*)&Cs[lrow*136 + ocol];
    bf16* dst = C + (size_t)seg*segStride + mrow*ldc + nb + ocol;
    float rowSum = 0.f, rowSq = 0.f;
    if (ADD){
      short8 c = *(const short8*)dst;
      short8 o;
      #pragma unroll
      for (int e = 0; e < 8; e++){
        bf16 va, ca;
        *reinterpret_cast<short*>(&va) = v[e];
        *reinterpret_cast<short*>(&ca) = c[e];
        float f = cvt(va) + cvt(ca);
        o[e] = bfbits(f);
        if (STATS){ rowSum += f; rowSq += f*f; }
      }
      *(short8*)dst = o;
    } else {
      if (STATS){
        #pragma unroll
        for (int e = 0; e < 8; e++){
          bf16 va; *reinterpret_cast<short*>(&va) = v[e];
          float f = cvt(va);
          rowSum += f; rowSq += f*f;
        }
      }
      *(short8*)dst = v;
    }
    if (STATS){
      #pragma unroll
      for (int mk = 1; mk <= 8; mk <<= 1){
        rowSum += __shfl_xor(rowSum, mk, 64);
        rowSq  += __shfl_xor(rowSq,  mk, 64);
      }
      if ((tid & 15) == 0){
        atomicAdd(&s1o[mrow], rowSum);
        atomicAdd(&s2o[mrow], rowSq);
      }
    }
  }
}

// ---- lightweight windowed attention: softmax(QK^T/sqrt(hd)) @ V -----------
__global__ __launch_bounds__(256) void attn_lite(
    bf16* __restrict__ Qg, const bf16* __restrict__ Kg, const bf16* __restrict__ Vg)
{
  __shared__ float qs[8][257], ks[8][257], vs[8][257];
  __shared__ float sc[8][8][8];   // [h][q][k]
  const int c = threadIdx.x;
  const size_t base = (size_t)blockIdx.x * 8 * 256;
  #pragma unroll
  for (int j = 0; j < 8; j++){
    qs[j][c] = cvt(Qg[base + j*256 + c]);
    ks[j][c] = cvt(Kg[base + j*256 + c]);
    vs[j][c] = cvt(Vg[base + j*256 + c]);
  }
  __syncthreads();

  const float scale = 0.17677669529663687f; // 1/sqrt(32)
  #pragma unroll
  for (int r = 0; r < 2; r++){
    int idx = r*256 + c;
    int h = idx >> 6, qi = (idx >> 3) & 7, ki = idx & 7;
    float s = 0.f;
    #pragma unroll
    for (int d = 0; d < 32; d++) s += qs[qi][h*32+d] * ks[ki][h*32+d];
    sc[h][qi][ki] = s * scale;
  }
  __syncthreads();

  if (c < 64){
    int h = c >> 3, qi = c & 7;
    float mx = -1e30f;
    #pragma unroll
    for (int u = 0; u < 8; u++) mx = fmaxf(mx, sc[h][qi][u]);
    float e[8], sum = 0.f;
    #pragma unroll
    for (int u = 0; u < 8; u++){ e[u] = __expf(sc[h][qi][u] - mx); sum += e[u]; }
    float inv = 1.f / sum;
    #pragma unroll
    for (int u = 0; u < 8; u++) sc[h][qi][u] = e[u] * inv;
  }
  __syncthreads();

  {
    int h = c >> 5;
    #pragma unroll
    for (int j = 0; j < 8; j++){
      float o = 0.f;
      #pragma unroll
      for (int u = 0; u < 8; u++) o += sc[h][j][u] * vs[u][c];
      Qg[base + j*256 + c] = __float2bfloat16(o);
    }
  }
}

// ---- alpha head with fused ln_f (raw sums): one wave per token ------------
__global__ __launch_bounds__(256) void alpha_kernel(
    const bf16* __restrict__ X, const float* __restrict__ s1,
    const float* __restrict__ s2, const float* __restrict__ s,
    const float* __restrict__ b, const float* __restrict__ wa,
    const float* __restrict__ ba, float* __restrict__ out)
{
  int lane = threadIdx.x & 63, w = threadIdx.x >> 6;
  size_t t = (size_t)blockIdx.x * 4 + w;
  float m = s1[t] * (1.f/256.f);
  float q = s2[t] * (1.f/256.f);
  float r = rsqrtf(q - m*m + 1e-6f);
  float acc = 0.f;
  #pragma unroll
  for (int j = 0; j < 4; j++){
    int c = lane + 64*j;
    float y = (cvt(X[t*DMODEL + c]) - m) * r * s[c] + b[c];
    acc += y * wa[c];
  }
  #pragma unroll
  for (int off = 32; off; off >>= 1) acc += __shfl_down(acc, off, 64);
  if (lane == 0) out[t] = acc + ba[0];
}

// ---- rgb2: t1 stored with ld=256 (cols 0..127), @ (128,3) + b (f32 out) ---
__global__ __launch_bounds__(256) void rgb2_kernel(
    const bf16* __restrict__ T1, const float* __restrict__ w2,
    const float* __restrict__ b2, float* __restrict__ out)
{
  int lane = threadIdx.x & 63, w = threadIdx.x >> 6;
  size_t t = (size_t)blockIdx.x * 4 + w;
  float h0 = cvt(T1[t*256 + lane]);
  float h1 = cvt(T1[t*256 + 64 + lane]);
  float a0 = h0*w2[lane*3+0] + h1*w2[(lane+64)*3+0];
  float a1 = h0*w2[lane*3+1] + h1*w2[(lane+64)*3+1];
  float a2 = h0*w2[lane*3+2] + h1*w2[(lane+64)*3+2];
  #pragma unroll
  for (int off = 32; off; off >>= 1){
    a0 += __shfl_down(a0, off, 64);
    a1 += __shfl_down(a1, off, 64);
    a2 += __shfl_down(a2, off, 64);
  }
  if (lane == 0){
    out[t*3+0] = a0 + b2[0];
    out[t*3+1] = a1 + b2[1];
    out[t*3+2] = a2 + b2[2];
  }
}

extern "C" void kernel_launch(void* const* d_in, const int* in_sizes, int n_in,
                              void* d_out, int out_size, void* d_ws, size_t ws_size,
                              hipStream_t stream)
{
  (void)in_sizes; (void)n_in; (void)out_size;
  const float* pts     = (const float*)d_in[0];
  const float* views   = (const float*)d_in[1];
  const float* w_in    = (const float*)d_in[2];
  const float* b_in    = (const float*)d_in[3];
  const float* ln_in_s = (const float*)d_in[4];
  const float* ln_in_b = (const float*)d_in[5];
  const float* ln1_s   = (const float*)d_in[6];
  const float* ln1_b   = (const float*)d_in[7];
  const float* wq      = (const float*)d_in[8];
  const float* bq      = (const float*)d_in[9];
  const float* wk      = (const float*)d_in[10];
  const float* bk      = (const float*)d_in[11];
  const float* wv      = (const float*)d_in[12];
  const float* bv      = (const float*)d_in[13];
  const float* wo      = (const float*)d_in[14];
  const float* bo      = (const float*)d_in[15];
  const float* ln2_s   = (const float*)d_in[16];
  const float* ln2_b   = (const float*)d_in[17];
  const float* w_mlp1  = (const float*)d_in[18];
  const float* b_mlp1  = (const float*)d_in[19];
  const float* w_mlp2  = (const float*)d_in[20];
  const float* b_mlp2  = (const float*)d_in[21];
  const float* w_skip  = (const float*)d_in[22];
  const float* b_skip  = (const float*)d_in[23];
  const float* ln_f_s  = (const float*)d_in[24];
  const float* ln_f_b  = (const float*)d_in[25];
  const float* w_alpha = (const float*)d_in[26];
  const float* b_alpha = (const float*)d_in[27];
  const float* w_feat  = (const float*)d_in[28];
  const float* b_feat  = (const float*)d_in[29];
  const float* w_rgb1  = (const float*)d_in[30];
  const float* b_rgb1  = (const float*)d_in[31];
  const float* w_rgb2  = (const float*)d_in[32];
  const float* b_rgb2  = (const float*)d_in[33];

  const size_t SZ = (size_t)T_TOK * DMODEL * 2;        // 100,663,296 B
  const size_t WT_ELEMS = 16384 + 2*(196608 + 3*65536 + 81920) + 65536 + 36864;
  const size_t UV_FLOATS = 2*768*2 + 2*256*2 + 2*256;  // u/wB buffers = 4608
  const size_t NEED = 2*SZ + (size_t)4*T_TOK*4 + NSEQ*DMODEL*4 + UV_FLOATS*4
                    + WT_ELEMS*2 + (size_t)T_TOK*64*2 + 1024*32*2;
  if (ws_size < NEED) return;

  char* wsp = (char*)d_ws;
  bf16* xr = (bf16*)(wsp);
  bf16* x2 = (bf16*)(wsp + SZ);
  float* s1A = (float*)(wsp + 2*SZ);
  float* s2A = s1A + T_TOK;
  float* s1B = s2A + T_TOK;
  float* s2B = s1B + T_TOK;
  float* PE  = s2B + T_TOK;                  // 192*256 floats
  float* uvp = PE + NSEQ*DMODEL;
  float* uqkv[2], *wBqkv[2], *um1[2], *wBm1[2];
  {
    float* q = uvp;
    for (int i = 0; i < 2; i++){ uqkv[i] = q; q += 768; }
    for (int i = 0; i < 2; i++){ wBqkv[i] = q; q += 768; }
    for (int i = 0; i < 2; i++){ um1[i] = q; q += 256; }
    for (int i = 0; i < 2; i++){ wBm1[i] = q; q += 256; }
  }
  float* ufeat  = uvp + 2*768*2 + 2*256*2;
  float* wBfeat = ufeat + 256;
  bf16* wtp = (bf16*)(uvp + UV_FLOATS);

  bf16* wt_in = wtp;                         // 256 x 64
  bf16* wt_qkv[2], *wt_o[2], *wt_m1[2], *wt_m2[2], *wt_sk[2];
  bf16* p = wt_in + 16384;
  for (int i = 0; i < 2; i++){
    wt_qkv[i] = p; p += 196608;              // 768 x 256
    wt_o[i]   = p; p += 65536;
    wt_m1[i]  = p; p += 65536;
    wt_m2[i]  = p; p += 65536;
    wt_sk[i]  = p; p += 81920;               // 256 x 320
  }
  bf16* wt_feat = p; p += 65536;
  bf16* wt_rgb1 = p; p += 36864;             // 128 x 288
  bf16* pts_b   = p; p += (size_t)T_TOK*64;  // T x 64
  bf16* views_b = p; p += 1024*32;

  float* out_rgb   = (float*)d_out;
  float* out_alpha = out_rgb + (size_t)T_TOK * 3;

  dim3 blk(256);
  dim3 g256(2, T_TOK/128);       // full-T, Nc=256
  dim3 gQKV(6, CHUNKM/128);      // chunk, Nc=768
  dim3 gC(2, CHUNKM/128);        // chunk, Nc=256
  dim3 g128(1, T_TOK/128);       // full-T, Nc=128
  dim3 gLN(T_TOK/4);             // wave-per-token LN+PE
  dim3 gStat(T_TOK/4);
  dim3 gAttn(CHUNKM/8);

  const float* NF = nullptr;
  const bf16*  NB = nullptr;
  float* NFW = nullptr;

  // ---- setup: PE table, pre-convert inputs & weights to bf16, u/wB ----
  pe_kernel<<<dim3(NSEQ), blk, 0, stream>>>(PE);
  pts2b_kernel<<<dim3(T_TOK*64/256), blk, 0, stream>>>(pts, pts_b);
  views2b_kernel<<<dim3(1024*32/256), blk, 0, stream>>>(views, views_b);
  #define W2B(src, dst, K_, N_, KL_, ST_, KO_, SC_) \
    w2b_kernel<<<dim3(((N_)*(KL_)+255)/256), blk, 0, stream>>>(src, dst, K_, N_, KL_, ST_, KO_, SC_)
  W2B(w_in, wt_in, 63, 256, 64, 64, 0, NF);
  for (int i = 0; i < 2; i++){
    const float* s1 = ln1_s + i*256;
    const float* b1 = ln1_b + i*256;
    W2B(wq + (size_t)i*65536, wt_qkv[i],            256, 256, 256, 256, 0, s1);
    W2B(wk + (size_t)i*65536, wt_qkv[i] + 65536,    256, 256, 256, 256, 0, s1);
    W2B(wv + (size_t)i*65536, wt_qkv[i] + 131072,   256, 256, 256, 256, 0, s1);
    ucalc_kernel<<<dim3(256), blk, 0, stream>>>(wq + (size_t)i*65536, s1, b1,
        bq + i*256, uqkv[i],       wBqkv[i],       256, 256);
    ucalc_kernel<<<dim3(256), blk, 0, stream>>>(wk + (size_t)i*65536, s1, b1,
        bk + i*256, uqkv[i] + 256, wBqkv[i] + 256, 256, 256);
    ucalc_kernel<<<dim3(256), blk, 0, stream>>>(wv + (size_t)i*65536, s1, b1,
        bv + i*256, uqkv[i] + 512, wBqkv[i] + 512, 256, 256);
    W2B(wo + (size_t)i*65536, wt_o[i],  256, 256, 256, 256, 0, NF);
    W2B(w_mlp1 + (size_t)i*65536, wt_m1[i], 256, 256, 256, 256, 0, ln2_s + i*256);
    ucalc_kernel<<<dim3(256), blk, 0, stream>>>(w_mlp1 + (size_t)i*65536,
        ln2_s + i*256, ln2_b + i*256, b_mlp1 + i*256, um1[i], wBm1[i], 256, 256);
    W2B(w_mlp2 + (size_t)i*65536, wt_m2[i], 256, 256, 256, 256, 0, NF);
    W2B(w_skip + (size_t)i*81664,            wt_sk[i], 63, 256, 64, 320, 0, NF);
    W2B(w_skip + (size_t)i*81664 + 63*256,   wt_sk[i], 256, 256, 256, 320, 64, NF);
  }
  W2B(w_feat, wt_feat, 256, 256, 256, 256, 0, ln_f_s);
  ucalc_kernel<<<dim3(256), blk, 0, stream>>>(w_feat, ln_f_s, ln_f_b, b_feat,
      ufeat, wBfeat, 256, 256);
  W2B(w_rgb1,                wt_rgb1, 256, 128, 256, 288, 0, NF);
  W2B(w_rgb1 + 256*128,      wt_rgb1, 27, 128, 32, 288, 256, NF);
  #undef W2B

  // x = pts @ w_in + b_in -> xr ; x = ln(x) + pe (in place, stats -> A)
  gemm_mfma<0,false,false,false,false><<<g256, blk, 0, stream>>>(pts_b, 64,
      NB, 0, 0, 0, NF, NF, NF, wt_in, 64, b_in,
      xr, 256, 0, 0, 0, NFW, NFW);
  ln_pe_kernel<<<gLN, blk, 0, stream>>>(xr, ln_in_s, ln_in_b, PE, s1A, s2A);

  for (int i = 0; i < 2; i++){
    const int shift = (i == 1) ? 4 : 0;
    const int shiftBack = (i == 1) ? (NSEQ - 4) : 0;

    // zero ln2-stats accumulators
    hipMemsetAsync(s1B, 0, (size_t)2*T_TOK*4, stream);

    // attention, chunked: Q/K/V buffers live inside x2 (3 x 24 MB)
    bf16* qb = x2;
    bf16* kb = x2 + (size_t)CHUNKM * 256;
    bf16* vb = x2 + (size_t)2 * CHUNKM * 256;
    for (int cch = 0; cch < CHUNKS; cch++){
      int base = cch * CHUNKM;
      // fused q|k|v = ln1(roll(x_chunk)) @ wqkv' + wB  (LN folded)
      gemm_mfma<0,true,false,false,false><<<gQKV, blk, 0, stream>>>(xr, 256,
          NB, 0, 0, base, s1A, s2A, uqkv[i], wt_qkv[i], 256, wBqkv[i],
          x2, 256, (size_t)CHUNKM*256, 0, shift, NFW, NFW);
      attn_lite<<<gAttn, blk, 0, stream>>>(qb, kb, vb);
      // x_chunk += roll_back(O) @ wo + bo   (stats -> B)
      gemm_mfma<0,false,true,false,true><<<gC, blk, 0, stream>>>(qb, 256,
          NB, 0, 0, 0, NF, NF, NF, wt_o[i], 256, bo + i*256,
          xr, 256, 0, base, shiftBack, s1B, s2B);
    }

    // mlp (ln2 folded, stats B)
    gemm_mfma<0,true,false,true,false><<<g256, blk, 0, stream>>>(xr, 256,
        NB, 0, 0, 0, s1B, s2B, um1[i], wt_m1[i], 256, wBm1[i],
        x2, 256, 0, 0, 0, NFW, NFW);
    gemm_mfma<0,false,true,false,false><<<g256, blk, 0, stream>>>(x2, 256,
        NB, 0, 0, 0, NF, NF, NF, wt_m2[i], 256, b_mlp2 + i*256,
        xr, 256, 0, 0, 0, NFW, NFW);
    // x = gelu(concat(pts, x) @ w_skip + b_skip) -> x2 (stats -> A), swap
    hipMemsetAsync(s1A, 0, (size_t)2*T_TOK*4, stream);
    gemm_mfma<2,false,false,true,true><<<g256, blk, 0, stream>>>(pts_b, 64,
        xr, 256, 64, 0, NF, NF, NF, wt_sk[i], 320, b_skip + i*256,
        x2, 256, 0, 0, 0, s1A, s2A);
    bf16* tmp = xr; xr = x2; x2 = tmp;
  }

  // head (ln_f from stats A)
  alpha_kernel<<<gStat, blk, 0, stream>>>(xr, s1A, s2A, ln_f_s, ln_f_b,
      w_alpha, b_alpha, out_alpha);
  // feature = ln_f(x) @ w_feat + b_feat -> x2  (LN folded)
  gemm_mfma<0,true,false,false,false><<<g256, blk, 0, stream>>>(xr, 256,
      NB, 0, 0, 0, s1A, s2A, ufeat, wt_feat, 256, wBfeat,
      x2, 256, 0, 0, 0, NFW, NFW);
  // t1 = gelu(concat(feature, views) @ w_rgb1 + b_rgb1) -> xr cols 0..127
  gemm_mfma<3,false,false,true,false><<<g128, blk, 0, stream>>>(x2, 256,
      views_b, 32, 256, 0, NF, NF, NF, wt_rgb1, 288, b_rgb1,
      xr, 256, 0, 0, 0, NFW, NFW);
  rgb2_kernel<<<gStat, blk, 0, stream>>>(xr, w_rgb2, b_rgb2, out_rgb);
}

// Round 11
// 2027.100 us; speedup vs baseline: 1.4353x; 1.4282x over previous
//
#include <hip/hip_runtime.h>
#include <hip/hip_bf16.h>
#include <math.h>

typedef __hip_bfloat16 bf16;
typedef __attribute__((ext_vector_type(8))) short short8;
typedef __attribute__((ext_vector_type(4))) float f32x4;

#define T_TOK 196608   // B*N = 1024*192
#define NSEQ  192
#define DMODEL 256
#define CHUNKS 4
#define CHUNKM (T_TOK/CHUNKS)   // 49152 tokens = 256 sequences

__device__ __forceinline__ float cvt(float v){ return v; }
__device__ __forceinline__ float cvt(bf16 v){ return __bfloat162float(v); }
__device__ __forceinline__ short bfbits(float f){
  bf16 h = __float2bfloat16(f); return *reinterpret_cast<short*>(&h);
}
__device__ __forceinline__ float bfu(unsigned short v){ return __uint_as_float(((unsigned)v) << 16); }

// gelu(tanh approx) == x * sigmoid(2u), u = k0(x+0.044715x^3).
// Uses HW v_exp_f32 instead of libm tanhf (~30 VALU ops -> ~8).
__device__ __forceinline__ float gelu_f(float x){
  const float k0 = 0.7978845608028654f; // sqrt(2/pi)
  float u = k0*(x + 0.044715f*x*x*x);
  return x / (1.f + __expf(-2.f*u));
}

// lgkm-only barrier: ds ops drained, global loads stay IN FLIGHT across it.
// (__syncthreads would emit s_waitcnt vmcnt(0) and kill the A-prefetch.)
__device__ __forceinline__ void barrier_lgkm(){
  asm volatile("s_waitcnt lgkmcnt(0)" ::: "memory");
  __builtin_amdgcn_s_barrier();
  asm volatile("" ::: "memory");
}

// ---- pos-embed table: PE[n][d], n<192 ------------------------------------
__global__ __launch_bounds__(256) void pe_kernel(float* __restrict__ PE){
  int n = blockIdx.x, d = threadIdx.x;
  float e = (float)(2*(d>>1)) / 256.f;
  float ang = (float)n * powf(10000.f, -e);
  PE[n*DMODEL + d] = (d & 1) ? cosf(ang) : sinf(ang);
}

// ---- weight convert+transpose into segment: dst[n*dstStride+kOff+k] ------
// optional scale[k] multiplied in (for LN-fold W' = diag(lnS) @ W)
__global__ __launch_bounds__(256) void w2b_kernel(
    const float* __restrict__ src, bf16* __restrict__ dst,
    int K, int N, int KL, int dstStride, int kOff, const float* __restrict__ scale)
{
  int idx = blockIdx.x*256 + threadIdx.x;
  if (idx >= N*KL) return;
  int n = idx / KL, k = idx - n*KL;
  float v = 0.f;
  if (k < K){
    v = src[(size_t)k*N + n];
    if (scale) v *= scale[k];
  }
  dst[(size_t)n*dstStride + kOff + k] = __float2bfloat16(v);
}

// ---- u[n] = sum_k bf16(lnS[k]*W[k,n]);  wB[n] = sum_k lnB[k]*W[k,n]+bias[n]
// ONE BLOCK PER OUTPUT n (grid=N): wave+LDS reduce over K=256.
__global__ __launch_bounds__(256) void ucalc_kernel(
    const float* __restrict__ W, const float* __restrict__ lnS,
    const float* __restrict__ lnB, const float* __restrict__ bias,
    float* __restrict__ u, float* __restrict__ wB, int K, int N)
{
  __shared__ float pu[4], pb[4];
  const int n = blockIdx.x;
  const int k = threadIdx.x;
  float su = 0.f, sb = 0.f;
  if (k < K){
    float w = W[(size_t)k*N + n];
    su = cvt(__float2bfloat16(lnS[k]*w));   // match MFMA's rounded W'
    sb = lnB[k]*w;
  }
  #pragma unroll
  for (int off = 32; off; off >>= 1){
    su += __shfl_xor(su, off, 64);
    sb += __shfl_xor(sb, off, 64);
  }
  int lane = k & 63, wv = k >> 6;
  if (lane == 0){ pu[wv] = su; pb[wv] = sb; }
  __syncthreads();
  if (k == 0){
    u[n]  = pu[0]+pu[1]+pu[2]+pu[3];
    wB[n] = pb[0]+pb[1]+pb[2]+pb[3] + bias[n];
  }
}

// ---- pts -> bf16 [T][64] zero-padded --------------------------------------
__global__ __launch_bounds__(256) void pts2b_kernel(
    const float* __restrict__ src, bf16* __restrict__ dst)
{
  int idx = blockIdx.x*256 + threadIdx.x;   // T*64
  int t = idx >> 6, k = idx & 63;
  dst[idx] = __float2bfloat16(k < 63 ? src[(size_t)t*63 + k] : 0.f);
}

// ---- views -> bf16 [1024][32] zero-padded ---------------------------------
__global__ __launch_bounds__(256) void views2b_kernel(
    const float* __restrict__ src, bf16* __restrict__ dst)
{
  int idx = blockIdx.x*256 + threadIdx.x;   // 1024*32
  int t = idx >> 5, k = idx & 31;
  dst[idx] = __float2bfloat16(k < 27 ? src[(size_t)t*27 + k] : 0.f);
}

// ---- wave-per-token: x = ln(x)*s+b + PE[n]; writes raw stats (s1=Σy,s2=Σy²)
__global__ __launch_bounds__(256) void ln_pe_kernel(
    bf16* __restrict__ X, const float* __restrict__ s, const float* __restrict__ b,
    const float* __restrict__ PE, float* __restrict__ s1o, float* __restrict__ s2o)
{
  const int lane = threadIdx.x & 63, w = threadIdx.x >> 6;
  const size_t t = (size_t)blockIdx.x * 4 + w;
  const int n = (int)(t % NSEQ);
  const int c = lane * 4;

  ushort4 u = *reinterpret_cast<const ushort4*>(X + t*DMODEL + c);
  float x0 = bfu(u.x), x1 = bfu(u.y), x2 = bfu(u.z), x3 = bfu(u.w);

  float sx = x0 + x1 + x2 + x3;
  float sq = x0*x0 + x1*x1 + x2*x2 + x3*x3;
  #pragma unroll
  for (int off = 32; off; off >>= 1){
    sx += __shfl_xor(sx, off, 64);
    sq += __shfl_xor(sq, off, 64);
  }
  float mean = sx * (1.f/256.f);
  float var  = sq * (1.f/256.f) - mean*mean;
  float rstd = rsqrtf(var + 1e-6f);

  float4 sv = *reinterpret_cast<const float4*>(s + c);
  float4 bv = *reinterpret_cast<const float4*>(b + c);
  float4 pv = *reinterpret_cast<const float4*>(PE + n*DMODEL + c);

  float y0 = (x0 - mean)*rstd*sv.x + bv.x + pv.x;
  float y1 = (x1 - mean)*rstd*sv.y + bv.y + pv.y;
  float y2 = (x2 - mean)*rstd*sv.z + bv.z + pv.z;
  float y3 = (x3 - mean)*rstd*sv.w + bv.w + pv.w;

  ushort4 o;
  o.x = (unsigned short)bfbits(y0);
  o.y = (unsigned short)bfbits(y1);
  o.z = (unsigned short)bfbits(y2);
  o.w = (unsigned short)bfbits(y3);
  *reinterpret_cast<ushort4*>(X + t*DMODEL + c) = o;

  float sy  = y0 + y1 + y2 + y3;
  float syq = y0*y0 + y1*y1 + y2*y2 + y3*y3;
  #pragma unroll
  for (int off = 32; off; off >>= 1){
    sy  += __shfl_xor(sy,  off, 64);
    syq += __shfl_xor(syq, off, 64);
  }
  if (lane == 0){ s1o[t] = sy; s2o[t] = syq; }
}

// ---- MFMA GEMM: C = A @ W, 128x128 tile, 4 waves (R8 = verified optimum) --
// A: LDS double-buffer, 2-deep register prefetch; B loaded in-iteration.
// ONE lgkm-only barrier per k-step; global loads stay in flight across it.
// Cs reuses As LDS after the K-loop (2x5120 < 17408 shorts = 34.8 KB).
// REGISTER BUDGET IS THE BINDING CONSTRAINT (measured): this config = 80
// VGPR -> 30% occ -> 110us. 3-deep A prefetch = 140 VGPR -> 11% -> 199us
// (R9). B ping-pong = 136 VGPR -> 11% -> 197us (R10). launch_bounds(256,4)
// = forced 64 VGPR -> spills -> 1.7GB scratch traffic (R4). DO NOT add
// per-wave latency state; TLP from 4-5 waves/SIMD beats per-wave ILP here.
// MODE 0: plain bf16 A1 (rollShift supported)
// MODE 2: concat: k<SB -> A1[arow][k], else A2[arow][k-SB]    (SB%16==0)
// MODE 3: concat: k<SB -> A1[arow][k], else A2[arow/192][k-SB]
// LNF: C = rstd[m]*acc + (-mu[m]*rstd[m])*u[n] + wB[n]  (weights pre-scaled)
// C cols >=256 map to segment buffers: dst += (n0>>8)*segStride.
// STATS: per-row Σ and Σ² of final C values atomically added to s1o/s2o.
template<int MODE, bool LNF, bool ADD, bool GELU, bool STATS>
__global__ __launch_bounds__(256) void gemm_mfma(
    const bf16* __restrict__ A1, int lda1,
    const bf16* __restrict__ A2, int lda2, int SB, int aOff,
    const float* __restrict__ s1i, const float* __restrict__ s2i,
    const float* __restrict__ uvec,
    const bf16* __restrict__ WT, int Kpad, const float* __restrict__ bias,
    bf16* __restrict__ C, int ldc, size_t segStride, int cOff, int rollShift,
    float* __restrict__ s1o, float* __restrict__ s2o)
{
  __shared__ short buf[17408];    // As0|As1 (2x5120) ∪ Cs (17408) = 34816 B
  short* As0 = buf;
  short* As1 = buf + 5120;
  short* Cs  = buf;
  __shared__ float sScale[128], sAlpha[128];

  const int tid = threadIdx.x;
  const int lane = tid & 63, wid = tid >> 6;
  const int wm = wid >> 1, wn = wid & 1;
  const int col16 = lane & 15, quad = lane >> 4;
  const int sm = tid >> 1, half = tid & 1;   // staging: row, k-half
  const int m0 = blockIdx.y * 128, n0 = blockIdx.x * 128;

  f32x4 acc[4][4];
  #pragma unroll
  for (int i = 0; i < 4; i++)
    #pragma unroll
    for (int j = 0; j < 4; j++) acc[i][j] = (f32x4){0.f,0.f,0.f,0.f};

  // staging source row (rolled)
  int row = m0 + sm;
  if (MODE == 0 && rollShift){
    int bb = row / NSEQ;
    int n  = row - bb*NSEQ;
    n += rollShift; if (n >= NSEQ) n -= NSEQ;
    row = bb*NSEQ + n;
  }
  const size_t arow = (size_t)aOff + row;
  const size_t arow2 = (MODE == 3) ? (arow / NSEQ) : arow;

  // ---- LN-fold per-row scale/alpha (from rolled source row) ----
  if (LNF && tid < 128){
    int r2 = m0 + tid;
    if (rollShift){
      int bb = r2 / NSEQ, n = r2 - bb*NSEQ;
      n += rollShift; if (n >= NSEQ) n -= NSEQ;
      r2 = bb*NSEQ + n;
    }
    size_t r = (size_t)aOff + r2;
    float m1 = s1i[r] * (1.f/256.f);
    float m2 = s2i[r] * (1.f/256.f);
    float rs = rsqrtf(m2 - m1*m1 + 1e-6f);
    sScale[tid] = rs;
    sAlpha[tid] = -m1*rs;
  }

  auto loadA = [&](int k0, uint4& u0, uint4& u1){
    const int gk = k0 + half*16;
    const bf16* src;
    if (MODE == 0) src = A1 + arow*(size_t)lda1 + gk;
    else src = (gk < SB) ? (A1 + arow*(size_t)lda1 + gk)
                         : (A2 + arow2*(size_t)lda2 + (gk - SB));
    u0 = *(const uint4*)(src);
    u1 = *(const uint4*)(src + 8);
  };
  auto writeA = [&](short* dst, const uint4& u0, const uint4& u1){
    *(uint4*)&dst[sm*40 + half*16]     = u0;
    *(uint4*)&dst[sm*40 + half*16 + 8] = u1;
  };

  // ---- prologue: tile 0 -> As0, tile 1 issued ----
  uint4 p0, p1;
  loadA(0, p0, p1);
  writeA(As0, p0, p1);
  if (Kpad > 32) loadA(32, p0, p1);
  barrier_lgkm();

  // ---- pipelined K-loop: ONE lgkm barrier per step ----
  int cur = 0;
  for (int k0 = 0; k0 < Kpad; k0 += 32){
    const short* Asc = cur ? As1 : As0;
    short8 afr[4];
    #pragma unroll
    for (int mi = 0; mi < 4; mi++)
      afr[mi] = *(const short8*)&Asc[(wm*64 + mi*16 + col16)*40 + quad*8];
    short8 bfr[4];
    #pragma unroll
    for (int ni = 0; ni < 4; ni++)
      bfr[ni] = *(const short8*)((const short*)WT
                 + (size_t)(n0 + wn*64 + ni*16 + col16)*Kpad + k0 + quad*8);
    #pragma unroll
    for (int mi = 0; mi < 4; mi++)
      #pragma unroll
      for (int ni = 0; ni < 4; ni++)
        acc[mi][ni] = __builtin_amdgcn_mfma_f32_16x16x32_bf16(
            afr[mi], bfr[ni], acc[mi][ni], 0, 0, 0);
    if (k0 + 32 < Kpad){
      short* Asn = cur ? As0 : As1;
      writeA(Asn, p0, p1);                    // waits vmcnt for tile t+1 only
      if (k0 + 64 < Kpad) loadA(k0+64, p0, p1);  // issue tile t+2
    }
    barrier_lgkm();
    cur ^= 1;
  }

  // ---- epilogue phase 1: acc -> affine/bias (+gelu) -> Cs bf16 ----
  // (last barrier drained all ds reads; As region safe to reuse as Cs)
  #pragma unroll
  for (int ni = 0; ni < 4; ni++){
    int ncol = wn*64 + ni*16 + col16;
    float bv = bias[n0 + ncol];
    float uv = LNF ? uvec[n0 + ncol] : 0.f;
    #pragma unroll
    for (int mi = 0; mi < 4; mi++){
      f32x4 a = acc[mi][ni];
      #pragma unroll
      for (int r = 0; r < 4; r++){
        int lrow = wm*64 + mi*16 + quad*4 + r;
        float val;
        if (LNF) val = sScale[lrow]*a[r] + sAlpha[lrow]*uv + bv;
        else     val = a[r] + bv;
        if (GELU) val = gelu_f(val);
        Cs[lrow*136 + ncol] = bfbits(val);
      }
    }
  }
  __syncthreads();

  // ---- epilogue phase 2: coalesced 16B stores (+ADD) (+STATS) ----
  const int seg = n0 >> 8;
  const int nb  = n0 & 255;
  const int orow = tid >> 4;         // 0..15
  const int ocol = (tid & 15) * 8;   // 0..120
  #pragma unroll
  for (int p = 0; p < 8; p++){
    int lrow = p*16 + orow;
    size_t mrow = (size_t)cOff + m0 + lrow;
    short8 v = *(const short8*)&Cs[lrow*136 + ocol];
    bf16* dst = C + (size_t)seg*segStride + mrow*ldc + nb + ocol;
    float rowSum = 0.f, rowSq = 0.f;
    if (ADD){
      short8 c = *(const short8*)dst;
      short8 o;
      #pragma unroll
      for (int e = 0; e < 8; e++){
        bf16 va, ca;
        *reinterpret_cast<short*>(&va) = v[e];
        *reinterpret_cast<short*>(&ca) = c[e];
        float f = cvt(va) + cvt(ca);
        o[e] = bfbits(f);
        if (STATS){ rowSum += f; rowSq += f*f; }
      }
      *(short8*)dst = o;
    } else {
      if (STATS){
        #pragma unroll
        for (int e = 0; e < 8; e++){
          bf16 va; *reinterpret_cast<short*>(&va) = v[e];
          float f = cvt(va);
          rowSum += f; rowSq += f*f;
        }
      }
      *(short8*)dst = v;
    }
    if (STATS){
      #pragma unroll
      for (int mk = 1; mk <= 8; mk <<= 1){
        rowSum += __shfl_xor(rowSum, mk, 64);
        rowSq  += __shfl_xor(rowSq,  mk, 64);
      }
      if ((tid & 15) == 0){
        atomicAdd(&s1o[mrow], rowSum);
        atomicAdd(&s2o[mrow], rowSq);
      }
    }
  }
}

// ---- lightweight windowed attention: softmax(QK^T/sqrt(hd)) @ V -----------
__global__ __launch_bounds__(256) void attn_lite(
    bf16* __restrict__ Qg, const bf16* __restrict__ Kg, const bf16* __restrict__ Vg)
{
  __shared__ float qs[8][257], ks[8][257], vs[8][257];
  __shared__ float sc[8][8][8];   // [h][q][k]
  const int c = threadIdx.x;
  const size_t base = (size_t)blockIdx.x * 8 * 256;
  #pragma unroll
  for (int j = 0; j < 8; j++){
    qs[j][c] = cvt(Qg[base + j*256 + c]);
    ks[j][c] = cvt(Kg[base + j*256 + c]);
    vs[j][c] = cvt(Vg[base + j*256 + c]);
  }
  __syncthreads();

  const float scale = 0.17677669529663687f; // 1/sqrt(32)
  #pragma unroll
  for (int r = 0; r < 2; r++){
    int idx = r*256 + c;
    int h = idx >> 6, qi = (idx >> 3) & 7, ki = idx & 7;
    float s = 0.f;
    #pragma unroll
    for (int d = 0; d < 32; d++) s += qs[qi][h*32+d] * ks[ki][h*32+d];
    sc[h][qi][ki] = s * scale;
  }
  __syncthreads();

  if (c < 64){
    int h = c >> 3, qi = c & 7;
    float mx = -1e30f;
    #pragma unroll
    for (int u = 0; u < 8; u++) mx = fmaxf(mx, sc[h][qi][u]);
    float e[8], sum = 0.f;
    #pragma unroll
    for (int u = 0; u < 8; u++){ e[u] = __expf(sc[h][qi][u] - mx); sum += e[u]; }
    float inv = 1.f / sum;
    #pragma unroll
    for (int u = 0; u < 8; u++) sc[h][qi][u] = e[u] * inv;
  }
  __syncthreads();

  {
    int h = c >> 5;
    #pragma unroll
    for (int j = 0; j < 8; j++){
      float o = 0.f;
      #pragma unroll
      for (int u = 0; u < 8; u++) o += sc[h][j][u] * vs[u][c];
      Qg[base + j*256 + c] = __float2bfloat16(o);
    }
  }
}

// ---- alpha head with fused ln_f (raw sums): one wave per token ------------
__global__ __launch_bounds__(256) void alpha_kernel(
    const bf16* __restrict__ X, const float* __restrict__ s1,
    const float* __restrict__ s2, const float* __restrict__ s,
    const float* __restrict__ b, const float* __restrict__ wa,
    const float* __restrict__ ba, float* __restrict__ out)
{
  int lane = threadIdx.x & 63, w = threadIdx.x >> 6;
  size_t t = (size_t)blockIdx.x * 4 + w;
  float m = s1[t] * (1.f/256.f);
  float q = s2[t] * (1.f/256.f);
  float r = rsqrtf(q - m*m + 1e-6f);
  float acc = 0.f;
  #pragma unroll
  for (int j = 0; j < 4; j++){
    int c = lane + 64*j;
    float y = (cvt(X[t*DMODEL + c]) - m) * r * s[c] + b[c];
    acc += y * wa[c];
  }
  #pragma unroll
  for (int off = 32; off; off >>= 1) acc += __shfl_down(acc, off, 64);
  if (lane == 0) out[t] = acc + ba[0];
}

// ---- rgb2: t1 stored with ld=256 (cols 0..127), @ (128,3) + b (f32 out) ---
__global__ __launch_bounds__(256) void rgb2_kernel(
    const bf16* __restrict__ T1, const float* __restrict__ w2,
    const float* __restrict__ b2, float* __restrict__ out)
{
  int lane = threadIdx.x & 63, w = threadIdx.x >> 6;
  size_t t = (size_t)blockIdx.x * 4 + w;
  float h0 = cvt(T1[t*256 + lane]);
  float h1 = cvt(T1[t*256 + 64 + lane]);
  float a0 = h0*w2[lane*3+0] + h1*w2[(lane+64)*3+0];
  float a1 = h0*w2[lane*3+1] + h1*w2[(lane+64)*3+1];
  float a2 = h0*w2[lane*3+2] + h1*w2[(lane+64)*3+2];
  #pragma unroll
  for (int off = 32; off; off >>= 1){
    a0 += __shfl_down(a0, off, 64);
    a1 += __shfl_down(a1, off, 64);
    a2 += __shfl_down(a2, off, 64);
  }
  if (lane == 0){
    out[t*3+0] = a0 + b2[0];
    out[t*3+1] = a1 + b2[1];
    out[t*3+2] = a2 + b2[2];
  }
}

extern "C" void kernel_launch(void* const* d_in, const int* in_sizes, int n_in,
                              void* d_out, int out_size, void* d_ws, size_t ws_size,
                              hipStream_t stream)
{
  (void)in_sizes; (void)n_in; (void)out_size;
  const float* pts     = (const float*)d_in[0];
  const float* views   = (const float*)d_in[1];
  const float* w_in    = (const float*)d_in[2];
  const float* b_in    = (const float*)d_in[3];
  const float* ln_in_s = (const float*)d_in[4];
  const float* ln_in_b = (const float*)d_in[5];
  const float* ln1_s   = (const float*)d_in[6];
  const float* ln1_b   = (const float*)d_in[7];
  const float* wq      = (const float*)d_in[8];
  const float* bq      = (const float*)d_in[9];
  const float* wk      = (const float*)d_in[10];
  const float* bk      = (const float*)d_in[11];
  const float* wv      = (const float*)d_in[12];
  const float* bv      = (const float*)d_in[13];
  const float* wo      = (const float*)d_in[14];
  const float* bo      = (const float*)d_in[15];
  const float* ln2_s   = (const float*)d_in[16];
  const float* ln2_b   = (const float*)d_in[17];
  const float* w_mlp1  = (const float*)d_in[18];
  const float* b_mlp1  = (const float*)d_in[19];
  const float* w_mlp2  = (const float*)d_in[20];
  const float* b_mlp2  = (const float*)d_in[21];
  const float* w_skip  = (const float*)d_in[22];
  const float* b_skip  = (const float*)d_in[23];
  const float* ln_f_s  = (const float*)d_in[24];
  const float* ln_f_b  = (const float*)d_in[25];
  const float* w_alpha = (const float*)d_in[26];
  const float* b_alpha = (const float*)d_in[27];
  const float* w_feat  = (const float*)d_in[28];
  const float* b_feat  = (const float*)d_in[29];
  const float* w_rgb1  = (const float*)d_in[30];
  const float* b_rgb1  = (const float*)d_in[31];
  const float* w_rgb2  = (const float*)d_in[32];
  const float* b_rgb2  = (const float*)d_in[33];

  const size_t SZ = (size_t)T_TOK * DMODEL * 2;        // 100,663,296 B
  const size_t WT_ELEMS = 16384 + 2*(196608 + 3*65536 + 81920) + 65536 + 36864;
  const size_t UV_FLOATS = 2*768*2 + 2*256*2 + 2*256;  // u/wB buffers = 4608
  const size_t NEED = 2*SZ + (size_t)4*T_TOK*4 + NSEQ*DMODEL*4 + UV_FLOATS*4
                    + WT_ELEMS*2 + (size_t)T_TOK*64*2 + 1024*32*2;
  if (ws_size < NEED) return;

  char* wsp = (char*)d_ws;
  bf16* xr = (bf16*)(wsp);
  bf16* x2 = (bf16*)(wsp + SZ);
  float* s1A = (float*)(wsp + 2*SZ);
  float* s2A = s1A + T_TOK;
  float* s1B = s2A + T_TOK;
  float* s2B = s1B + T_TOK;
  float* PE  = s2B + T_TOK;                  // 192*256 floats
  float* uvp = PE + NSEQ*DMODEL;
  float* uqkv[2], *wBqkv[2], *um1[2], *wBm1[2];
  {
    float* q = uvp;
    for (int i = 0; i < 2; i++){ uqkv[i] = q; q += 768; }
    for (int i = 0; i < 2; i++){ wBqkv[i] = q; q += 768; }
    for (int i = 0; i < 2; i++){ um1[i] = q; q += 256; }
    for (int i = 0; i < 2; i++){ wBm1[i] = q; q += 256; }
  }
  float* ufeat  = uvp + 2*768*2 + 2*256*2;
  float* wBfeat = ufeat + 256;
  bf16* wtp = (bf16*)(uvp + UV_FLOATS);

  bf16* wt_in = wtp;                         // 256 x 64
  bf16* wt_qkv[2], *wt_o[2], *wt_m1[2], *wt_m2[2], *wt_sk[2];
  bf16* p = wt_in + 16384;
  for (int i = 0; i < 2; i++){
    wt_qkv[i] = p; p += 196608;              // 768 x 256
    wt_o[i]   = p; p += 65536;
    wt_m1[i]  = p; p += 65536;
    wt_m2[i]  = p; p += 65536;
    wt_sk[i]  = p; p += 81920;               // 256 x 320
  }
  bf16* wt_feat = p; p += 65536;
  bf16* wt_rgb1 = p; p += 36864;             // 128 x 288
  bf16* pts_b   = p; p += (size_t)T_TOK*64;  // T x 64
  bf16* views_b = p; p += 1024*32;

  float* out_rgb   = (float*)d_out;
  float* out_alpha = out_rgb + (size_t)T_TOK * 3;

  dim3 blk(256);
  dim3 g256(2, T_TOK/128);       // full-T, Nc=256
  dim3 gQKV(6, CHUNKM/128);      // chunk, Nc=768
  dim3 gC(2, CHUNKM/128);        // chunk, Nc=256
  dim3 g128(1, T_TOK/128);       // full-T, Nc=128
  dim3 gLN(T_TOK/4);             // wave-per-token LN+PE
  dim3 gStat(T_TOK/4);
  dim3 gAttn(CHUNKM/8);

  const float* NF = nullptr;
  const bf16*  NB = nullptr;
  float* NFW = nullptr;

  // ---- setup: PE table, pre-convert inputs & weights to bf16, u/wB ----
  pe_kernel<<<dim3(NSEQ), blk, 0, stream>>>(PE);
  pts2b_kernel<<<dim3(T_TOK*64/256), blk, 0, stream>>>(pts, pts_b);
  views2b_kernel<<<dim3(1024*32/256), blk, 0, stream>>>(views, views_b);
  #define W2B(src, dst, K_, N_, KL_, ST_, KO_, SC_) \
    w2b_kernel<<<dim3(((N_)*(KL_)+255)/256), blk, 0, stream>>>(src, dst, K_, N_, KL_, ST_, KO_, SC_)
  W2B(w_in, wt_in, 63, 256, 64, 64, 0, NF);
  for (int i = 0; i < 2; i++){
    const float* s1 = ln1_s + i*256;
    const float* b1 = ln1_b + i*256;
    W2B(wq + (size_t)i*65536, wt_qkv[i],            256, 256, 256, 256, 0, s1);
    W2B(wk + (size_t)i*65536, wt_qkv[i] + 65536,    256, 256, 256, 256, 0, s1);
    W2B(wv + (size_t)i*65536, wt_qkv[i] + 131072,   256, 256, 256, 256, 0, s1);
    ucalc_kernel<<<dim3(256), blk, 0, stream>>>(wq + (size_t)i*65536, s1, b1,
        bq + i*256, uqkv[i],       wBqkv[i],       256, 256);
    ucalc_kernel<<<dim3(256), blk, 0, stream>>>(wk + (size_t)i*65536, s1, b1,
        bk + i*256, uqkv[i] + 256, wBqkv[i] + 256, 256, 256);
    ucalc_kernel<<<dim3(256), blk, 0, stream>>>(wv + (size_t)i*65536, s1, b1,
        bv + i*256, uqkv[i] + 512, wBqkv[i] + 512, 256, 256);
    W2B(wo + (size_t)i*65536, wt_o[i],  256, 256, 256, 256, 0, NF);
    W2B(w_mlp1 + (size_t)i*65536, wt_m1[i], 256, 256, 256, 256, 0, ln2_s + i*256);
    ucalc_kernel<<<dim3(256), blk, 0, stream>>>(w_mlp1 + (size_t)i*65536,
        ln2_s + i*256, ln2_b + i*256, b_mlp1 + i*256, um1[i], wBm1[i], 256, 256);
    W2B(w_mlp2 + (size_t)i*65536, wt_m2[i], 256, 256, 256, 256, 0, NF);
    W2B(w_skip + (size_t)i*81664,            wt_sk[i], 63, 256, 64, 320, 0, NF);
    W2B(w_skip + (size_t)i*81664 + 63*256,   wt_sk[i], 256, 256, 256, 320, 64, NF);
  }
  W2B(w_feat, wt_feat, 256, 256, 256, 256, 0, ln_f_s);
  ucalc_kernel<<<dim3(256), blk, 0, stream>>>(w_feat, ln_f_s, ln_f_b, b_feat,
      ufeat, wBfeat, 256, 256);
  W2B(w_rgb1,                wt_rgb1, 256, 128, 256, 288, 0, NF);
  W2B(w_rgb1 + 256*128,      wt_rgb1, 27, 128, 32, 288, 256, NF);
  #undef W2B

  // x = pts @ w_in + b_in -> xr ; x = ln(x) + pe (in place, stats -> A)
  gemm_mfma<0,false,false,false,false><<<g256, blk, 0, stream>>>(pts_b, 64,
      NB, 0, 0, 0, NF, NF, NF, wt_in, 64, b_in,
      xr, 256, 0, 0, 0, NFW, NFW);
  ln_pe_kernel<<<gLN, blk, 0, stream>>>(xr, ln_in_s, ln_in_b, PE, s1A, s2A);

  for (int i = 0; i < 2; i++){
    const int shift = (i == 1) ? 4 : 0;
    const int shiftBack = (i == 1) ? (NSEQ - 4) : 0;

    // zero ln2-stats accumulators
    hipMemsetAsync(s1B, 0, (size_t)2*T_TOK*4, stream);

    // attention, chunked: Q/K/V buffers live inside x2 (3 x 24 MB)
    bf16* qb = x2;
    bf16* kb = x2 + (size_t)CHUNKM * 256;
    bf16* vb = x2 + (size_t)2 * CHUNKM * 256;
    for (int cch = 0; cch < CHUNKS; cch++){
      int base = cch * CHUNKM;
      // fused q|k|v = ln1(roll(x_chunk)) @ wqkv' + wB  (LN folded)
      gemm_mfma<0,true,false,false,false><<<gQKV, blk, 0, stream>>>(xr, 256,
          NB, 0, 0, base, s1A, s2A, uqkv[i], wt_qkv[i], 256, wBqkv[i],
          x2, 256, (size_t)CHUNKM*256, 0, shift, NFW, NFW);
      attn_lite<<<gAttn, blk, 0, stream>>>(qb, kb, vb);
      // x_chunk += roll_back(O) @ wo + bo   (stats -> B)
      gemm_mfma<0,false,true,false,true><<<gC, blk, 0, stream>>>(qb, 256,
          NB, 0, 0, 0, NF, NF, NF, wt_o[i], 256, bo + i*256,
          xr, 256, 0, base, shiftBack, s1B, s2B);
    }

    // mlp (ln2 folded, stats B)
    gemm_mfma<0,true,false,true,false><<<g256, blk, 0, stream>>>(xr, 256,
        NB, 0, 0, 0, s1B, s2B, um1[i], wt_m1[i], 256, wBm1[i],
        x2, 256, 0, 0, 0, NFW, NFW);
    gemm_mfma<0,false,true,false,false><<<g256, blk, 0, stream>>>(x2, 256,
        NB, 0, 0, 0, NF, NF, NF, wt_m2[i], 256, b_mlp2 + i*256,
        xr, 256, 0, 0, 0, NFW, NFW);
    // x = gelu(concat(pts, x) @ w_skip + b_skip) -> x2 (stats -> A), swap
    hipMemsetAsync(s1A, 0, (size_t)2*T_TOK*4, stream);
    gemm_mfma<2,false,false,true,true><<<g256, blk, 0, stream>>>(pts_b, 64,
        xr, 256, 64, 0, NF, NF, NF, wt_sk[i], 320, b_skip + i*256,
        x2, 256, 0, 0, 0, s1A, s2A);
    bf16* tmp = xr; xr = x2; x2 = tmp;
  }

  // head (ln_f from stats A)
  alpha_kernel<<<gStat, blk, 0, stream>>>(xr, s1A, s2A, ln_f_s, ln_f_b,
      w_alpha, b_alpha, out_alpha);
  // feature = ln_f(x) @ w_feat + b_feat -> x2  (LN folded)
  gemm_mfma<0,true,false,false,false><<<g256, blk, 0, stream>>>(xr, 256,
      NB, 0, 0, 0, s1A, s2A, ufeat, wt_feat, 256, wBfeat,
      x2, 256, 0, 0, 0, NFW, NFW);
  // t1 = gelu(concat(feature, views) @ w_rgb1 + b_rgb1) -> xr cols 0..127
  gemm_mfma<3,false,false,true,false><<<g128, blk, 0, stream>>>(x2, 256,
      views_b, 32, 256, 0, NF, NF, NF, wt_rgb1, 288, b_rgb1,
      xr, 256, 0, 0, 0, NFW, NFW);
  rgb2_kernel<<<gStat, blk, 0, stream>>>(xr, w_rgb2, b_rgb2, out_rgb);
}

// Round 12
// 2024.613 us; speedup vs baseline: 1.4370x; 1.0012x over previous
//
#include <hip/hip_runtime.h>
#include <hip/hip_bf16.h>
#include <math.h>

typedef __hip_bfloat16 bf16;
typedef __attribute__((ext_vector_type(8))) short short8;
typedef __attribute__((ext_vector_type(4))) float f32x4;

#define T_TOK 196608   // B*N = 1024*192
#define NSEQ  192
#define DMODEL 256
#define CHUNKS 4
#define CHUNKM (T_TOK/CHUNKS)   // 49152 tokens = 256 sequences

__device__ __forceinline__ float cvt(float v){ return v; }
__device__ __forceinline__ float cvt(bf16 v){ return __bfloat162float(v); }
__device__ __forceinline__ short bfbits(float f){
  bf16 h = __float2bfloat16(f); return *reinterpret_cast<short*>(&h);
}
__device__ __forceinline__ float bfu(unsigned short v){ return __uint_as_float(((unsigned)v) << 16); }

// gelu(tanh approx) == x * sigmoid(2u), u = k0(x+0.044715x^3).
// Uses HW v_exp_f32 instead of libm tanhf (~30 VALU ops -> ~8).
__device__ __forceinline__ float gelu_f(float x){
  const float k0 = 0.7978845608028654f; // sqrt(2/pi)
  float u = k0*(x + 0.044715f*x*x*x);
  return x / (1.f + __expf(-2.f*u));
}

// lgkm-only barrier: ds ops drained, global loads stay IN FLIGHT across it.
// (__syncthreads would emit s_waitcnt vmcnt(0) and kill the A-prefetch.)
__device__ __forceinline__ void barrier_lgkm(){
  asm volatile("s_waitcnt lgkmcnt(0)" ::: "memory");
  __builtin_amdgcn_s_barrier();
  asm volatile("" ::: "memory");
}

// ---- pos-embed table: PE[n][d], n<192 ------------------------------------
__global__ __launch_bounds__(256) void pe_kernel(float* __restrict__ PE){
  int n = blockIdx.x, d = threadIdx.x;
  float e = (float)(2*(d>>1)) / 256.f;
  float ang = (float)n * powf(10000.f, -e);
  PE[n*DMODEL + d] = (d & 1) ? cosf(ang) : sinf(ang);
}

// ---- weight convert+transpose into segment: dst[n*dstStride+kOff+k] ------
// optional scale[k] multiplied in (for LN-fold W' = diag(lnS) @ W)
__global__ __launch_bounds__(256) void w2b_kernel(
    const float* __restrict__ src, bf16* __restrict__ dst,
    int K, int N, int KL, int dstStride, int kOff, const float* __restrict__ scale)
{
  int idx = blockIdx.x*256 + threadIdx.x;
  if (idx >= N*KL) return;
  int n = idx / KL, k = idx - n*KL;
  float v = 0.f;
  if (k < K){
    v = src[(size_t)k*N + n];
    if (scale) v *= scale[k];
  }
  dst[(size_t)n*dstStride + kOff + k] = __float2bfloat16(v);
}

// ---- u[n] = sum_k bf16(lnS[k]*W[k,n]);  wB[n] = sum_k lnB[k]*W[k,n]+bias[n]
// ONE BLOCK PER OUTPUT n (grid=N): wave+LDS reduce over K=256.
__global__ __launch_bounds__(256) void ucalc_kernel(
    const float* __restrict__ W, const float* __restrict__ lnS,
    const float* __restrict__ lnB, const float* __restrict__ bias,
    float* __restrict__ u, float* __restrict__ wB, int K, int N)
{
  __shared__ float pu[4], pb[4];
  const int n = blockIdx.x;
  const int k = threadIdx.x;
  float su = 0.f, sb = 0.f;
  if (k < K){
    float w = W[(size_t)k*N + n];
    su = cvt(__float2bfloat16(lnS[k]*w));   // match MFMA's rounded W'
    sb = lnB[k]*w;
  }
  #pragma unroll
  for (int off = 32; off; off >>= 1){
    su += __shfl_xor(su, off, 64);
    sb += __shfl_xor(sb, off, 64);
  }
  int lane = k & 63, wv = k >> 6;
  if (lane == 0){ pu[wv] = su; pb[wv] = sb; }
  __syncthreads();
  if (k == 0){
    u[n]  = pu[0]+pu[1]+pu[2]+pu[3];
    wB[n] = pb[0]+pb[1]+pb[2]+pb[3] + bias[n];
  }
}

// ---- pts -> bf16 [T][64] zero-padded --------------------------------------
__global__ __launch_bounds__(256) void pts2b_kernel(
    const float* __restrict__ src, bf16* __restrict__ dst)
{
  int idx = blockIdx.x*256 + threadIdx.x;   // T*64
  int t = idx >> 6, k = idx & 63;
  dst[idx] = __float2bfloat16(k < 63 ? src[(size_t)t*63 + k] : 0.f);
}

// ---- views -> bf16 [1024][32] zero-padded ---------------------------------
__global__ __launch_bounds__(256) void views2b_kernel(
    const float* __restrict__ src, bf16* __restrict__ dst)
{
  int idx = blockIdx.x*256 + threadIdx.x;   // 1024*32
  int t = idx >> 5, k = idx & 31;
  dst[idx] = __float2bfloat16(k < 27 ? src[(size_t)t*27 + k] : 0.f);
}

// ---- wave-per-token: x = ln(x)*s+b + PE[n]; writes raw stats (s1=Σy,s2=Σy²)
__global__ __launch_bounds__(256) void ln_pe_kernel(
    bf16* __restrict__ X, const float* __restrict__ s, const float* __restrict__ b,
    const float* __restrict__ PE, float* __restrict__ s1o, float* __restrict__ s2o)
{
  const int lane = threadIdx.x & 63, w = threadIdx.x >> 6;
  const size_t t = (size_t)blockIdx.x * 4 + w;
  const int n = (int)(t % NSEQ);
  const int c = lane * 4;

  ushort4 u = *reinterpret_cast<const ushort4*>(X + t*DMODEL + c);
  float x0 = bfu(u.x), x1 = bfu(u.y), x2 = bfu(u.z), x3 = bfu(u.w);

  float sx = x0 + x1 + x2 + x3;
  float sq = x0*x0 + x1*x1 + x2*x2 + x3*x3;
  #pragma unroll
  for (int off = 32; off; off >>= 1){
    sx += __shfl_xor(sx, off, 64);
    sq += __shfl_xor(sq, off, 64);
  }
  float mean = sx * (1.f/256.f);
  float var  = sq * (1.f/256.f) - mean*mean;
  float rstd = rsqrtf(var + 1e-6f);

  float4 sv = *reinterpret_cast<const float4*>(s + c);
  float4 bv = *reinterpret_cast<const float4*>(b + c);
  float4 pv = *reinterpret_cast<const float4*>(PE + n*DMODEL + c);

  float y0 = (x0 - mean)*rstd*sv.x + bv.x + pv.x;
  float y1 = (x1 - mean)*rstd*sv.y + bv.y + pv.y;
  float y2 = (x2 - mean)*rstd*sv.z + bv.z + pv.z;
  float y3 = (x3 - mean)*rstd*sv.w + bv.w + pv.w;

  ushort4 o;
  o.x = (unsigned short)bfbits(y0);
  o.y = (unsigned short)bfbits(y1);
  o.z = (unsigned short)bfbits(y2);
  o.w = (unsigned short)bfbits(y3);
  *reinterpret_cast<ushort4*>(X + t*DMODEL + c) = o;

  float sy  = y0 + y1 + y2 + y3;
  float syq = y0*y0 + y1*y1 + y2*y2 + y3*y3;
  #pragma unroll
  for (int off = 32; off; off >>= 1){
    sy  += __shfl_xor(sy,  off, 64);
    syq += __shfl_xor(syq, off, 64);
  }
  if (lane == 0){ s1o[t] = sy; s2o[t] = syq; }
}

// ---- MFMA GEMM: C = A @ W, 128x128 tile, 4 waves (R8 = verified optimum) --
// A: LDS double-buffer, 2-deep register prefetch; B loaded in-iteration.
// ONE lgkm-only barrier per k-step; global loads stay in flight across it.
// Cs reuses As LDS after the K-loop (2x5120 < 17408 shorts = 34.8 KB).
// REGISTER BUDGET IS THE BINDING CONSTRAINT (measured): this config = 80
// VGPR -> 30% occ -> 110us. 3-deep A prefetch = 140 VGPR -> 11% -> 199us
// (R9). B ping-pong = 136 VGPR -> 11% -> 197us (R10). launch_bounds(256,4)
// = forced 64 VGPR -> spills -> 1.7GB scratch traffic (R4). DO NOT add
// per-wave latency state; TLP from 4-5 waves/SIMD beats per-wave ILP here.
// MODE 0: plain bf16 A1 (rollShift supported)
// MODE 2: concat: k<SB -> A1[arow][k], else A2[arow][k-SB]    (SB%16==0)
// MODE 3: concat: k<SB -> A1[arow][k], else A2[arow/192][k-SB]
// LNF: C = rstd[m]*acc + (-mu[m]*rstd[m])*u[n] + wB[n]  (weights pre-scaled)
// C cols >=256 map to segment buffers: dst += (n0>>8)*segStride.
// STATS: per-row Σ and Σ² of final C values atomically added to s1o/s2o.
template<int MODE, bool LNF, bool ADD, bool GELU, bool STATS>
__global__ __launch_bounds__(256) void gemm_mfma(
    const bf16* __restrict__ A1, int lda1,
    const bf16* __restrict__ A2, int lda2, int SB, int aOff,
    const float* __restrict__ s1i, const float* __restrict__ s2i,
    const float* __restrict__ uvec,
    const bf16* __restrict__ WT, int Kpad, const float* __restrict__ bias,
    bf16* __restrict__ C, int ldc, size_t segStride, int cOff, int rollShift,
    float* __restrict__ s1o, float* __restrict__ s2o)
{
  __shared__ short buf[17408];    // As0|As1 (2x5120) ∪ Cs (17408) = 34816 B
  short* As0 = buf;
  short* As1 = buf + 5120;
  short* Cs  = buf;
  __shared__ float sScale[128], sAlpha[128];

  const int tid = threadIdx.x;
  const int lane = tid & 63, wid = tid >> 6;
  const int wm = wid >> 1, wn = wid & 1;
  const int col16 = lane & 15, quad = lane >> 4;
  const int sm = tid >> 1, half = tid & 1;   // staging: row, k-half
  const int m0 = blockIdx.y * 128, n0 = blockIdx.x * 128;

  f32x4 acc[4][4];
  #pragma unroll
  for (int i = 0; i < 4; i++)
    #pragma unroll
    for (int j = 0; j < 4; j++) acc[i][j] = (f32x4){0.f,0.f,0.f,0.f};

  // staging source row (rolled)
  int row = m0 + sm;
  if (MODE == 0 && rollShift){
    int bb = row / NSEQ;
    int n  = row - bb*NSEQ;
    n += rollShift; if (n >= NSEQ) n -= NSEQ;
    row = bb*NSEQ + n;
  }
  const size_t arow = (size_t)aOff + row;
  const size_t arow2 = (MODE == 3) ? (arow / NSEQ) : arow;

  // ---- LN-fold per-row scale/alpha (from rolled source row) ----
  if (LNF && tid < 128){
    int r2 = m0 + tid;
    if (rollShift){
      int bb = r2 / NSEQ, n = r2 - bb*NSEQ;
      n += rollShift; if (n >= NSEQ) n -= NSEQ;
      r2 = bb*NSEQ + n;
    }
    size_t r = (size_t)aOff + r2;
    float m1 = s1i[r] * (1.f/256.f);
    float m2 = s2i[r] * (1.f/256.f);
    float rs = rsqrtf(m2 - m1*m1 + 1e-6f);
    sScale[tid] = rs;
    sAlpha[tid] = -m1*rs;
  }

  auto loadA = [&](int k0, uint4& u0, uint4& u1){
    const int gk = k0 + half*16;
    const bf16* src;
    if (MODE == 0) src = A1 + arow*(size_t)lda1 + gk;
    else src = (gk < SB) ? (A1 + arow*(size_t)lda1 + gk)
                         : (A2 + arow2*(size_t)lda2 + (gk - SB));
    u0 = *(const uint4*)(src);
    u1 = *(const uint4*)(src + 8);
  };
  auto writeA = [&](short* dst, const uint4& u0, const uint4& u1){
    *(uint4*)&dst[sm*40 + half*16]     = u0;
    *(uint4*)&dst[sm*40 + half*16 + 8] = u1;
  };

  // ---- prologue: tile 0 -> As0, tile 1 issued ----
  uint4 p0, p1;
  loadA(0, p0, p1);
  writeA(As0, p0, p1);
  if (Kpad > 32) loadA(32, p0, p1);
  barrier_lgkm();

  // ---- pipelined K-loop: ONE lgkm barrier per step ----
  int cur = 0;
  for (int k0 = 0; k0 < Kpad; k0 += 32){
    const short* Asc = cur ? As1 : As0;
    short8 afr[4];
    #pragma unroll
    for (int mi = 0; mi < 4; mi++)
      afr[mi] = *(const short8*)&Asc[(wm*64 + mi*16 + col16)*40 + quad*8];
    short8 bfr[4];
    #pragma unroll
    for (int ni = 0; ni < 4; ni++)
      bfr[ni] = *(const short8*)((const short*)WT
                 + (size_t)(n0 + wn*64 + ni*16 + col16)*Kpad + k0 + quad*8);
    #pragma unroll
    for (int mi = 0; mi < 4; mi++)
      #pragma unroll
      for (int ni = 0; ni < 4; ni++)
        acc[mi][ni] = __builtin_amdgcn_mfma_f32_16x16x32_bf16(
            afr[mi], bfr[ni], acc[mi][ni], 0, 0, 0);
    if (k0 + 32 < Kpad){
      short* Asn = cur ? As0 : As1;
      writeA(Asn, p0, p1);                    // waits vmcnt for tile t+1 only
      if (k0 + 64 < Kpad) loadA(k0+64, p0, p1);  // issue tile t+2
    }
    barrier_lgkm();
    cur ^= 1;
  }

  // ---- epilogue phase 1: acc -> affine/bias (+gelu) -> Cs bf16 ----
  // (last barrier drained all ds reads; As region safe to reuse as Cs)
  #pragma unroll
  for (int ni = 0; ni < 4; ni++){
    int ncol = wn*64 + ni*16 + col16;
    float bv = bias[n0 + ncol];
    float uv = LNF ? uvec[n0 + ncol] : 0.f;
    #pragma unroll
    for (int mi = 0; mi < 4; mi++){
      f32x4 a = acc[mi][ni];
      #pragma unroll
      for (int r = 0; r < 4; r++){
        int lrow = wm*64 + mi*16 + quad*4 + r;
        float val;
        if (LNF) val = sScale[lrow]*a[r] + sAlpha[lrow]*uv + bv;
        else     val = a[r] + bv;
        if (GELU) val = gelu_f(val);
        Cs[lrow*136 + ncol] = bfbits(val);
      }
    }
  }
  __syncthreads();

  // ---- epilogue phase 2: coalesced 16B stores (+ADD) (+STATS) ----
  const int seg = n0 >> 8;
  const int nb  = n0 & 255;
  const int orow = tid >> 4;         // 0..15
  const int ocol = (tid & 15) * 8;   // 0..120
  #pragma unroll
  for (int p = 0; p < 8; p++){
    int lrow = p*16 + orow;
    size_t mrow = (size_t)cOff + m0 + lrow;
    short8 v = *(const short8*)&Cs[lrow*136 + ocol];
    bf16* dst = C + (size_t)seg*segStride + mrow*ldc + nb + ocol;
    float rowSum = 0.f, rowSq = 0.f;
    if (ADD){
      short8 c = *(const short8*)dst;
      short8 o;
      #pragma unroll
      for (int e = 0; e < 8; e++){
        bf16 va, ca;
        *reinterpret_cast<short*>(&va) = v[e];
        *reinterpret_cast<short*>(&ca) = c[e];
        float f = cvt(va) + cvt(ca);
        o[e] = bfbits(f);
        if (STATS){ rowSum += f; rowSq += f*f; }
      }
      *(short8*)dst = o;
    } else {
      if (STATS){
        #pragma unroll
        for (int e = 0; e < 8; e++){
          bf16 va; *reinterpret_cast<short*>(&va) = v[e];
          float f = cvt(va);
          rowSum += f; rowSq += f*f;
        }
      }
      *(short8*)dst = v;
    }
    if (STATS){
      #pragma unroll
      for (int mk = 1; mk <= 8; mk <<= 1){
        rowSum += __shfl_xor(rowSum, mk, 64);
        rowSq  += __shfl_xor(rowSq,  mk, 64);
      }
      if ((tid & 15) == 0){
        atomicAdd(&s1o[mrow], rowSum);
        atomicAdd(&s2o[mrow], rowSq);
      }
    }
  }
}

// ---- FUSED MLP: Y += gelu(ln2(X)@W1 + b1) @ W2 + b2  (64-row tile) --------
// Stage 1: R8-style pipelined K-loop (LDS dbuf As, lgkm barriers), LN folded
//          into pre-scaled W1' + u/wB vectors; gelu -> sT (64x264 bf16 LDS).
// Stage 2: barrier-free K-loop, A-frags ds_read from sT, B = W2 (L2-hot).
// Epilogue: bias + residual-ADD via sT reused as the Cs shuffle buffer.
// Saves the 100MB t-intermediate write+read per layer (500->300 MB traffic).
// LDS 44032 B -> 3 blocks/CU. Watch VGPR <= ~115 (stage acc liveness
// disjoint; if >128 this kernel regresses - see R9/R10 journal).
__global__ __launch_bounds__(256) void mlp_fused(
    const bf16* __restrict__ X,
    const float* __restrict__ s1i, const float* __restrict__ s2i,
    const float* __restrict__ uvec,      // u (col sums of W1')
    const bf16* __restrict__ W1T,        // [256][256] (n,k), pre-scaled
    const float* __restrict__ wB1,       // lnB.W1 + b1
    const bf16* __restrict__ W2T,        // [256][256] (n,k)
    const float* __restrict__ b2,
    bf16* __restrict__ Y)                // in-place: Y == X
{
  __shared__ short sT[64*264];    // 33792 B: gelu(t1) tile, later Cs
  __shared__ short buf[5120];     // As dbuf: 2 x 64x40
  short* As0 = buf;
  short* As1 = buf + 2560;
  short* Cs  = sT;                // reused after stage-2 reads complete
  __shared__ float sScale[64], sAlpha[64];

  const int tid = threadIdx.x;
  const int lane = tid & 63, wid = tid >> 6;   // wave = 64-col block
  const int col16 = lane & 15, quad = lane >> 4;
  const int qr = tid >> 2, qc = tid & 3;       // staging: row 0-63, 8-chunk
  const int m0 = blockIdx.x * 64;

  // ---- LN-fold per-row factors ----
  if (tid < 64){
    size_t r = (size_t)m0 + tid;
    float m1 = s1i[r] * (1.f/256.f);
    float m2 = s2i[r] * (1.f/256.f);
    float rs = rsqrtf(m2 - m1*m1 + 1e-6f);
    sScale[tid] = rs;
    sAlpha[tid] = -m1*rs;
  }

  const size_t arow = (size_t)m0 + qr;
  auto loadA = [&](int k0, uint4& u){
    u = *(const uint4*)(X + arow*DMODEL + k0 + qc*8);
  };
  auto writeA = [&](short* dst, const uint4& u){
    *(uint4*)&dst[qr*40 + qc*8] = u;
  };

  f32x4 acc[4][4];
  #pragma unroll
  for (int i = 0; i < 4; i++)
    #pragma unroll
    for (int j = 0; j < 4; j++) acc[i][j] = (f32x4){0.f,0.f,0.f,0.f};

  // ---- stage 1: t = LNF(x) @ W1'  (pipelined, one lgkm barrier/step) ----
  uint4 p;
  loadA(0, p); writeA(As0, p);
  loadA(32, p);
  barrier_lgkm();
  int cur = 0;
  for (int k0 = 0; k0 < 256; k0 += 32){
    const short* Asc = cur ? As1 : As0;
    short8 afr[4];
    #pragma unroll
    for (int mi = 0; mi < 4; mi++)
      afr[mi] = *(const short8*)&Asc[(mi*16 + col16)*40 + quad*8];
    short8 bfr[4];
    #pragma unroll
    for (int ni = 0; ni < 4; ni++)
      bfr[ni] = *(const short8*)((const short*)W1T
                 + (size_t)(wid*64 + ni*16 + col16)*256 + k0 + quad*8);
    #pragma unroll
    for (int mi = 0; mi < 4; mi++)
      #pragma unroll
      for (int ni = 0; ni < 4; ni++)
        acc[mi][ni] = __builtin_amdgcn_mfma_f32_16x16x32_bf16(
            afr[mi], bfr[ni], acc[mi][ni], 0, 0, 0);
    if (k0 + 32 < 256){
      short* Asn = cur ? As0 : As1;
      writeA(Asn, p);
      if (k0 + 64 < 256) loadA(k0 + 64, p);
    }
    barrier_lgkm();
    cur ^= 1;
  }

  // ---- affine + gelu -> sT ----
  #pragma unroll
  for (int ni = 0; ni < 4; ni++){
    int ncol = wid*64 + ni*16 + col16;
    float uv = uvec[ncol];
    float bv = wB1[ncol];
    #pragma unroll
    for (int mi = 0; mi < 4; mi++){
      f32x4 a = acc[mi][ni];
      #pragma unroll
      for (int r = 0; r < 4; r++){
        int lrow = mi*16 + quad*4 + r;
        float val = sScale[lrow]*a[r] + sAlpha[lrow]*uv + bv;
        sT[lrow*264 + ncol] = bfbits(gelu_f(val));
      }
    }
  }
  __syncthreads();

  // ---- stage 2: y = t @ W2 (barrier-free; sT read-only) ----
  f32x4 acc2[4][4];
  #pragma unroll
  for (int i = 0; i < 4; i++)
    #pragma unroll
    for (int j = 0; j < 4; j++) acc2[i][j] = (f32x4){0.f,0.f,0.f,0.f};
  for (int k0 = 0; k0 < 256; k0 += 32){
    short8 afr[4];
    #pragma unroll
    for (int mi = 0; mi < 4; mi++)
      afr[mi] = *(const short8*)&sT[(mi*16 + col16)*264 + k0 + quad*8];
    short8 bfr[4];
    #pragma unroll
    for (int ni = 0; ni < 4; ni++)
      bfr[ni] = *(const short8*)((const short*)W2T
                 + (size_t)(wid*64 + ni*16 + col16)*256 + k0 + quad*8);
    #pragma unroll
    for (int mi = 0; mi < 4; mi++)
      #pragma unroll
      for (int ni = 0; ni < 4; ni++)
        acc2[mi][ni] = __builtin_amdgcn_mfma_f32_16x16x32_bf16(
            afr[mi], bfr[ni], acc2[mi][ni], 0, 0, 0);
  }
  __syncthreads();   // all sT reads done -> safe to reuse as Cs

  // ---- epilogue phase 1: acc2 + b2 -> Cs(=sT) bf16 ----
  #pragma unroll
  for (int ni = 0; ni < 4; ni++){
    int ncol = wid*64 + ni*16 + col16;
    float bv = b2[ncol];
    #pragma unroll
    for (int mi = 0; mi < 4; mi++){
      f32x4 a = acc2[mi][ni];
      #pragma unroll
      for (int r = 0; r < 4; r++){
        int lrow = mi*16 + quad*4 + r;
        Cs[lrow*264 + ncol] = bfbits(a[r] + bv);
      }
    }
  }
  __syncthreads();

  // ---- epilogue phase 2: coalesced residual-ADD stores ----
  const int orow = tid >> 5;         // 0..7
  const int oc   = (tid & 31) * 8;   // 0..248
  #pragma unroll
  for (int ppp = 0; ppp < 8; ppp++){
    int lrow = ppp*8 + orow;
    size_t mrow = (size_t)m0 + lrow;
    short8 v = *(const short8*)&Cs[lrow*264 + oc];
    bf16* dst = Y + mrow*DMODEL + oc;
    short8 c = *(const short8*)dst;
    short8 o;
    #pragma unroll
    for (int e = 0; e < 8; e++){
      bf16 va, ca;
      *reinterpret_cast<short*>(&va) = v[e];
      *reinterpret_cast<short*>(&ca) = c[e];
      o[e] = bfbits(cvt(va) + cvt(ca));
    }
    *(short8*)dst = o;
  }
}

// ---- lightweight windowed attention: softmax(QK^T/sqrt(hd)) @ V -----------
__global__ __launch_bounds__(256) void attn_lite(
    bf16* __restrict__ Qg, const bf16* __restrict__ Kg, const bf16* __restrict__ Vg)
{
  __shared__ float qs[8][257], ks[8][257], vs[8][257];
  __shared__ float sc[8][8][8];   // [h][q][k]
  const int c = threadIdx.x;
  const size_t base = (size_t)blockIdx.x * 8 * 256;
  #pragma unroll
  for (int j = 0; j < 8; j++){
    qs[j][c] = cvt(Qg[base + j*256 + c]);
    ks[j][c] = cvt(Kg[base + j*256 + c]);
    vs[j][c] = cvt(Vg[base + j*256 + c]);
  }
  __syncthreads();

  const float scale = 0.17677669529663687f; // 1/sqrt(32)
  #pragma unroll
  for (int r = 0; r < 2; r++){
    int idx = r*256 + c;
    int h = idx >> 6, qi = (idx >> 3) & 7, ki = idx & 7;
    float s = 0.f;
    #pragma unroll
    for (int d = 0; d < 32; d++) s += qs[qi][h*32+d] * ks[ki][h*32+d];
    sc[h][qi][ki] = s * scale;
  }
  __syncthreads();

  if (c < 64){
    int h = c >> 3, qi = c & 7;
    float mx = -1e30f;
    #pragma unroll
    for (int u = 0; u < 8; u++) mx = fmaxf(mx, sc[h][qi][u]);
    float e[8], sum = 0.f;
    #pragma unroll
    for (int u = 0; u < 8; u++){ e[u] = __expf(sc[h][qi][u] - mx); sum += e[u]; }
    float inv = 1.f / sum;
    #pragma unroll
    for (int u = 0; u < 8; u++) sc[h][qi][u] = e[u] * inv;
  }
  __syncthreads();

  {
    int h = c >> 5;
    #pragma unroll
    for (int j = 0; j < 8; j++){
      float o = 0.f;
      #pragma unroll
      for (int u = 0; u < 8; u++) o += sc[h][j][u] * vs[u][c];
      Qg[base + j*256 + c] = __float2bfloat16(o);
    }
  }
}

// ---- alpha head with fused ln_f (raw sums): one wave per token ------------
__global__ __launch_bounds__(256) void alpha_kernel(
    const bf16* __restrict__ X, const float* __restrict__ s1,
    const float* __restrict__ s2, const float* __restrict__ s,
    const float* __restrict__ b, const float* __restrict__ wa,
    const float* __restrict__ ba, float* __restrict__ out)
{
  int lane = threadIdx.x & 63, w = threadIdx.x >> 6;
  size_t t = (size_t)blockIdx.x * 4 + w;
  float m = s1[t] * (1.f/256.f);
  float q = s2[t] * (1.f/256.f);
  float r = rsqrtf(q - m*m + 1e-6f);
  float acc = 0.f;
  #pragma unroll
  for (int j = 0; j < 4; j++){
    int c = lane + 64*j;
    float y = (cvt(X[t*DMODEL + c]) - m) * r * s[c] + b[c];
    acc += y * wa[c];
  }
  #pragma unroll
  for (int off = 32; off; off >>= 1) acc += __shfl_down(acc, off, 64);
  if (lane == 0) out[t] = acc + ba[0];
}

// ---- rgb2: t1 stored with ld=256 (cols 0..127), @ (128,3) + b (f32 out) ---
__global__ __launch_bounds__(256) void rgb2_kernel(
    const bf16* __restrict__ T1, const float* __restrict__ w2,
    const float* __restrict__ b2, float* __restrict__ out)
{
  int lane = threadIdx.x & 63, w = threadIdx.x >> 6;
  size_t t = (size_t)blockIdx.x * 4 + w;
  float h0 = cvt(T1[t*256 + lane]);
  float h1 = cvt(T1[t*256 + 64 + lane]);
  float a0 = h0*w2[lane*3+0] + h1*w2[(lane+64)*3+0];
  float a1 = h0*w2[lane*3+1] + h1*w2[(lane+64)*3+1];
  float a2 = h0*w2[lane*3+2] + h1*w2[(lane+64)*3+2];
  #pragma unroll
  for (int off = 32; off; off >>= 1){
    a0 += __shfl_down(a0, off, 64);
    a1 += __shfl_down(a1, off, 64);
    a2 += __shfl_down(a2, off, 64);
  }
  if (lane == 0){
    out[t*3+0] = a0 + b2[0];
    out[t*3+1] = a1 + b2[1];
    out[t*3+2] = a2 + b2[2];
  }
}

extern "C" void kernel_launch(void* const* d_in, const int* in_sizes, int n_in,
                              void* d_out, int out_size, void* d_ws, size_t ws_size,
                              hipStream_t stream)
{
  (void)in_sizes; (void)n_in; (void)out_size;
  const float* pts     = (const float*)d_in[0];
  const float* views   = (const float*)d_in[1];
  const float* w_in    = (const float*)d_in[2];
  const float* b_in    = (const float*)d_in[3];
  const float* ln_in_s = (const float*)d_in[4];
  const float* ln_in_b = (const float*)d_in[5];
  const float* ln1_s   = (const float*)d_in[6];
  const float* ln1_b   = (const float*)d_in[7];
  const float* wq      = (const float*)d_in[8];
  const float* bq      = (const float*)d_in[9];
  const float* wk      = (const float*)d_in[10];
  const float* bk      = (const float*)d_in[11];
  const float* wv      = (const float*)d_in[12];
  const float* bv      = (const float*)d_in[13];
  const float* wo      = (const float*)d_in[14];
  const float* bo      = (const float*)d_in[15];
  const float* ln2_s   = (const float*)d_in[16];
  const float* ln2_b   = (const float*)d_in[17];
  const float* w_mlp1  = (const float*)d_in[18];
  const float* b_mlp1  = (const float*)d_in[19];
  const float* w_mlp2  = (const float*)d_in[20];
  const float* b_mlp2  = (const float*)d_in[21];
  const float* w_skip  = (const float*)d_in[22];
  const float* b_skip  = (const float*)d_in[23];
  const float* ln_f_s  = (const float*)d_in[24];
  const float* ln_f_b  = (const float*)d_in[25];
  const float* w_alpha = (const float*)d_in[26];
  const float* b_alpha = (const float*)d_in[27];
  const float* w_feat  = (const float*)d_in[28];
  const float* b_feat  = (const float*)d_in[29];
  const float* w_rgb1  = (const float*)d_in[30];
  const float* b_rgb1  = (const float*)d_in[31];
  const float* w_rgb2  = (const float*)d_in[32];
  const float* b_rgb2  = (const float*)d_in[33];

  const size_t SZ = (size_t)T_TOK * DMODEL * 2;        // 100,663,296 B
  const size_t WT_ELEMS = 16384 + 2*(196608 + 3*65536 + 81920) + 65536 + 36864;
  const size_t UV_FLOATS = 2*768*2 + 2*256*2 + 2*256;  // u/wB buffers = 4608
  const size_t NEED = 2*SZ + (size_t)4*T_TOK*4 + NSEQ*DMODEL*4 + UV_FLOATS*4
                    + WT_ELEMS*2 + (size_t)T_TOK*64*2 + 1024*32*2;
  if (ws_size < NEED) return;

  char* wsp = (char*)d_ws;
  bf16* xr = (bf16*)(wsp);
  bf16* x2 = (bf16*)(wsp + SZ);
  float* s1A = (float*)(wsp + 2*SZ);
  float* s2A = s1A + T_TOK;
  float* s1B = s2A + T_TOK;
  float* s2B = s1B + T_TOK;
  float* PE  = s2B + T_TOK;                  // 192*256 floats
  float* uvp = PE + NSEQ*DMODEL;
  float* uqkv[2], *wBqkv[2], *um1[2], *wBm1[2];
  {
    float* q = uvp;
    for (int i = 0; i < 2; i++){ uqkv[i] = q; q += 768; }
    for (int i = 0; i < 2; i++){ wBqkv[i] = q; q += 768; }
    for (int i = 0; i < 2; i++){ um1[i] = q; q += 256; }
    for (int i = 0; i < 2; i++){ wBm1[i] = q; q += 256; }
  }
  float* ufeat  = uvp + 2*768*2 + 2*256*2;
  float* wBfeat = ufeat + 256;
  bf16* wtp = (bf16*)(uvp + UV_FLOATS);

  bf16* wt_in = wtp;                         // 256 x 64
  bf16* wt_qkv[2], *wt_o[2], *wt_m1[2], *wt_m2[2], *wt_sk[2];
  bf16* p = wt_in + 16384;
  for (int i = 0; i < 2; i++){
    wt_qkv[i] = p; p += 196608;              // 768 x 256
    wt_o[i]   = p; p += 65536;
    wt_m1[i]  = p; p += 65536;
    wt_m2[i]  = p; p += 65536;
    wt_sk[i]  = p; p += 81920;               // 256 x 320
  }
  bf16* wt_feat = p; p += 65536;
  bf16* wt_rgb1 = p; p += 36864;             // 128 x 288
  bf16* pts_b   = p; p += (size_t)T_TOK*64;  // T x 64
  bf16* views_b = p; p += 1024*32;

  float* out_rgb   = (float*)d_out;
  float* out_alpha = out_rgb + (size_t)T_TOK * 3;

  dim3 blk(256);
  dim3 g256(2, T_TOK/128);       // full-T, Nc=256
  dim3 gQKV(6, CHUNKM/128);      // chunk, Nc=768
  dim3 gC(2, CHUNKM/128);        // chunk, Nc=256
  dim3 g128(1, T_TOK/128);       // full-T, Nc=128
  dim3 gLN(T_TOK/4);             // wave-per-token LN+PE
  dim3 gMLP(T_TOK/64);           // fused MLP, 64-row tiles
  dim3 gStat(T_TOK/4);
  dim3 gAttn(CHUNKM/8);

  const float* NF = nullptr;
  const bf16*  NB = nullptr;
  float* NFW = nullptr;

  // ---- setup: PE table, pre-convert inputs & weights to bf16, u/wB ----
  pe_kernel<<<dim3(NSEQ), blk, 0, stream>>>(PE);
  pts2b_kernel<<<dim3(T_TOK*64/256), blk, 0, stream>>>(pts, pts_b);
  views2b_kernel<<<dim3(1024*32/256), blk, 0, stream>>>(views, views_b);
  #define W2B(src, dst, K_, N_, KL_, ST_, KO_, SC_) \
    w2b_kernel<<<dim3(((N_)*(KL_)+255)/256), blk, 0, stream>>>(src, dst, K_, N_, KL_, ST_, KO_, SC_)
  W2B(w_in, wt_in, 63, 256, 64, 64, 0, NF);
  for (int i = 0; i < 2; i++){
    const float* s1 = ln1_s + i*256;
    const float* b1 = ln1_b + i*256;
    W2B(wq + (size_t)i*65536, wt_qkv[i],            256, 256, 256, 256, 0, s1);
    W2B(wk + (size_t)i*65536, wt_qkv[i] + 65536,    256, 256, 256, 256, 0, s1);
    W2B(wv + (size_t)i*65536, wt_qkv[i] + 131072,   256, 256, 256, 256, 0, s1);
    ucalc_kernel<<<dim3(256), blk, 0, stream>>>(wq + (size_t)i*65536, s1, b1,
        bq + i*256, uqkv[i],       wBqkv[i],       256, 256);
    ucalc_kernel<<<dim3(256), blk, 0, stream>>>(wk + (size_t)i*65536, s1, b1,
        bk + i*256, uqkv[i] + 256, wBqkv[i] + 256, 256, 256);
    ucalc_kernel<<<dim3(256), blk, 0, stream>>>(wv + (size_t)i*65536, s1, b1,
        bv + i*256, uqkv[i] + 512, wBqkv[i] + 512, 256, 256);
    W2B(wo + (size_t)i*65536, wt_o[i],  256, 256, 256, 256, 0, NF);
    W2B(w_mlp1 + (size_t)i*65536, wt_m1[i], 256, 256, 256, 256, 0, ln2_s + i*256);
    ucalc_kernel<<<dim3(256), blk, 0, stream>>>(w_mlp1 + (size_t)i*65536,
        ln2_s + i*256, ln2_b + i*256, b_mlp1 + i*256, um1[i], wBm1[i], 256, 256);
    W2B(w_mlp2 + (size_t)i*65536, wt_m2[i], 256, 256, 256, 256, 0, NF);
    W2B(w_skip + (size_t)i*81664,            wt_sk[i], 63, 256, 64, 320, 0, NF);
    W2B(w_skip + (size_t)i*81664 + 63*256,   wt_sk[i], 256, 256, 256, 320, 64, NF);
  }
  W2B(w_feat, wt_feat, 256, 256, 256, 256, 0, ln_f_s);
  ucalc_kernel<<<dim3(256), blk, 0, stream>>>(w_feat, ln_f_s, ln_f_b, b_feat,
      ufeat, wBfeat, 256, 256);
  W2B(w_rgb1,                wt_rgb1, 256, 128, 256, 288, 0, NF);
  W2B(w_rgb1 + 256*128,      wt_rgb1, 27, 128, 32, 288, 256, NF);
  #undef W2B

  // x = pts @ w_in + b_in -> xr ; x = ln(x) + pe (in place, stats -> A)
  gemm_mfma<0,false,false,false,false><<<g256, blk, 0, stream>>>(pts_b, 64,
      NB, 0, 0, 0, NF, NF, NF, wt_in, 64, b_in,
      xr, 256, 0, 0, 0, NFW, NFW);
  ln_pe_kernel<<<gLN, blk, 0, stream>>>(xr, ln_in_s, ln_in_b, PE, s1A, s2A);

  for (int i = 0; i < 2; i++){
    const int shift = (i == 1) ? 4 : 0;
    const int shiftBack = (i == 1) ? (NSEQ - 4) : 0;

    // zero ln2-stats accumulators
    hipMemsetAsync(s1B, 0, (size_t)2*T_TOK*4, stream);

    // attention, chunked: Q/K/V buffers live inside x2 (3 x 24 MB)
    bf16* qb = x2;
    bf16* kb = x2 + (size_t)CHUNKM * 256;
    bf16* vb = x2 + (size_t)2 * CHUNKM * 256;
    for (int cch = 0; cch < CHUNKS; cch++){
      int base = cch * CHUNKM;
      // fused q|k|v = ln1(roll(x_chunk)) @ wqkv' + wB  (LN folded)
      gemm_mfma<0,true,false,false,false><<<gQKV, blk, 0, stream>>>(xr, 256,
          NB, 0, 0, base, s1A, s2A, uqkv[i], wt_qkv[i], 256, wBqkv[i],
          x2, 256, (size_t)CHUNKM*256, 0, shift, NFW, NFW);
      attn_lite<<<gAttn, blk, 0, stream>>>(qb, kb, vb);
      // x_chunk += roll_back(O) @ wo + bo   (stats -> B)
      gemm_mfma<0,false,true,false,true><<<gC, blk, 0, stream>>>(qb, 256,
          NB, 0, 0, 0, NF, NF, NF, wt_o[i], 256, bo + i*256,
          xr, 256, 0, base, shiftBack, s1B, s2B);
    }

    // FUSED mlp (ln2 folded, stats B): xr += gelu(ln2(xr)@W1+b1)@W2 + b2
    mlp_fused<<<gMLP, blk, 0, stream>>>(xr, s1B, s2B, um1[i],
        wt_m1[i], wBm1[i], wt_m2[i], b_mlp2 + i*256, xr);

    // x = gelu(concat(pts, x) @ w_skip + b_skip) -> x2 (stats -> A), swap
    hipMemsetAsync(s1A, 0, (size_t)2*T_TOK*4, stream);
    gemm_mfma<2,false,false,true,true><<<g256, blk, 0, stream>>>(pts_b, 64,
        xr, 256, 64, 0, NF, NF, NF, wt_sk[i], 320, b_skip + i*256,
        x2, 256, 0, 0, 0, s1A, s2A);
    bf16* tmp = xr; xr = x2; x2 = tmp;
  }

  // head (ln_f from stats A)
  alpha_kernel<<<gStat, blk, 0, stream>>>(xr, s1A, s2A, ln_f_s, ln_f_b,
      w_alpha, b_alpha, out_alpha);
  // feature = ln_f(x) @ w_feat + b_feat -> x2  (LN folded)
  gemm_mfma<0,true,false,false,false><<<g256, blk, 0, stream>>>(xr, 256,
      NB, 0, 0, 0, s1A, s2A, ufeat, wt_feat, 256, wBfeat,
      x2, 256, 0, 0, 0, NFW, NFW);
  // t1 = gelu(concat(feature, views) @ w_rgb1 + b_rgb1) -> xr cols 0..127
  gemm_mfma<3,false,false,true,false><<<g128, blk, 0, stream>>>(x2, 256,
      views_b, 32, 256, 0, NF, NF, NF, wt_rgb1, 288, b_rgb1,
      xr, 256, 0, 0, 0, NFW, NFW);
  rgb2_kernel<<<gStat, blk, 0, stream>>>(xr, w_rgb2, b_rgb2, out_rgb);
}

// Round 13
// 1935.566 us; speedup vs baseline: 1.5031x; 1.0460x over previous
//
#include <hip/hip_runtime.h>
#include <hip/hip_bf16.h>
#include <math.h>

typedef __hip_bfloat16 bf16;
typedef __attribute__((ext_vector_type(8))) short short8;
typedef __attribute__((ext_vector_type(4))) float f32x4;

#define T_TOK 196608   // B*N = 1024*192
#define NSEQ  192
#define DMODEL 256
#define CHUNKS 4
#define CHUNKM (T_TOK/CHUNKS)   // 49152 tokens = 256 sequences

__device__ __forceinline__ float cvt(float v){ return v; }
__device__ __forceinline__ float cvt(bf16 v){ return __bfloat162float(v); }
__device__ __forceinline__ short bfbits(float f){
  bf16 h = __float2bfloat16(f); return *reinterpret_cast<short*>(&h);
}
__device__ __forceinline__ float bfu(unsigned short v){ return __uint_as_float(((unsigned)v) << 16); }

// gelu(tanh approx) == x * sigmoid(2u), u = k0(x+0.044715x^3).
// Uses HW v_exp_f32 instead of libm tanhf (~30 VALU ops -> ~8).
__device__ __forceinline__ float gelu_f(float x){
  const float k0 = 0.7978845608028654f; // sqrt(2/pi)
  float u = k0*(x + 0.044715f*x*x*x);
  return x / (1.f + __expf(-2.f*u));
}

// lgkm-only barrier: ds ops drained, global loads stay IN FLIGHT across it.
// (__syncthreads would emit s_waitcnt vmcnt(0) and kill the A-prefetch.)
__device__ __forceinline__ void barrier_lgkm(){
  asm volatile("s_waitcnt lgkmcnt(0)" ::: "memory");
  __builtin_amdgcn_s_barrier();
  asm volatile("" ::: "memory");
}

// ---- pos-embed table: PE[n][d], n<192 ------------------------------------
__global__ __launch_bounds__(256) void pe_kernel(float* __restrict__ PE){
  int n = blockIdx.x, d = threadIdx.x;
  float e = (float)(2*(d>>1)) / 256.f;
  float ang = (float)n * powf(10000.f, -e);
  PE[n*DMODEL + d] = (d & 1) ? cosf(ang) : sinf(ang);
}

// ---- weight convert+transpose into segment: dst[n*dstStride+kOff+k] ------
// optional scale[k] multiplied in (for LN-fold W' = diag(lnS) @ W)
__global__ __launch_bounds__(256) void w2b_kernel(
    const float* __restrict__ src, bf16* __restrict__ dst,
    int K, int N, int KL, int dstStride, int kOff, const float* __restrict__ scale)
{
  int idx = blockIdx.x*256 + threadIdx.x;
  if (idx >= N*KL) return;
  int n = idx / KL, k = idx - n*KL;
  float v = 0.f;
  if (k < K){
    v = src[(size_t)k*N + n];
    if (scale) v *= scale[k];
  }
  dst[(size_t)n*dstStride + kOff + k] = __float2bfloat16(v);
}

// ---- u[n] = sum_k bf16(lnS[k]*W[k,n]);  wB[n] = sum_k lnB[k]*W[k,n]+bias[n]
// ONE BLOCK PER OUTPUT n (grid=N): wave+LDS reduce over K=256.
__global__ __launch_bounds__(256) void ucalc_kernel(
    const float* __restrict__ W, const float* __restrict__ lnS,
    const float* __restrict__ lnB, const float* __restrict__ bias,
    float* __restrict__ u, float* __restrict__ wB, int K, int N)
{
  __shared__ float pu[4], pb[4];
  const int n = blockIdx.x;
  const int k = threadIdx.x;
  float su = 0.f, sb = 0.f;
  if (k < K){
    float w = W[(size_t)k*N + n];
    su = cvt(__float2bfloat16(lnS[k]*w));   // match MFMA's rounded W'
    sb = lnB[k]*w;
  }
  #pragma unroll
  for (int off = 32; off; off >>= 1){
    su += __shfl_xor(su, off, 64);
    sb += __shfl_xor(sb, off, 64);
  }
  int lane = k & 63, wv = k >> 6;
  if (lane == 0){ pu[wv] = su; pb[wv] = sb; }
  __syncthreads();
  if (k == 0){
    u[n]  = pu[0]+pu[1]+pu[2]+pu[3];
    wB[n] = pb[0]+pb[1]+pb[2]+pb[3] + bias[n];
  }
}

// ---- pts -> bf16 [T][64] zero-padded --------------------------------------
__global__ __launch_bounds__(256) void pts2b_kernel(
    const float* __restrict__ src, bf16* __restrict__ dst)
{
  int idx = blockIdx.x*256 + threadIdx.x;   // T*64
  int t = idx >> 6, k = idx & 63;
  dst[idx] = __float2bfloat16(k < 63 ? src[(size_t)t*63 + k] : 0.f);
}

// ---- views -> bf16 [1024][32] zero-padded ---------------------------------
__global__ __launch_bounds__(256) void views2b_kernel(
    const float* __restrict__ src, bf16* __restrict__ dst)
{
  int idx = blockIdx.x*256 + threadIdx.x;   // 1024*32
  int t = idx >> 5, k = idx & 31;
  dst[idx] = __float2bfloat16(k < 27 ? src[(size_t)t*27 + k] : 0.f);
}

// ---- wave-per-token: x = ln(x)*s+b + PE[n]; writes raw stats (s1=Σy,s2=Σy²)
__global__ __launch_bounds__(256) void ln_pe_kernel(
    bf16* __restrict__ X, const float* __restrict__ s, const float* __restrict__ b,
    const float* __restrict__ PE, float* __restrict__ s1o, float* __restrict__ s2o)
{
  const int lane = threadIdx.x & 63, w = threadIdx.x >> 6;
  const size_t t = (size_t)blockIdx.x * 4 + w;
  const int n = (int)(t % NSEQ);
  const int c = lane * 4;

  ushort4 u = *reinterpret_cast<const ushort4*>(X + t*DMODEL + c);
  float x0 = bfu(u.x), x1 = bfu(u.y), x2 = bfu(u.z), x3 = bfu(u.w);

  float sx = x0 + x1 + x2 + x3;
  float sq = x0*x0 + x1*x1 + x2*x2 + x3*x3;
  #pragma unroll
  for (int off = 32; off; off >>= 1){
    sx += __shfl_xor(sx, off, 64);
    sq += __shfl_xor(sq, off, 64);
  }
  float mean = sx * (1.f/256.f);
  float var  = sq * (1.f/256.f) - mean*mean;
  float rstd = rsqrtf(var + 1e-6f);

  float4 sv = *reinterpret_cast<const float4*>(s + c);
  float4 bv = *reinterpret_cast<const float4*>(b + c);
  float4 pv = *reinterpret_cast<const float4*>(PE + n*DMODEL + c);

  float y0 = (x0 - mean)*rstd*sv.x + bv.x + pv.x;
  float y1 = (x1 - mean)*rstd*sv.y + bv.y + pv.y;
  float y2 = (x2 - mean)*rstd*sv.z + bv.z + pv.z;
  float y3 = (x3 - mean)*rstd*sv.w + bv.w + pv.w;

  ushort4 o;
  o.x = (unsigned short)bfbits(y0);
  o.y = (unsigned short)bfbits(y1);
  o.z = (unsigned short)bfbits(y2);
  o.w = (unsigned short)bfbits(y3);
  *reinterpret_cast<ushort4*>(X + t*DMODEL + c) = o;

  float sy  = y0 + y1 + y2 + y3;
  float syq = y0*y0 + y1*y1 + y2*y2 + y3*y3;
  #pragma unroll
  for (int off = 32; off; off >>= 1){
    sy  += __shfl_xor(sy,  off, 64);
    syq += __shfl_xor(syq, off, 64);
  }
  if (lane == 0){ s1o[t] = sy; s2o[t] = syq; }
}

// ---- MFMA GEMM: C = A @ W, 128x128 tile, 4 waves (R8 = verified optimum) --
// A: LDS double-buffer, 2-deep register prefetch; B loaded in-iteration.
// ONE lgkm-only barrier per k-step; global loads stay in flight across it.
// Cs reuses As LDS after the K-loop (2x5120 < 17408 shorts = 34.8 KB).
// REGISTER BUDGET IS THE BINDING CONSTRAINT (measured): this config = 80
// VGPR -> 30% occ -> 110us. 3-deep A prefetch = 140 VGPR -> 11% -> 199us
// (R9). B ping-pong = 136 VGPR -> 11% -> 197us (R10). launch_bounds(256,4)
// = forced 64 VGPR -> spills -> 1.7GB scratch traffic (R4). DO NOT add
// per-wave latency state; TLP from 4-5 waves/SIMD beats per-wave ILP here.
// MODE 0: plain bf16 A1 (rollShift supported)
// MODE 2: concat: k<SB -> A1[arow][k], else A2[arow][k-SB]    (SB%16==0)
// MODE 3: concat: k<SB -> A1[arow][k], else A2[arow/192][k-SB]
// LNF: C = rstd[m]*acc + (-mu[m]*rstd[m])*u[n] + wB[n]  (weights pre-scaled)
// C cols >=256 map to segment buffers: dst += (n0>>8)*segStride.
// STATS: per-row Σ and Σ² of final C values atomically added to s1o/s2o.
template<int MODE, bool LNF, bool ADD, bool GELU, bool STATS>
__global__ __launch_bounds__(256) void gemm_mfma(
    const bf16* __restrict__ A1, int lda1,
    const bf16* __restrict__ A2, int lda2, int SB, int aOff,
    const float* __restrict__ s1i, const float* __restrict__ s2i,
    const float* __restrict__ uvec,
    const bf16* __restrict__ WT, int Kpad, const float* __restrict__ bias,
    bf16* __restrict__ C, int ldc, size_t segStride, int cOff, int rollShift,
    float* __restrict__ s1o, float* __restrict__ s2o)
{
  __shared__ short buf[17408];    // As0|As1 (2x5120) ∪ Cs (17408) = 34816 B
  short* As0 = buf;
  short* As1 = buf + 5120;
  short* Cs  = buf;
  __shared__ float sScale[128], sAlpha[128];

  const int tid = threadIdx.x;
  const int lane = tid & 63, wid = tid >> 6;
  const int wm = wid >> 1, wn = wid & 1;
  const int col16 = lane & 15, quad = lane >> 4;
  const int sm = tid >> 1, half = tid & 1;   // staging: row, k-half
  const int m0 = blockIdx.y * 128, n0 = blockIdx.x * 128;

  f32x4 acc[4][4];
  #pragma unroll
  for (int i = 0; i < 4; i++)
    #pragma unroll
    for (int j = 0; j < 4; j++) acc[i][j] = (f32x4){0.f,0.f,0.f,0.f};

  // staging source row (rolled)
  int row = m0 + sm;
  if (MODE == 0 && rollShift){
    int bb = row / NSEQ;
    int n  = row - bb*NSEQ;
    n += rollShift; if (n >= NSEQ) n -= NSEQ;
    row = bb*NSEQ + n;
  }
  const size_t arow = (size_t)aOff + row;
  const size_t arow2 = (MODE == 3) ? (arow / NSEQ) : arow;

  // ---- LN-fold per-row scale/alpha (from rolled source row) ----
  if (LNF && tid < 128){
    int r2 = m0 + tid;
    if (rollShift){
      int bb = r2 / NSEQ, n = r2 - bb*NSEQ;
      n += rollShift; if (n >= NSEQ) n -= NSEQ;
      r2 = bb*NSEQ + n;
    }
    size_t r = (size_t)aOff + r2;
    float m1 = s1i[r] * (1.f/256.f);
    float m2 = s2i[r] * (1.f/256.f);
    float rs = rsqrtf(m2 - m1*m1 + 1e-6f);
    sScale[tid] = rs;
    sAlpha[tid] = -m1*rs;
  }

  auto loadA = [&](int k0, uint4& u0, uint4& u1){
    const int gk = k0 + half*16;
    const bf16* src;
    if (MODE == 0) src = A1 + arow*(size_t)lda1 + gk;
    else src = (gk < SB) ? (A1 + arow*(size_t)lda1 + gk)
                         : (A2 + arow2*(size_t)lda2 + (gk - SB));
    u0 = *(const uint4*)(src);
    u1 = *(const uint4*)(src + 8);
  };
  auto writeA = [&](short* dst, const uint4& u0, const uint4& u1){
    *(uint4*)&dst[sm*40 + half*16]     = u0;
    *(uint4*)&dst[sm*40 + half*16 + 8] = u1;
  };

  // ---- prologue: tile 0 -> As0, tile 1 issued ----
  uint4 p0, p1;
  loadA(0, p0, p1);
  writeA(As0, p0, p1);
  if (Kpad > 32) loadA(32, p0, p1);
  barrier_lgkm();

  // ---- pipelined K-loop: ONE lgkm barrier per step ----
  int cur = 0;
  for (int k0 = 0; k0 < Kpad; k0 += 32){
    const short* Asc = cur ? As1 : As0;
    short8 afr[4];
    #pragma unroll
    for (int mi = 0; mi < 4; mi++)
      afr[mi] = *(const short8*)&Asc[(wm*64 + mi*16 + col16)*40 + quad*8];
    short8 bfr[4];
    #pragma unroll
    for (int ni = 0; ni < 4; ni++)
      bfr[ni] = *(const short8*)((const short*)WT
                 + (size_t)(n0 + wn*64 + ni*16 + col16)*Kpad + k0 + quad*8);
    #pragma unroll
    for (int mi = 0; mi < 4; mi++)
      #pragma unroll
      for (int ni = 0; ni < 4; ni++)
        acc[mi][ni] = __builtin_amdgcn_mfma_f32_16x16x32_bf16(
            afr[mi], bfr[ni], acc[mi][ni], 0, 0, 0);
    if (k0 + 32 < Kpad){
      short* Asn = cur ? As0 : As1;
      writeA(Asn, p0, p1);                    // waits vmcnt for tile t+1 only
      if (k0 + 64 < Kpad) loadA(k0+64, p0, p1);  // issue tile t+2
    }
    barrier_lgkm();
    cur ^= 1;
  }

  // ---- epilogue phase 1: acc -> affine/bias (+gelu) -> Cs bf16 ----
  // (last barrier drained all ds reads; As region safe to reuse as Cs)
  #pragma unroll
  for (int ni = 0; ni < 4; ni++){
    int ncol = wn*64 + ni*16 + col16;
    float bv = bias[n0 + ncol];
    float uv = LNF ? uvec[n0 + ncol] : 0.f;
    #pragma unroll
    for (int mi = 0; mi < 4; mi++){
      f32x4 a = acc[mi][ni];
      #pragma unroll
      for (int r = 0; r < 4; r++){
        int lrow = wm*64 + mi*16 + quad*4 + r;
        float val;
        if (LNF) val = sScale[lrow]*a[r] + sAlpha[lrow]*uv + bv;
        else     val = a[r] + bv;
        if (GELU) val = gelu_f(val);
        Cs[lrow*136 + ncol] = bfbits(val);
      }
    }
  }
  __syncthreads();

  // ---- epilogue phase 2: coalesced 16B stores (+ADD) (+STATS) ----
  const int seg = n0 >> 8;
  const int nb  = n0 & 255;
  const int orow = tid >> 4;         // 0..15
  const int ocol = (tid & 15) * 8;   // 0..120
  #pragma unroll
  for (int p = 0; p < 8; p++){
    int lrow = p*16 + orow;
    size_t mrow = (size_t)cOff + m0 + lrow;
    short8 v = *(const short8*)&Cs[lrow*136 + ocol];
    bf16* dst = C + (size_t)seg*segStride + mrow*ldc + nb + ocol;
    float rowSum = 0.f, rowSq = 0.f;
    if (ADD){
      short8 c = *(const short8*)dst;
      short8 o;
      #pragma unroll
      for (int e = 0; e < 8; e++){
        bf16 va, ca;
        *reinterpret_cast<short*>(&va) = v[e];
        *reinterpret_cast<short*>(&ca) = c[e];
        float f = cvt(va) + cvt(ca);
        o[e] = bfbits(f);
        if (STATS){ rowSum += f; rowSq += f*f; }
      }
      *(short8*)dst = o;
    } else {
      if (STATS){
        #pragma unroll
        for (int e = 0; e < 8; e++){
          bf16 va; *reinterpret_cast<short*>(&va) = v[e];
          float f = cvt(va);
          rowSum += f; rowSq += f*f;
        }
      }
      *(short8*)dst = v;
    }
    if (STATS){
      #pragma unroll
      for (int mk = 1; mk <= 8; mk <<= 1){
        rowSum += __shfl_xor(rowSum, mk, 64);
        rowSq  += __shfl_xor(rowSq,  mk, 64);
      }
      if ((tid & 15) == 0){
        atomicAdd(&s1o[mrow], rowSum);
        atomicAdd(&s2o[mrow], rowSq);
      }
    }
  }
}

// ---- FUSED MLP: Y += gelu(ln2(X)@W1 + b1) @ W2 + b2  (64-row tile) --------
// Stage 1: R8-style pipelined K-loop (LDS dbuf As, lgkm barriers), LN folded
//          into pre-scaled W1' + u/wB vectors; gelu -> sT (64x264 bf16 LDS).
// Stage 2: barrier-free K-loop, A-frags ds_read from sT, B = W2 (L2-hot).
// Epilogue: bias + residual-ADD via sT reused as the Cs shuffle buffer.
// LDS UNION (R13): As dbuf (10 KB) lives inside sT's first 10 KB - they are
// disjoint in time (As dead after stage-1's final barrier; sT written after).
// 44.5 -> 34.3 KB => 4 blocks/CU (was 3; VGPR 104 allows exactly 4 w/SIMD).
__global__ __launch_bounds__(256) void mlp_fused(
    const bf16* __restrict__ X,
    const float* __restrict__ s1i, const float* __restrict__ s2i,
    const float* __restrict__ uvec,      // u (col sums of W1')
    const bf16* __restrict__ W1T,        // [256][256] (n,k), pre-scaled
    const float* __restrict__ wB1,       // lnB.W1 + b1
    const bf16* __restrict__ W2T,        // [256][256] (n,k)
    const float* __restrict__ b2,
    bf16* __restrict__ Y)                // in-place: Y == X
{
  __shared__ short sT[64*264];    // 33792 B: As dbuf ∪ gelu(t1) tile ∪ Cs
  short* As0 = sT;                // stage-1 only (first 5120 B)
  short* As1 = sT + 2560;         // stage-1 only (next 5120 B)
  short* Cs  = sT;                // reused after stage-2 reads complete
  __shared__ float sScale[64], sAlpha[64];

  const int tid = threadIdx.x;
  const int lane = tid & 63, wid = tid >> 6;   // wave = 64-col block
  const int col16 = lane & 15, quad = lane >> 4;
  const int qr = tid >> 2, qc = tid & 3;       // staging: row 0-63, 8-chunk
  const int m0 = blockIdx.x * 64;

  // ---- LN-fold per-row factors ----
  if (tid < 64){
    size_t r = (size_t)m0 + tid;
    float m1 = s1i[r] * (1.f/256.f);
    float m2 = s2i[r] * (1.f/256.f);
    float rs = rsqrtf(m2 - m1*m1 + 1e-6f);
    sScale[tid] = rs;
    sAlpha[tid] = -m1*rs;
  }

  const size_t arow = (size_t)m0 + qr;
  auto loadA = [&](int k0, uint4& u){
    u = *(const uint4*)(X + arow*DMODEL + k0 + qc*8);
  };
  auto writeA = [&](short* dst, const uint4& u){
    *(uint4*)&dst[qr*40 + qc*8] = u;
  };

  f32x4 acc[4][4];
  #pragma unroll
  for (int i = 0; i < 4; i++)
    #pragma unroll
    for (int j = 0; j < 4; j++) acc[i][j] = (f32x4){0.f,0.f,0.f,0.f};

  // ---- stage 1: t = LNF(x) @ W1'  (pipelined, one lgkm barrier/step) ----
  uint4 p;
  loadA(0, p); writeA(As0, p);
  loadA(32, p);
  barrier_lgkm();
  int cur = 0;
  for (int k0 = 0; k0 < 256; k0 += 32){
    const short* Asc = cur ? As1 : As0;
    short8 afr[4];
    #pragma unroll
    for (int mi = 0; mi < 4; mi++)
      afr[mi] = *(const short8*)&Asc[(mi*16 + col16)*40 + quad*8];
    short8 bfr[4];
    #pragma unroll
    for (int ni = 0; ni < 4; ni++)
      bfr[ni] = *(const short8*)((const short*)W1T
                 + (size_t)(wid*64 + ni*16 + col16)*256 + k0 + quad*8);
    #pragma unroll
    for (int mi = 0; mi < 4; mi++)
      #pragma unroll
      for (int ni = 0; ni < 4; ni++)
        acc[mi][ni] = __builtin_amdgcn_mfma_f32_16x16x32_bf16(
            afr[mi], bfr[ni], acc[mi][ni], 0, 0, 0);
    if (k0 + 32 < 256){
      short* Asn = cur ? As0 : As1;
      writeA(Asn, p);
      if (k0 + 64 < 256) loadA(k0 + 64, p);
    }
    barrier_lgkm();
    cur ^= 1;
  }
  // final barrier drained all As ds-reads + synced waves: As region is dead,
  // safe for every thread to write sT (which overlaps it) below.

  // ---- affine + gelu -> sT ----
  #pragma unroll
  for (int ni = 0; ni < 4; ni++){
    int ncol = wid*64 + ni*16 + col16;
    float uv = uvec[ncol];
    float bv = wB1[ncol];
    #pragma unroll
    for (int mi = 0; mi < 4; mi++){
      f32x4 a = acc[mi][ni];
      #pragma unroll
      for (int r = 0; r < 4; r++){
        int lrow = mi*16 + quad*4 + r;
        float val = sScale[lrow]*a[r] + sAlpha[lrow]*uv + bv;
        sT[lrow*264 + ncol] = bfbits(gelu_f(val));
      }
    }
  }
  __syncthreads();

  // ---- stage 2: y = t @ W2 (barrier-free; sT read-only) ----
  f32x4 acc2[4][4];
  #pragma unroll
  for (int i = 0; i < 4; i++)
    #pragma unroll
    for (int j = 0; j < 4; j++) acc2[i][j] = (f32x4){0.f,0.f,0.f,0.f};
  for (int k0 = 0; k0 < 256; k0 += 32){
    short8 afr[4];
    #pragma unroll
    for (int mi = 0; mi < 4; mi++)
      afr[mi] = *(const short8*)&sT[(mi*16 + col16)*264 + k0 + quad*8];
    short8 bfr[4];
    #pragma unroll
    for (int ni = 0; ni < 4; ni++)
      bfr[ni] = *(const short8*)((const short*)W2T
                 + (size_t)(wid*64 + ni*16 + col16)*256 + k0 + quad*8);
    #pragma unroll
    for (int mi = 0; mi < 4; mi++)
      #pragma unroll
      for (int ni = 0; ni < 4; ni++)
        acc2[mi][ni] = __builtin_amdgcn_mfma_f32_16x16x32_bf16(
            afr[mi], bfr[ni], acc2[mi][ni], 0, 0, 0);
  }
  __syncthreads();   // all sT reads done -> safe to reuse as Cs

  // ---- epilogue phase 1: acc2 + b2 -> Cs(=sT) bf16 ----
  #pragma unroll
  for (int ni = 0; ni < 4; ni++){
    int ncol = wid*64 + ni*16 + col16;
    float bv = b2[ncol];
    #pragma unroll
    for (int mi = 0; mi < 4; mi++){
      f32x4 a = acc2[mi][ni];
      #pragma unroll
      for (int r = 0; r < 4; r++){
        int lrow = mi*16 + quad*4 + r;
        Cs[lrow*264 + ncol] = bfbits(a[r] + bv);
      }
    }
  }
  __syncthreads();

  // ---- epilogue phase 2: coalesced residual-ADD stores ----
  const int orow = tid >> 5;         // 0..7
  const int oc   = (tid & 31) * 8;   // 0..248
  #pragma unroll
  for (int ppp = 0; ppp < 8; ppp++){
    int lrow = ppp*8 + orow;
    size_t mrow = (size_t)m0 + lrow;
    short8 v = *(const short8*)&Cs[lrow*264 + oc];
    bf16* dst = Y + mrow*DMODEL + oc;
    short8 c = *(const short8*)dst;
    short8 o;
    #pragma unroll
    for (int e = 0; e < 8; e++){
      bf16 va, ca;
      *reinterpret_cast<short*>(&va) = v[e];
      *reinterpret_cast<short*>(&ca) = c[e];
      o[e] = bfbits(cvt(va) + cvt(ca));
    }
    *(short8*)dst = o;
  }
}

// ---- lightweight windowed attention: softmax(QK^T/sqrt(hd)) @ V -----------
__global__ __launch_bounds__(256) void attn_lite(
    bf16* __restrict__ Qg, const bf16* __restrict__ Kg, const bf16* __restrict__ Vg)
{
  __shared__ float qs[8][257], ks[8][257], vs[8][257];
  __shared__ float sc[8][8][8];   // [h][q][k]
  const int c = threadIdx.x;
  const size_t base = (size_t)blockIdx.x * 8 * 256;
  #pragma unroll
  for (int j = 0; j < 8; j++){
    qs[j][c] = cvt(Qg[base + j*256 + c]);
    ks[j][c] = cvt(Kg[base + j*256 + c]);
    vs[j][c] = cvt(Vg[base + j*256 + c]);
  }
  __syncthreads();

  const float scale = 0.17677669529663687f; // 1/sqrt(32)
  #pragma unroll
  for (int r = 0; r < 2; r++){
    int idx = r*256 + c;
    int h = idx >> 6, qi = (idx >> 3) & 7, ki = idx & 7;
    float s = 0.f;
    #pragma unroll
    for (int d = 0; d < 32; d++) s += qs[qi][h*32+d] * ks[ki][h*32+d];
    sc[h][qi][ki] = s * scale;
  }
  __syncthreads();

  if (c < 64){
    int h = c >> 3, qi = c & 7;
    float mx = -1e30f;
    #pragma unroll
    for (int u = 0; u < 8; u++) mx = fmaxf(mx, sc[h][qi][u]);
    float e[8], sum = 0.f;
    #pragma unroll
    for (int u = 0; u < 8; u++){ e[u] = __expf(sc[h][qi][u] - mx); sum += e[u]; }
    float inv = 1.f / sum;
    #pragma unroll
    for (int u = 0; u < 8; u++) sc[h][qi][u] = e[u] * inv;
  }
  __syncthreads();

  {
    int h = c >> 5;
    #pragma unroll
    for (int j = 0; j < 8; j++){
      float o = 0.f;
      #pragma unroll
      for (int u = 0; u < 8; u++) o += sc[h][j][u] * vs[u][c];
      Qg[base + j*256 + c] = __float2bfloat16(o);
    }
  }
}

// ---- alpha head with fused ln_f (raw sums): one wave per token ------------
__global__ __launch_bounds__(256) void alpha_kernel(
    const bf16* __restrict__ X, const float* __restrict__ s1,
    const float* __restrict__ s2, const float* __restrict__ s,
    const float* __restrict__ b, const float* __restrict__ wa,
    const float* __restrict__ ba, float* __restrict__ out)
{
  int lane = threadIdx.x & 63, w = threadIdx.x >> 6;
  size_t t = (size_t)blockIdx.x * 4 + w;
  float m = s1[t] * (1.f/256.f);
  float q = s2[t] * (1.f/256.f);
  float r = rsqrtf(q - m*m + 1e-6f);
  float acc = 0.f;
  #pragma unroll
  for (int j = 0; j < 4; j++){
    int c = lane + 64*j;
    float y = (cvt(X[t*DMODEL + c]) - m) * r * s[c] + b[c];
    acc += y * wa[c];
  }
  #pragma unroll
  for (int off = 32; off; off >>= 1) acc += __shfl_down(acc, off, 64);
  if (lane == 0) out[t] = acc + ba[0];
}

// ---- rgb2: t1 stored with ld=256 (cols 0..127), @ (128,3) + b (f32 out) ---
__global__ __launch_bounds__(256) void rgb2_kernel(
    const bf16* __restrict__ T1, const float* __restrict__ w2,
    const float* __restrict__ b2, float* __restrict__ out)
{
  int lane = threadIdx.x & 63, w = threadIdx.x >> 6;
  size_t t = (size_t)blockIdx.x * 4 + w;
  float h0 = cvt(T1[t*256 + lane]);
  float h1 = cvt(T1[t*256 + 64 + lane]);
  float a0 = h0*w2[lane*3+0] + h1*w2[(lane+64)*3+0];
  float a1 = h0*w2[lane*3+1] + h1*w2[(lane+64)*3+1];
  float a2 = h0*w2[lane*3+2] + h1*w2[(lane+64)*3+2];
  #pragma unroll
  for (int off = 32; off; off >>= 1){
    a0 += __shfl_down(a0, off, 64);
    a1 += __shfl_down(a1, off, 64);
    a2 += __shfl_down(a2, off, 64);
  }
  if (lane == 0){
    out[t*3+0] = a0 + b2[0];
    out[t*3+1] = a1 + b2[1];
    out[t*3+2] = a2 + b2[2];
  }
}

extern "C" void kernel_launch(void* const* d_in, const int* in_sizes, int n_in,
                              void* d_out, int out_size, void* d_ws, size_t ws_size,
                              hipStream_t stream)
{
  (void)in_sizes; (void)n_in; (void)out_size;
  const float* pts     = (const float*)d_in[0];
  const float* views   = (const float*)d_in[1];
  const float* w_in    = (const float*)d_in[2];
  const float* b_in    = (const float*)d_in[3];
  const float* ln_in_s = (const float*)d_in[4];
  const float* ln_in_b = (const float*)d_in[5];
  const float* ln1_s   = (const float*)d_in[6];
  const float* ln1_b   = (const float*)d_in[7];
  const float* wq      = (const float*)d_in[8];
  const float* bq      = (const float*)d_in[9];
  const float* wk      = (const float*)d_in[10];
  const float* bk      = (const float*)d_in[11];
  const float* wv      = (const float*)d_in[12];
  const float* bv      = (const float*)d_in[13];
  const float* wo      = (const float*)d_in[14];
  const float* bo      = (const float*)d_in[15];
  const float* ln2_s   = (const float*)d_in[16];
  const float* ln2_b   = (const float*)d_in[17];
  const float* w_mlp1  = (const float*)d_in[18];
  const float* b_mlp1  = (const float*)d_in[19];
  const float* w_mlp2  = (const float*)d_in[20];
  const float* b_mlp2  = (const float*)d_in[21];
  const float* w_skip  = (const float*)d_in[22];
  const float* b_skip  = (const float*)d_in[23];
  const float* ln_f_s  = (const float*)d_in[24];
  const float* ln_f_b  = (const float*)d_in[25];
  const float* w_alpha = (const float*)d_in[26];
  const float* b_alpha = (const float*)d_in[27];
  const float* w_feat  = (const float*)d_in[28];
  const float* b_feat  = (const float*)d_in[29];
  const float* w_rgb1  = (const float*)d_in[30];
  const float* b_rgb1  = (const float*)d_in[31];
  const float* w_rgb2  = (const float*)d_in[32];
  const float* b_rgb2  = (const float*)d_in[33];

  const size_t SZ = (size_t)T_TOK * DMODEL * 2;        // 100,663,296 B
  const size_t WT_ELEMS = 16384 + 2*(196608 + 3*65536 + 81920) + 65536 + 36864;
  const size_t UV_FLOATS = 2*768*2 + 2*256*2 + 2*256;  // u/wB buffers = 4608
  const size_t NEED = 2*SZ + (size_t)4*T_TOK*4 + NSEQ*DMODEL*4 + UV_FLOATS*4
                    + WT_ELEMS*2 + (size_t)T_TOK*64*2 + 1024*32*2;
  if (ws_size < NEED) return;

  char* wsp = (char*)d_ws;
  bf16* xr = (bf16*)(wsp);
  bf16* x2 = (bf16*)(wsp + SZ);
  float* s1A = (float*)(wsp + 2*SZ);
  float* s2A = s1A + T_TOK;
  float* s1B = s2A + T_TOK;
  float* s2B = s1B + T_TOK;
  float* PE  = s2B + T_TOK;                  // 192*256 floats
  float* uvp = PE + NSEQ*DMODEL;
  float* uqkv[2], *wBqkv[2], *um1[2], *wBm1[2];
  {
    float* q = uvp;
    for (int i = 0; i < 2; i++){ uqkv[i] = q; q += 768; }
    for (int i = 0; i < 2; i++){ wBqkv[i] = q; q += 768; }
    for (int i = 0; i < 2; i++){ um1[i] = q; q += 256; }
    for (int i = 0; i < 2; i++){ wBm1[i] = q; q += 256; }
  }
  float* ufeat  = uvp + 2*768*2 + 2*256*2;
  float* wBfeat = ufeat + 256;
  bf16* wtp = (bf16*)(uvp + UV_FLOATS);

  bf16* wt_in = wtp;                         // 256 x 64
  bf16* wt_qkv[2], *wt_o[2], *wt_m1[2], *wt_m2[2], *wt_sk[2];
  bf16* p = wt_in + 16384;
  for (int i = 0; i < 2; i++){
    wt_qkv[i] = p; p += 196608;              // 768 x 256
    wt_o[i]   = p; p += 65536;
    wt_m1[i]  = p; p += 65536;
    wt_m2[i]  = p; p += 65536;
    wt_sk[i]  = p; p += 81920;               // 256 x 320
  }
  bf16* wt_feat = p; p += 65536;
  bf16* wt_rgb1 = p; p += 36864;             // 128 x 288
  bf16* pts_b   = p; p += (size_t)T_TOK*64;  // T x 64
  bf16* views_b = p; p += 1024*32;

  float* out_rgb   = (float*)d_out;
  float* out_alpha = out_rgb + (size_t)T_TOK * 3;

  dim3 blk(256);
  dim3 g256(2, T_TOK/128);       // full-T, Nc=256
  dim3 gQKV(6, CHUNKM/128);      // chunk, Nc=768
  dim3 gC(2, CHUNKM/128);        // chunk, Nc=256
  dim3 g128(1, T_TOK/128);       // full-T, Nc=128
  dim3 gLN(T_TOK/4);             // wave-per-token LN+PE
  dim3 gMLP(T_TOK/64);           // fused MLP, 64-row tiles
  dim3 gStat(T_TOK/4);
  dim3 gAttn(CHUNKM/8);

  const float* NF = nullptr;
  const bf16*  NB = nullptr;
  float* NFW = nullptr;

  // ---- setup: PE table, pre-convert inputs & weights to bf16, u/wB ----
  pe_kernel<<<dim3(NSEQ), blk, 0, stream>>>(PE);
  pts2b_kernel<<<dim3(T_TOK*64/256), blk, 0, stream>>>(pts, pts_b);
  views2b_kernel<<<dim3(1024*32/256), blk, 0, stream>>>(views, views_b);
  #define W2B(src, dst, K_, N_, KL_, ST_, KO_, SC_) \
    w2b_kernel<<<dim3(((N_)*(KL_)+255)/256), blk, 0, stream>>>(src, dst, K_, N_, KL_, ST_, KO_, SC_)
  W2B(w_in, wt_in, 63, 256, 64, 64, 0, NF);
  for (int i = 0; i < 2; i++){
    const float* s1 = ln1_s + i*256;
    const float* b1 = ln1_b + i*256;
    W2B(wq + (size_t)i*65536, wt_qkv[i],            256, 256, 256, 256, 0, s1);
    W2B(wk + (size_t)i*65536, wt_qkv[i] + 65536,    256, 256, 256, 256, 0, s1);
    W2B(wv + (size_t)i*65536, wt_qkv[i] + 131072,   256, 256, 256, 256, 0, s1);
    ucalc_kernel<<<dim3(256), blk, 0, stream>>>(wq + (size_t)i*65536, s1, b1,
        bq + i*256, uqkv[i],       wBqkv[i],       256, 256);
    ucalc_kernel<<<dim3(256), blk, 0, stream>>>(wk + (size_t)i*65536, s1, b1,
        bk + i*256, uqkv[i] + 256, wBqkv[i] + 256, 256, 256);
    ucalc_kernel<<<dim3(256), blk, 0, stream>>>(wv + (size_t)i*65536, s1, b1,
        bv + i*256, uqkv[i] + 512, wBqkv[i] + 512, 256, 256);
    W2B(wo + (size_t)i*65536, wt_o[i],  256, 256, 256, 256, 0, NF);
    W2B(w_mlp1 + (size_t)i*65536, wt_m1[i], 256, 256, 256, 256, 0, ln2_s + i*256);
    ucalc_kernel<<<dim3(256), blk, 0, stream>>>(w_mlp1 + (size_t)i*65536,
        ln2_s + i*256, ln2_b + i*256, b_mlp1 + i*256, um1[i], wBm1[i], 256, 256);
    W2B(w_mlp2 + (size_t)i*65536, wt_m2[i], 256, 256, 256, 256, 0, NF);
    W2B(w_skip + (size_t)i*81664,            wt_sk[i], 63, 256, 64, 320, 0, NF);
    W2B(w_skip + (size_t)i*81664 + 63*256,   wt_sk[i], 256, 256, 256, 320, 64, NF);
  }
  W2B(w_feat, wt_feat, 256, 256, 256, 256, 0, ln_f_s);
  ucalc_kernel<<<dim3(256), blk, 0, stream>>>(w_feat, ln_f_s, ln_f_b, b_feat,
      ufeat, wBfeat, 256, 256);
  W2B(w_rgb1,                wt_rgb1, 256, 128, 256, 288, 0, NF);
  W2B(w_rgb1 + 256*128,      wt_rgb1, 27, 128, 32, 288, 256, NF);
  #undef W2B

  // x = pts @ w_in + b_in -> xr ; x = ln(x) + pe (in place, stats -> A)
  gemm_mfma<0,false,false,false,false><<<g256, blk, 0, stream>>>(pts_b, 64,
      NB, 0, 0, 0, NF, NF, NF, wt_in, 64, b_in,
      xr, 256, 0, 0, 0, NFW, NFW);
  ln_pe_kernel<<<gLN, blk, 0, stream>>>(xr, ln_in_s, ln_in_b, PE, s1A, s2A);

  for (int i = 0; i < 2; i++){
    const int shift = (i == 1) ? 4 : 0;
    const int shiftBack = (i == 1) ? (NSEQ - 4) : 0;

    // zero ln2-stats accumulators
    hipMemsetAsync(s1B, 0, (size_t)2*T_TOK*4, stream);

    // attention, chunked: Q/K/V buffers live inside x2 (3 x 24 MB)
    bf16* qb = x2;
    bf16* kb = x2 + (size_t)CHUNKM * 256;
    bf16* vb = x2 + (size_t)2 * CHUNKM * 256;
    for (int cch = 0; cch < CHUNKS; cch++){
      int base = cch * CHUNKM;
      // fused q|k|v = ln1(roll(x_chunk)) @ wqkv' + wB  (LN folded)
      gemm_mfma<0,true,false,false,false><<<gQKV, blk, 0, stream>>>(xr, 256,
          NB, 0, 0, base, s1A, s2A, uqkv[i], wt_qkv[i], 256, wBqkv[i],
          x2, 256, (size_t)CHUNKM*256, 0, shift, NFW, NFW);
      attn_lite<<<gAttn, blk, 0, stream>>>(qb, kb, vb);
      // x_chunk += roll_back(O) @ wo + bo   (stats -> B)
      gemm_mfma<0,false,true,false,true><<<gC, blk, 0, stream>>>(qb, 256,
          NB, 0, 0, 0, NF, NF, NF, wt_o[i], 256, bo + i*256,
          xr, 256, 0, base, shiftBack, s1B, s2B);
    }

    // FUSED mlp (ln2 folded, stats B): xr += gelu(ln2(xr)@W1+b1)@W2 + b2
    mlp_fused<<<gMLP, blk, 0, stream>>>(xr, s1B, s2B, um1[i],
        wt_m1[i], wBm1[i], wt_m2[i], b_mlp2 + i*256, xr);

    // x = gelu(concat(pts, x) @ w_skip + b_skip) -> x2 (stats -> A), swap
    hipMemsetAsync(s1A, 0, (size_t)2*T_TOK*4, stream);
    gemm_mfma<2,false,false,true,true><<<g256, blk, 0, stream>>>(pts_b, 64,
        xr, 256, 64, 0, NF, NF, NF, wt_sk[i], 320, b_skip + i*256,
        x2, 256, 0, 0, 0, s1A, s2A);
    bf16* tmp = xr; xr = x2; x2 = tmp;
  }

  // head (ln_f from stats A)
  alpha_kernel<<<gStat, blk, 0, stream>>>(xr, s1A, s2A, ln_f_s, ln_f_b,
      w_alpha, b_alpha, out_alpha);
  // feature = ln_f(x) @ w_feat + b_feat -> x2  (LN folded)
  gemm_mfma<0,true,false,false,false><<<g256, blk, 0, stream>>>(xr, 256,
      NB, 0, 0, 0, s1A, s2A, ufeat, wt_feat, 256, wBfeat,
      x2, 256, 0, 0, 0, NFW, NFW);
  // t1 = gelu(concat(feature, views) @ w_rgb1 + b_rgb1) -> xr cols 0..127
  gemm_mfma<3,false,false,true,false><<<g128, blk, 0, stream>>>(x2, 256,
      views_b, 32, 256, 0, NF, NF, NF, wt_rgb1, 288, b_rgb1,
      xr, 256, 0, 0, 0, NFW, NFW);
  rgb2_kernel<<<gStat, blk, 0, stream>>>(xr, w_rgb2, b_rgb2, out_rgb);
}

// Round 14
// 1905.416 us; speedup vs baseline: 1.5269x; 1.0158x over previous
//
#include <hip/hip_runtime.h>
#include <hip/hip_bf16.h>
#include <math.h>

typedef __hip_bfloat16 bf16;
typedef __attribute__((ext_vector_type(8))) short short8;
typedef __attribute__((ext_vector_type(4))) float f32x4;

#define T_TOK 196608   // B*N = 1024*192
#define NSEQ  192
#define DMODEL 256
#define CHUNKS 4
#define CHUNKM (T_TOK/CHUNKS)   // 49152 tokens = 256 sequences

__device__ __forceinline__ float cvt(float v){ return v; }
__device__ __forceinline__ float cvt(bf16 v){ return __bfloat162float(v); }
__device__ __forceinline__ short bfbits(float f){
  bf16 h = __float2bfloat16(f); return *reinterpret_cast<short*>(&h);
}
__device__ __forceinline__ float bfu(unsigned short v){ return __uint_as_float(((unsigned)v) << 16); }

// gelu(tanh approx) == x * sigmoid(2u), u = k0(x+0.044715x^3).
// Uses HW v_exp_f32 instead of libm tanhf (~30 VALU ops -> ~8).
__device__ __forceinline__ float gelu_f(float x){
  const float k0 = 0.7978845608028654f; // sqrt(2/pi)
  float u = k0*(x + 0.044715f*x*x*x);
  return x / (1.f + __expf(-2.f*u));
}

// lgkm-only barrier: ds ops drained, global loads stay IN FLIGHT across it.
// (__syncthreads would emit s_waitcnt vmcnt(0) and kill the A-prefetch.)
__device__ __forceinline__ void barrier_lgkm(){
  asm volatile("s_waitcnt lgkmcnt(0)" ::: "memory");
  __builtin_amdgcn_s_barrier();
  asm volatile("" ::: "memory");
}

// ---- pos-embed table: PE[n][d], n<192 ------------------------------------
__global__ __launch_bounds__(256) void pe_kernel(float* __restrict__ PE){
  int n = blockIdx.x, d = threadIdx.x;
  float e = (float)(2*(d>>1)) / 256.f;
  float ang = (float)n * powf(10000.f, -e);
  PE[n*DMODEL + d] = (d & 1) ? cosf(ang) : sinf(ang);
}

// ---- weight convert+transpose into segment: dst[n*dstStride+kOff+k] ------
// optional scale[k] multiplied in (for LN-fold W' = diag(lnS) @ W)
__global__ __launch_bounds__(256) void w2b_kernel(
    const float* __restrict__ src, bf16* __restrict__ dst,
    int K, int N, int KL, int dstStride, int kOff, const float* __restrict__ scale)
{
  int idx = blockIdx.x*256 + threadIdx.x;
  if (idx >= N*KL) return;
  int n = idx / KL, k = idx - n*KL;
  float v = 0.f;
  if (k < K){
    v = src[(size_t)k*N + n];
    if (scale) v *= scale[k];
  }
  dst[(size_t)n*dstStride + kOff + k] = __float2bfloat16(v);
}

// ---- u[n] = sum_k bf16(lnS[k]*W[k,n]);  wB[n] = sum_k lnB[k]*W[k,n]+bias[n]
// ONE BLOCK PER OUTPUT n (grid=N): wave+LDS reduce over K=256.
__global__ __launch_bounds__(256) void ucalc_kernel(
    const float* __restrict__ W, const float* __restrict__ lnS,
    const float* __restrict__ lnB, const float* __restrict__ bias,
    float* __restrict__ u, float* __restrict__ wB, int K, int N)
{
  __shared__ float pu[4], pb[4];
  const int n = blockIdx.x;
  const int k = threadIdx.x;
  float su = 0.f, sb = 0.f;
  if (k < K){
    float w = W[(size_t)k*N + n];
    su = cvt(__float2bfloat16(lnS[k]*w));   // match MFMA's rounded W'
    sb = lnB[k]*w;
  }
  #pragma unroll
  for (int off = 32; off; off >>= 1){
    su += __shfl_xor(su, off, 64);
    sb += __shfl_xor(sb, off, 64);
  }
  int lane = k & 63, wv = k >> 6;
  if (lane == 0){ pu[wv] = su; pb[wv] = sb; }
  __syncthreads();
  if (k == 0){
    u[n]  = pu[0]+pu[1]+pu[2]+pu[3];
    wB[n] = pb[0]+pb[1]+pb[2]+pb[3] + bias[n];
  }
}

// ---- pts -> bf16 [T][64] zero-padded --------------------------------------
__global__ __launch_bounds__(256) void pts2b_kernel(
    const float* __restrict__ src, bf16* __restrict__ dst)
{
  int idx = blockIdx.x*256 + threadIdx.x;   // T*64
  int t = idx >> 6, k = idx & 63;
  dst[idx] = __float2bfloat16(k < 63 ? src[(size_t)t*63 + k] : 0.f);
}

// ---- views -> bf16 [1024][32] zero-padded ---------------------------------
__global__ __launch_bounds__(256) void views2b_kernel(
    const float* __restrict__ src, bf16* __restrict__ dst)
{
  int idx = blockIdx.x*256 + threadIdx.x;   // 1024*32
  int t = idx >> 5, k = idx & 31;
  dst[idx] = __float2bfloat16(k < 27 ? src[(size_t)t*27 + k] : 0.f);
}

// ---- wave-per-token: x = ln(x)*s+b + PE[n]; writes raw stats (s1=Σy,s2=Σy²)
__global__ __launch_bounds__(256) void ln_pe_kernel(
    bf16* __restrict__ X, const float* __restrict__ s, const float* __restrict__ b,
    const float* __restrict__ PE, float* __restrict__ s1o, float* __restrict__ s2o)
{
  const int lane = threadIdx.x & 63, w = threadIdx.x >> 6;
  const size_t t = (size_t)blockIdx.x * 4 + w;
  const int n = (int)(t % NSEQ);
  const int c = lane * 4;

  ushort4 u = *reinterpret_cast<const ushort4*>(X + t*DMODEL + c);
  float x0 = bfu(u.x), x1 = bfu(u.y), x2 = bfu(u.z), x3 = bfu(u.w);

  float sx = x0 + x1 + x2 + x3;
  float sq = x0*x0 + x1*x1 + x2*x2 + x3*x3;
  #pragma unroll
  for (int off = 32; off; off >>= 1){
    sx += __shfl_xor(sx, off, 64);
    sq += __shfl_xor(sq, off, 64);
  }
  float mean = sx * (1.f/256.f);
  float var  = sq * (1.f/256.f) - mean*mean;
  float rstd = rsqrtf(var + 1e-6f);

  float4 sv = *reinterpret_cast<const float4*>(s + c);
  float4 bv = *reinterpret_cast<const float4*>(b + c);
  float4 pv = *reinterpret_cast<const float4*>(PE + n*DMODEL + c);

  float y0 = (x0 - mean)*rstd*sv.x + bv.x + pv.x;
  float y1 = (x1 - mean)*rstd*sv.y + bv.y + pv.y;
  float y2 = (x2 - mean)*rstd*sv.z + bv.z + pv.z;
  float y3 = (x3 - mean)*rstd*sv.w + bv.w + pv.w;

  ushort4 o;
  o.x = (unsigned short)bfbits(y0);
  o.y = (unsigned short)bfbits(y1);
  o.z = (unsigned short)bfbits(y2);
  o.w = (unsigned short)bfbits(y3);
  *reinterpret_cast<ushort4*>(X + t*DMODEL + c) = o;

  float sy  = y0 + y1 + y2 + y3;
  float syq = y0*y0 + y1*y1 + y2*y2 + y3*y3;
  #pragma unroll
  for (int off = 32; off; off >>= 1){
    sy  += __shfl_xor(sy,  off, 64);
    syq += __shfl_xor(syq, off, 64);
  }
  if (lane == 0){ s1o[t] = sy; s2o[t] = syq; }
}

// ---- MFMA GEMM: C = A @ W, 128x128 tile, 4 waves (R8 = verified optimum) --
// A: LDS double-buffer, 2-deep register prefetch; B loaded in-iteration.
// ONE lgkm-only barrier per k-step; global loads stay in flight across it.
// Cs reuses As LDS after the K-loop (2x5120 < 17408 shorts = 34.8 KB).
// REGISTER BUDGET IS THE BINDING CONSTRAINT (measured): this config = 80
// VGPR -> 30% occ -> 110us. 3-deep A prefetch = 140 VGPR -> 11% -> 199us
// (R9). B ping-pong = 136 VGPR -> 11% -> 197us (R10). launch_bounds(256,4)
// = forced 64 VGPR -> spills -> 1.7GB scratch traffic (R4). DO NOT add
// per-wave latency state; TLP from 4-5 waves/SIMD beats per-wave ILP here.
// MODE 0: plain bf16 A1 (rollShift supported)
// MODE 2: concat: k<SB -> A1[arow][k], else A2[arow][k-SB]    (SB%16==0)
// MODE 3: concat: k<SB -> A1[arow][k], else A2[arow/192][k-SB]
// LNF: C = rstd[m]*acc + (-mu[m]*rstd[m])*u[n] + wB[n]  (weights pre-scaled)
// C cols >=256 map to segment buffers: dst += (n0>>8)*segStride.
// STATS: per-row Σ and Σ² of final C values atomically added to s1o/s2o.
template<int MODE, bool LNF, bool ADD, bool GELU, bool STATS>
__global__ __launch_bounds__(256) void gemm_mfma(
    const bf16* __restrict__ A1, int lda1,
    const bf16* __restrict__ A2, int lda2, int SB, int aOff,
    const float* __restrict__ s1i, const float* __restrict__ s2i,
    const float* __restrict__ uvec,
    const bf16* __restrict__ WT, int Kpad, const float* __restrict__ bias,
    bf16* __restrict__ C, int ldc, size_t segStride, int cOff, int rollShift,
    float* __restrict__ s1o, float* __restrict__ s2o)
{
  __shared__ short buf[17408];    // As0|As1 (2x5120) ∪ Cs (17408) = 34816 B
  short* As0 = buf;
  short* As1 = buf + 5120;
  short* Cs  = buf;
  __shared__ float sScale[128], sAlpha[128];

  const int tid = threadIdx.x;
  const int lane = tid & 63, wid = tid >> 6;
  const int wm = wid >> 1, wn = wid & 1;
  const int col16 = lane & 15, quad = lane >> 4;
  const int sm = tid >> 1, half = tid & 1;   // staging: row, k-half
  const int m0 = blockIdx.y * 128, n0 = blockIdx.x * 128;

  f32x4 acc[4][4];
  #pragma unroll
  for (int i = 0; i < 4; i++)
    #pragma unroll
    for (int j = 0; j < 4; j++) acc[i][j] = (f32x4){0.f,0.f,0.f,0.f};

  // staging source row (rolled)
  int row = m0 + sm;
  if (MODE == 0 && rollShift){
    int bb = row / NSEQ;
    int n  = row - bb*NSEQ;
    n += rollShift; if (n >= NSEQ) n -= NSEQ;
    row = bb*NSEQ + n;
  }
  const size_t arow = (size_t)aOff + row;
  const size_t arow2 = (MODE == 3) ? (arow / NSEQ) : arow;

  // ---- LN-fold per-row scale/alpha (from rolled source row) ----
  if (LNF && tid < 128){
    int r2 = m0 + tid;
    if (rollShift){
      int bb = r2 / NSEQ, n = r2 - bb*NSEQ;
      n += rollShift; if (n >= NSEQ) n -= NSEQ;
      r2 = bb*NSEQ + n;
    }
    size_t r = (size_t)aOff + r2;
    float m1 = s1i[r] * (1.f/256.f);
    float m2 = s2i[r] * (1.f/256.f);
    float rs = rsqrtf(m2 - m1*m1 + 1e-6f);
    sScale[tid] = rs;
    sAlpha[tid] = -m1*rs;
  }

  auto loadA = [&](int k0, uint4& u0, uint4& u1){
    const int gk = k0 + half*16;
    const bf16* src;
    if (MODE == 0) src = A1 + arow*(size_t)lda1 + gk;
    else src = (gk < SB) ? (A1 + arow*(size_t)lda1 + gk)
                         : (A2 + arow2*(size_t)lda2 + (gk - SB));
    u0 = *(const uint4*)(src);
    u1 = *(const uint4*)(src + 8);
  };
  auto writeA = [&](short* dst, const uint4& u0, const uint4& u1){
    *(uint4*)&dst[sm*40 + half*16]     = u0;
    *(uint4*)&dst[sm*40 + half*16 + 8] = u1;
  };

  // ---- prologue: tile 0 -> As0, tile 1 issued ----
  uint4 p0, p1;
  loadA(0, p0, p1);
  writeA(As0, p0, p1);
  if (Kpad > 32) loadA(32, p0, p1);
  barrier_lgkm();

  // ---- pipelined K-loop: ONE lgkm barrier per step ----
  int cur = 0;
  for (int k0 = 0; k0 < Kpad; k0 += 32){
    const short* Asc = cur ? As1 : As0;
    short8 afr[4];
    #pragma unroll
    for (int mi = 0; mi < 4; mi++)
      afr[mi] = *(const short8*)&Asc[(wm*64 + mi*16 + col16)*40 + quad*8];
    short8 bfr[4];
    #pragma unroll
    for (int ni = 0; ni < 4; ni++)
      bfr[ni] = *(const short8*)((const short*)WT
                 + (size_t)(n0 + wn*64 + ni*16 + col16)*Kpad + k0 + quad*8);
    #pragma unroll
    for (int mi = 0; mi < 4; mi++)
      #pragma unroll
      for (int ni = 0; ni < 4; ni++)
        acc[mi][ni] = __builtin_amdgcn_mfma_f32_16x16x32_bf16(
            afr[mi], bfr[ni], acc[mi][ni], 0, 0, 0);
    if (k0 + 32 < Kpad){
      short* Asn = cur ? As0 : As1;
      writeA(Asn, p0, p1);                    // waits vmcnt for tile t+1 only
      if (k0 + 64 < Kpad) loadA(k0+64, p0, p1);  // issue tile t+2
    }
    barrier_lgkm();
    cur ^= 1;
  }

  // ---- epilogue phase 1: acc -> affine/bias (+gelu) -> Cs bf16 ----
  // (last barrier drained all ds reads; As region safe to reuse as Cs)
  #pragma unroll
  for (int ni = 0; ni < 4; ni++){
    int ncol = wn*64 + ni*16 + col16;
    float bv = bias[n0 + ncol];
    float uv = LNF ? uvec[n0 + ncol] : 0.f;
    #pragma unroll
    for (int mi = 0; mi < 4; mi++){
      f32x4 a = acc[mi][ni];
      #pragma unroll
      for (int r = 0; r < 4; r++){
        int lrow = wm*64 + mi*16 + quad*4 + r;
        float val;
        if (LNF) val = sScale[lrow]*a[r] + sAlpha[lrow]*uv + bv;
        else     val = a[r] + bv;
        if (GELU) val = gelu_f(val);
        Cs[lrow*136 + ncol] = bfbits(val);
      }
    }
  }
  __syncthreads();

  // ---- epilogue phase 2: coalesced 16B stores (+ADD) (+STATS) ----
  const int seg = n0 >> 8;
  const int nb  = n0 & 255;
  const int orow = tid >> 4;         // 0..15
  const int ocol = (tid & 15) * 8;   // 0..120
  #pragma unroll
  for (int p = 0; p < 8; p++){
    int lrow = p*16 + orow;
    size_t mrow = (size_t)cOff + m0 + lrow;
    short8 v = *(const short8*)&Cs[lrow*136 + ocol];
    bf16* dst = C + (size_t)seg*segStride + mrow*ldc + nb + ocol;
    float rowSum = 0.f, rowSq = 0.f;
    if (ADD){
      short8 c = *(const short8*)dst;
      short8 o;
      #pragma unroll
      for (int e = 0; e < 8; e++){
        bf16 va, ca;
        *reinterpret_cast<short*>(&va) = v[e];
        *reinterpret_cast<short*>(&ca) = c[e];
        float f = cvt(va) + cvt(ca);
        o[e] = bfbits(f);
        if (STATS){ rowSum += f; rowSq += f*f; }
      }
      *(short8*)dst = o;
    } else {
      if (STATS){
        #pragma unroll
        for (int e = 0; e < 8; e++){
          bf16 va; *reinterpret_cast<short*>(&va) = v[e];
          float f = cvt(va);
          rowSum += f; rowSq += f*f;
        }
      }
      *(short8*)dst = v;
    }
    if (STATS){
      #pragma unroll
      for (int mk = 1; mk <= 8; mk <<= 1){
        rowSum += __shfl_xor(rowSum, mk, 64);
        rowSq  += __shfl_xor(rowSq,  mk, 64);
      }
      if ((tid & 15) == 0){
        atomicAdd(&s1o[mrow], rowSum);
        atomicAdd(&s2o[mrow], rowSq);
      }
    }
  }
}

// ---- FUSED MLP: Y += gelu(ln2(X)@W1 + b1) @ W2 + b2  (64-row tile) --------
// Stage 1: R8-style pipelined K-loop (LDS dbuf As, lgkm barriers), LN folded
//          into pre-scaled W1' + u/wB vectors; gelu -> sT (64x264 bf16 LDS).
// Stage 2: barrier-free K-loop, A-frags ds_read from sT, B = W2 (L2-hot).
// Epilogue: bias + residual-ADD via sT reused as the Cs shuffle buffer.
// LDS UNION (R13): As dbuf (10 KB) lives inside sT's first 10 KB - they are
// disjoint in time (As dead after stage-1's final barrier; sT written after).
// 44.5 -> 34.3 KB => 4 blocks/CU: R13 measured 176 -> 150us from this alone.
__global__ __launch_bounds__(256) void mlp_fused(
    const bf16* __restrict__ X,
    const float* __restrict__ s1i, const float* __restrict__ s2i,
    const float* __restrict__ uvec,      // u (col sums of W1')
    const bf16* __restrict__ W1T,        // [256][256] (n,k), pre-scaled
    const float* __restrict__ wB1,       // lnB.W1 + b1
    const bf16* __restrict__ W2T,        // [256][256] (n,k)
    const float* __restrict__ b2,
    bf16* __restrict__ Y)                // in-place: Y == X
{
  __shared__ short sT[64*264];    // 33792 B: As dbuf ∪ gelu(t1) tile ∪ Cs
  short* As0 = sT;                // stage-1 only (first 5120 B)
  short* As1 = sT + 2560;         // stage-1 only (next 5120 B)
  short* Cs  = sT;                // reused after stage-2 reads complete
  __shared__ float sScale[64], sAlpha[64];

  const int tid = threadIdx.x;
  const int lane = tid & 63, wid = tid >> 6;   // wave = 64-col block
  const int col16 = lane & 15, quad = lane >> 4;
  const int qr = tid >> 2, qc = tid & 3;       // staging: row 0-63, 8-chunk
  const int m0 = blockIdx.x * 64;

  // ---- LN-fold per-row factors ----
  if (tid < 64){
    size_t r = (size_t)m0 + tid;
    float m1 = s1i[r] * (1.f/256.f);
    float m2 = s2i[r] * (1.f/256.f);
    float rs = rsqrtf(m2 - m1*m1 + 1e-6f);
    sScale[tid] = rs;
    sAlpha[tid] = -m1*rs;
  }

  const size_t arow = (size_t)m0 + qr;
  auto loadA = [&](int k0, uint4& u){
    u = *(const uint4*)(X + arow*DMODEL + k0 + qc*8);
  };
  auto writeA = [&](short* dst, const uint4& u){
    *(uint4*)&dst[qr*40 + qc*8] = u;
  };

  f32x4 acc[4][4];
  #pragma unroll
  for (int i = 0; i < 4; i++)
    #pragma unroll
    for (int j = 0; j < 4; j++) acc[i][j] = (f32x4){0.f,0.f,0.f,0.f};

  // ---- stage 1: t = LNF(x) @ W1'  (pipelined, one lgkm barrier/step) ----
  uint4 p;
  loadA(0, p); writeA(As0, p);
  loadA(32, p);
  barrier_lgkm();
  int cur = 0;
  for (int k0 = 0; k0 < 256; k0 += 32){
    const short* Asc = cur ? As1 : As0;
    short8 afr[4];
    #pragma unroll
    for (int mi = 0; mi < 4; mi++)
      afr[mi] = *(const short8*)&Asc[(mi*16 + col16)*40 + quad*8];
    short8 bfr[4];
    #pragma unroll
    for (int ni = 0; ni < 4; ni++)
      bfr[ni] = *(const short8*)((const short*)W1T
                 + (size_t)(wid*64 + ni*16 + col16)*256 + k0 + quad*8);
    #pragma unroll
    for (int mi = 0; mi < 4; mi++)
      #pragma unroll
      for (int ni = 0; ni < 4; ni++)
        acc[mi][ni] = __builtin_amdgcn_mfma_f32_16x16x32_bf16(
            afr[mi], bfr[ni], acc[mi][ni], 0, 0, 0);
    if (k0 + 32 < 256){
      short* Asn = cur ? As0 : As1;
      writeA(Asn, p);
      if (k0 + 64 < 256) loadA(k0 + 64, p);
    }
    barrier_lgkm();
    cur ^= 1;
  }
  // final barrier drained all As ds-reads + synced waves: As region is dead,
  // safe for every thread to write sT (which overlaps it) below.

  // ---- affine + gelu -> sT ----
  #pragma unroll
  for (int ni = 0; ni < 4; ni++){
    int ncol = wid*64 + ni*16 + col16;
    float uv = uvec[ncol];
    float bv = wB1[ncol];
    #pragma unroll
    for (int mi = 0; mi < 4; mi++){
      f32x4 a = acc[mi][ni];
      #pragma unroll
      for (int r = 0; r < 4; r++){
        int lrow = mi*16 + quad*4 + r;
        float val = sScale[lrow]*a[r] + sAlpha[lrow]*uv + bv;
        sT[lrow*264 + ncol] = bfbits(gelu_f(val));
      }
    }
  }
  __syncthreads();

  // ---- stage 2: y = t @ W2 (barrier-free; sT read-only) ----
  f32x4 acc2[4][4];
  #pragma unroll
  for (int i = 0; i < 4; i++)
    #pragma unroll
    for (int j = 0; j < 4; j++) acc2[i][j] = (f32x4){0.f,0.f,0.f,0.f};
  for (int k0 = 0; k0 < 256; k0 += 32){
    short8 afr[4];
    #pragma unroll
    for (int mi = 0; mi < 4; mi++)
      afr[mi] = *(const short8*)&sT[(mi*16 + col16)*264 + k0 + quad*8];
    short8 bfr[4];
    #pragma unroll
    for (int ni = 0; ni < 4; ni++)
      bfr[ni] = *(const short8*)((const short*)W2T
                 + (size_t)(wid*64 + ni*16 + col16)*256 + k0 + quad*8);
    #pragma unroll
    for (int mi = 0; mi < 4; mi++)
      #pragma unroll
      for (int ni = 0; ni < 4; ni++)
        acc2[mi][ni] = __builtin_amdgcn_mfma_f32_16x16x32_bf16(
            afr[mi], bfr[ni], acc2[mi][ni], 0, 0, 0);
  }
  __syncthreads();   // all sT reads done -> safe to reuse as Cs

  // ---- epilogue phase 1: acc2 + b2 -> Cs(=sT) bf16 ----
  #pragma unroll
  for (int ni = 0; ni < 4; ni++){
    int ncol = wid*64 + ni*16 + col16;
    float bv = b2[ncol];
    #pragma unroll
    for (int mi = 0; mi < 4; mi++){
      f32x4 a = acc2[mi][ni];
      #pragma unroll
      for (int r = 0; r < 4; r++){
        int lrow = mi*16 + quad*4 + r;
        Cs[lrow*264 + ncol] = bfbits(a[r] + bv);
      }
    }
  }
  __syncthreads();

  // ---- epilogue phase 2: coalesced residual-ADD stores ----
  const int orow = tid >> 5;         // 0..7
  const int oc   = (tid & 31) * 8;   // 0..248
  #pragma unroll
  for (int ppp = 0; ppp < 8; ppp++){
    int lrow = ppp*8 + orow;
    size_t mrow = (size_t)m0 + lrow;
    short8 v = *(const short8*)&Cs[lrow*264 + oc];
    bf16* dst = Y + mrow*DMODEL + oc;
    short8 c = *(const short8*)dst;
    short8 o;
    #pragma unroll
    for (int e = 0; e < 8; e++){
      bf16 va, ca;
      *reinterpret_cast<short*>(&va) = v[e];
      *reinterpret_cast<short*>(&ca) = c[e];
      o[e] = bfbits(cvt(va) + cvt(ca));
    }
    *(short8*)dst = o;
  }
}

// ---- windowed attention: 16 tokens (2 windows) per block, vectorized ------
// Q/K/V staged bf16 via coalesced short8 loads (512B contiguous per wave
// instruction; old version used scalar 2B loads + f32 LDS = Common-mistake
// #2).  Scores+softmax: 128 threads own one (win,h,q) row fully in regs.
// PV: 256 threads (one column each); O overwrites dead Qs region; coalesced
// short8 store-back.  LDS 29.3 KB -> 5 blocks/CU.
__global__ __launch_bounds__(256) void attn_lite(
    bf16* __restrict__ Qg, const bf16* __restrict__ Kg, const bf16* __restrict__ Vg)
{
  __shared__ short Qs[16*264], Ks[16*264], Vs[16*264];  // 25.3 KB
  __shared__ float sc[2*8*8*8];                         // [win][qi][h][k] 4 KB
  const int tid = threadIdx.x;
  const size_t base = (size_t)blockIdx.x * 16 * 256;

  // ---- load Q,K,V tiles (16x256 bf16), fully coalesced short8 ----
  #pragma unroll
  for (int it = 0; it < 2; it++){
    int c = it*256 + tid;          // 512 short8-chunks
    int row = c >> 5, cb = (c & 31) * 8;
    size_t g = base + (size_t)row*256 + cb;
    *(uint4*)&Qs[row*264 + cb] = *(const uint4*)(Qg + g);
    *(uint4*)&Ks[row*264 + cb] = *(const uint4*)(Kg + g);
    *(uint4*)&Vs[row*264 + cb] = *(const uint4*)(Vg + g);
  }
  __syncthreads();

  // ---- scores + in-register softmax: thread < 128 owns (win,h,qi) ----
  const float scale = 0.17677669529663687f; // 1/sqrt(32)
  if (tid < 128){
    int win = tid >> 6, h = (tid >> 3) & 7, qi = tid & 7;
    int qrow = win*8 + qi;
    short8 qv[4];
    #pragma unroll
    for (int j = 0; j < 4; j++)
      qv[j] = *(const short8*)&Qs[qrow*264 + h*32 + j*8];
    float s[8];
    #pragma unroll
    for (int k = 0; k < 8; k++){
      int krow = win*8 + k;
      float a = 0.f;
      #pragma unroll
      for (int j = 0; j < 4; j++){
        short8 kv = *(const short8*)&Ks[krow*264 + h*32 + j*8];
        #pragma unroll
        for (int e = 0; e < 8; e++)
          a += bfu((unsigned short)qv[j][e]) * bfu((unsigned short)kv[e]);
      }
      s[k] = a * scale;
    }
    float mx = s[0];
    #pragma unroll
    for (int k = 1; k < 8; k++) mx = fmaxf(mx, s[k]);
    float sum = 0.f;
    #pragma unroll
    for (int k = 0; k < 8; k++){ s[k] = __expf(s[k] - mx); sum += s[k]; }
    float inv = 1.f / sum;
    #pragma unroll
    for (int k = 0; k < 8; k++)
      sc[((win*8 + qi)*8 + h)*8 + k] = s[k] * inv;
  }
  __syncthreads();

  // ---- PV: thread = column c; O -> Qs (dead after score phase) ----
  {
    const int c = tid, h = c >> 5;
    #pragma unroll
    for (int j = 0; j < 16; j++){
      int win = j >> 3, qi = j & 7;
      const float* pr = &sc[((win*8 + qi)*8 + h)*8];
      float o = 0.f;
      #pragma unroll
      for (int k = 0; k < 8; k++)
        o += pr[k] * bfu((unsigned short)Vs[(win*8 + k)*264 + c]);
      Qs[j*264 + c] = bfbits(o);
    }
  }
  __syncthreads();

  // ---- coalesced store-back ----
  #pragma unroll
  for (int it = 0; it < 2; it++){
    int c = it*256 + tid;
    int row = c >> 5, cb = (c & 31) * 8;
    *(uint4*)(Qg + base + (size_t)row*256 + cb) = *(uint4*)&Qs[row*264 + cb];
  }
}

// ---- alpha head with fused ln_f (raw sums): one wave per token ------------
__global__ __launch_bounds__(256) void alpha_kernel(
    const bf16* __restrict__ X, const float* __restrict__ s1,
    const float* __restrict__ s2, const float* __restrict__ s,
    const float* __restrict__ b, const float* __restrict__ wa,
    const float* __restrict__ ba, float* __restrict__ out)
{
  int lane = threadIdx.x & 63, w = threadIdx.x >> 6;
  size_t t = (size_t)blockIdx.x * 4 + w;
  float m = s1[t] * (1.f/256.f);
  float q = s2[t] * (1.f/256.f);
  float r = rsqrtf(q - m*m + 1e-6f);
  float acc = 0.f;
  #pragma unroll
  for (int j = 0; j < 4; j++){
    int c = lane + 64*j;
    float y = (cvt(X[t*DMODEL + c]) - m) * r * s[c] + b[c];
    acc += y * wa[c];
  }
  #pragma unroll
  for (int off = 32; off; off >>= 1) acc += __shfl_down(acc, off, 64);
  if (lane == 0) out[t] = acc + ba[0];
}

// ---- rgb2: t1 stored with ld=256 (cols 0..127), @ (128,3) + b (f32 out) ---
__global__ __launch_bounds__(256) void rgb2_kernel(
    const bf16* __restrict__ T1, const float* __restrict__ w2,
    const float* __restrict__ b2, float* __restrict__ out)
{
  int lane = threadIdx.x & 63, w = threadIdx.x >> 6;
  size_t t = (size_t)blockIdx.x * 4 + w;
  float h0 = cvt(T1[t*256 + lane]);
  float h1 = cvt(T1[t*256 + 64 + lane]);
  float a0 = h0*w2[lane*3+0] + h1*w2[(lane+64)*3+0];
  float a1 = h0*w2[lane*3+1] + h1*w2[(lane+64)*3+1];
  float a2 = h0*w2[lane*3+2] + h1*w2[(lane+64)*3+2];
  #pragma unroll
  for (int off = 32; off; off >>= 1){
    a0 += __shfl_down(a0, off, 64);
    a1 += __shfl_down(a1, off, 64);
    a2 += __shfl_down(a2, off, 64);
  }
  if (lane == 0){
    out[t*3+0] = a0 + b2[0];
    out[t*3+1] = a1 + b2[1];
    out[t*3+2] = a2 + b2[2];
  }
}

extern "C" void kernel_launch(void* const* d_in, const int* in_sizes, int n_in,
                              void* d_out, int out_size, void* d_ws, size_t ws_size,
                              hipStream_t stream)
{
  (void)in_sizes; (void)n_in; (void)out_size;
  const float* pts     = (const float*)d_in[0];
  const float* views   = (const float*)d_in[1];
  const float* w_in    = (const float*)d_in[2];
  const float* b_in    = (const float*)d_in[3];
  const float* ln_in_s = (const float*)d_in[4];
  const float* ln_in_b = (const float*)d_in[5];
  const float* ln1_s   = (const float*)d_in[6];
  const float* ln1_b   = (const float*)d_in[7];
  const float* wq      = (const float*)d_in[8];
  const float* bq      = (const float*)d_in[9];
  const float* wk      = (const float*)d_in[10];
  const float* bk      = (const float*)d_in[11];
  const float* wv      = (const float*)d_in[12];
  const float* bv      = (const float*)d_in[13];
  const float* wo      = (const float*)d_in[14];
  const float* bo      = (const float*)d_in[15];
  const float* ln2_s   = (const float*)d_in[16];
  const float* ln2_b   = (const float*)d_in[17];
  const float* w_mlp1  = (const float*)d_in[18];
  const float* b_mlp1  = (const float*)d_in[19];
  const float* w_mlp2  = (const float*)d_in[20];
  const float* b_mlp2  = (const float*)d_in[21];
  const float* w_skip  = (const float*)d_in[22];
  const float* b_skip  = (const float*)d_in[23];
  const float* ln_f_s  = (const float*)d_in[24];
  const float* ln_f_b  = (const float*)d_in[25];
  const float* w_alpha = (const float*)d_in[26];
  const float* b_alpha = (const float*)d_in[27];
  const float* w_feat  = (const float*)d_in[28];
  const float* b_feat  = (const float*)d_in[29];
  const float* w_rgb1  = (const float*)d_in[30];
  const float* b_rgb1  = (const float*)d_in[31];
  const float* w_rgb2  = (const float*)d_in[32];
  const float* b_rgb2  = (const float*)d_in[33];

  const size_t SZ = (size_t)T_TOK * DMODEL * 2;        // 100,663,296 B
  const size_t WT_ELEMS = 16384 + 2*(196608 + 3*65536 + 81920) + 65536 + 36864;
  const size_t UV_FLOATS = 2*768*2 + 2*256*2 + 2*256;  // u/wB buffers = 4608
  const size_t NEED = 2*SZ + (size_t)4*T_TOK*4 + NSEQ*DMODEL*4 + UV_FLOATS*4
                    + WT_ELEMS*2 + (size_t)T_TOK*64*2 + 1024*32*2;
  if (ws_size < NEED) return;

  char* wsp = (char*)d_ws;
  bf16* xr = (bf16*)(wsp);
  bf16* x2 = (bf16*)(wsp + SZ);
  float* s1A = (float*)(wsp + 2*SZ);
  float* s2A = s1A + T_TOK;
  float* s1B = s2A + T_TOK;
  float* s2B = s1B + T_TOK;
  float* PE  = s2B + T_TOK;                  // 192*256 floats
  float* uvp = PE + NSEQ*DMODEL;
  float* uqkv[2], *wBqkv[2], *um1[2], *wBm1[2];
  {
    float* q = uvp;
    for (int i = 0; i < 2; i++){ uqkv[i] = q; q += 768; }
    for (int i = 0; i < 2; i++){ wBqkv[i] = q; q += 768; }
    for (int i = 0; i < 2; i++){ um1[i] = q; q += 256; }
    for (int i = 0; i < 2; i++){ wBm1[i] = q; q += 256; }
  }
  float* ufeat  = uvp + 2*768*2 + 2*256*2;
  float* wBfeat = ufeat + 256;
  bf16* wtp = (bf16*)(uvp + UV_FLOATS);

  bf16* wt_in = wtp;                         // 256 x 64
  bf16* wt_qkv[2], *wt_o[2], *wt_m1[2], *wt_m2[2], *wt_sk[2];
  bf16* p = wt_in + 16384;
  for (int i = 0; i < 2; i++){
    wt_qkv[i] = p; p += 196608;              // 768 x 256
    wt_o[i]   = p; p += 65536;
    wt_m1[i]  = p; p += 65536;
    wt_m2[i]  = p; p += 65536;
    wt_sk[i]  = p; p += 81920;               // 256 x 320
  }
  bf16* wt_feat = p; p += 65536;
  bf16* wt_rgb1 = p; p += 36864;             // 128 x 288
  bf16* pts_b   = p; p += (size_t)T_TOK*64;  // T x 64
  bf16* views_b = p; p += 1024*32;

  float* out_rgb   = (float*)d_out;
  float* out_alpha = out_rgb + (size_t)T_TOK * 3;

  dim3 blk(256);
  dim3 g256(2, T_TOK/128);       // full-T, Nc=256
  dim3 gQKV(6, CHUNKM/128);      // chunk, Nc=768
  dim3 gC(2, CHUNKM/128);        // chunk, Nc=256
  dim3 g128(1, T_TOK/128);       // full-T, Nc=128
  dim3 gLN(T_TOK/4);             // wave-per-token LN+PE
  dim3 gMLP(T_TOK/64);           // fused MLP, 64-row tiles
  dim3 gStat(T_TOK/4);
  dim3 gAttn(CHUNKM/16);         // 16 tokens (2 windows) per block

  const float* NF = nullptr;
  const bf16*  NB = nullptr;
  float* NFW = nullptr;

  // ---- setup: PE table, pre-convert inputs & weights to bf16, u/wB ----
  pe_kernel<<<dim3(NSEQ), blk, 0, stream>>>(PE);
  pts2b_kernel<<<dim3(T_TOK*64/256), blk, 0, stream>>>(pts, pts_b);
  views2b_kernel<<<dim3(1024*32/256), blk, 0, stream>>>(views, views_b);
  #define W2B(src, dst, K_, N_, KL_, ST_, KO_, SC_) \
    w2b_kernel<<<dim3(((N_)*(KL_)+255)/256), blk, 0, stream>>>(src, dst, K_, N_, KL_, ST_, KO_, SC_)
  W2B(w_in, wt_in, 63, 256, 64, 64, 0, NF);
  for (int i = 0; i < 2; i++){
    const float* s1 = ln1_s + i*256;
    const float* b1 = ln1_b + i*256;
    W2B(wq + (size_t)i*65536, wt_qkv[i],            256, 256, 256, 256, 0, s1);
    W2B(wk + (size_t)i*65536, wt_qkv[i] + 65536,    256, 256, 256, 256, 0, s1);
    W2B(wv + (size_t)i*65536, wt_qkv[i] + 131072,   256, 256, 256, 256, 0, s1);
    ucalc_kernel<<<dim3(256), blk, 0, stream>>>(wq + (size_t)i*65536, s1, b1,
        bq + i*256, uqkv[i],       wBqkv[i],       256, 256);
    ucalc_kernel<<<dim3(256), blk, 0, stream>>>(wk + (size_t)i*65536, s1, b1,
        bk + i*256, uqkv[i] + 256, wBqkv[i] + 256, 256, 256);
    ucalc_kernel<<<dim3(256), blk, 0, stream>>>(wv + (size_t)i*65536, s1, b1,
        bv + i*256, uqkv[i] + 512, wBqkv[i] + 512, 256, 256);
    W2B(wo + (size_t)i*65536, wt_o[i],  256, 256, 256, 256, 0, NF);
    W2B(w_mlp1 + (size_t)i*65536, wt_m1[i], 256, 256, 256, 256, 0, ln2_s + i*256);
    ucalc_kernel<<<dim3(256), blk, 0, stream>>>(w_mlp1 + (size_t)i*65536,
        ln2_s + i*256, ln2_b + i*256, b_mlp1 + i*256, um1[i], wBm1[i], 256, 256);
    W2B(w_mlp2 + (size_t)i*65536, wt_m2[i], 256, 256, 256, 256, 0, NF);
    W2B(w_skip + (size_t)i*81664,            wt_sk[i], 63, 256, 64, 320, 0, NF);
    W2B(w_skip + (size_t)i*81664 + 63*256,   wt_sk[i], 256, 256, 256, 320, 64, NF);
  }
  W2B(w_feat, wt_feat, 256, 256, 256, 256, 0, ln_f_s);
  ucalc_kernel<<<dim3(256), blk, 0, stream>>>(w_feat, ln_f_s, ln_f_b, b_feat,
      ufeat, wBfeat, 256, 256);
  W2B(w_rgb1,                wt_rgb1, 256, 128, 256, 288, 0, NF);
  W2B(w_rgb1 + 256*128,      wt_rgb1, 27, 128, 32, 288, 256, NF);
  #undef W2B

  // x = pts @ w_in + b_in -> xr ; x = ln(x) + pe (in place, stats -> A)
  gemm_mfma<0,false,false,false,false><<<g256, blk, 0, stream>>>(pts_b, 64,
      NB, 0, 0, 0, NF, NF, NF, wt_in, 64, b_in,
      xr, 256, 0, 0, 0, NFW, NFW);
  ln_pe_kernel<<<gLN, blk, 0, stream>>>(xr, ln_in_s, ln_in_b, PE, s1A, s2A);

  for (int i = 0; i < 2; i++){
    const int shift = (i == 1) ? 4 : 0;
    const int shiftBack = (i == 1) ? (NSEQ - 4) : 0;

    // zero ln2-stats accumulators
    hipMemsetAsync(s1B, 0, (size_t)2*T_TOK*4, stream);

    // attention, chunked: Q/K/V buffers live inside x2 (3 x 24 MB)
    bf16* qb = x2;
    bf16* kb = x2 + (size_t)CHUNKM * 256;
    bf16* vb = x2 + (size_t)2 * CHUNKM * 256;
    for (int cch = 0; cch < CHUNKS; cch++){
      int base = cch * CHUNKM;
      // fused q|k|v = ln1(roll(x_chunk)) @ wqkv' + wB  (LN folded)
      gemm_mfma<0,true,false,false,false><<<gQKV, blk, 0, stream>>>(xr, 256,
          NB, 0, 0, base, s1A, s2A, uqkv[i], wt_qkv[i], 256, wBqkv[i],
          x2, 256, (size_t)CHUNKM*256, 0, shift, NFW, NFW);
      attn_lite<<<gAttn, blk, 0, stream>>>(qb, kb, vb);
      // x_chunk += roll_back(O) @ wo + bo   (stats -> B)
      gemm_mfma<0,false,true,false,true><<<gC, blk, 0, stream>>>(qb, 256,
          NB, 0, 0, 0, NF, NF, NF, wt_o[i], 256, bo + i*256,
          xr, 256, 0, base, shiftBack, s1B, s2B);
    }

    // FUSED mlp (ln2 folded, stats B): xr += gelu(ln2(xr)@W1+b1)@W2 + b2
    mlp_fused<<<gMLP, blk, 0, stream>>>(xr, s1B, s2B, um1[i],
        wt_m1[i], wBm1[i], wt_m2[i], b_mlp2 + i*256, xr);

    // x = gelu(concat(pts, x) @ w_skip + b_skip) -> x2 (stats -> A), swap
    hipMemsetAsync(s1A, 0, (size_t)2*T_TOK*4, stream);
    gemm_mfma<2,false,false,true,true><<<g256, blk, 0, stream>>>(pts_b, 64,
        xr, 256, 64, 0, NF, NF, NF, wt_sk[i], 320, b_skip + i*256,
        x2, 256, 0, 0, 0, s1A, s2A);
    bf16* tmp = xr; xr = x2; x2 = tmp;
  }

  // head (ln_f from stats A)
  alpha_kernel<<<gStat, blk, 0, stream>>>(xr, s1A, s2A, ln_f_s, ln_f_b,
      w_alpha, b_alpha, out_alpha);
  // feature = ln_f(x) @ w_feat + b_feat -> x2  (LN folded)
  gemm_mfma<0,true,false,false,false><<<g256, blk, 0, stream>>>(xr, 256,
      NB, 0, 0, 0, s1A, s2A, ufeat, wt_feat, 256, wBfeat,
      x2, 256, 0, 0, 0, NFW, NFW);
  // t1 = gelu(concat(feature, views) @ w_rgb1 + b_rgb1) -> xr cols 0..127
  gemm_mfma<3,false,false,true,false><<<g128, blk, 0, stream>>>(x2, 256,
      views_b, 32, 256, 0, NF, NF, NF, wt_rgb1, 288, b_rgb1,
      xr, 256, 0, 0, 0, NFW, NFW);
  rgb2_kernel<<<gStat, blk, 0, stream>>>(xr, w_rgb2, b_rgb2, out_rgb);
}

// Round 15
// 1867.960 us; speedup vs baseline: 1.5575x; 1.0201x over previous
//
#include <hip/hip_runtime.h>
#include <hip/hip_bf16.h>
#include <math.h>

typedef __hip_bfloat16 bf16;
typedef __attribute__((ext_vector_type(8))) short short8;
typedef __attribute__((ext_vector_type(4))) float f32x4;

#define T_TOK 196608   // B*N = 1024*192
#define NSEQ  192
#define DMODEL 256
#define CHUNKS 4
#define CHUNKM (T_TOK/CHUNKS)   // 49152 tokens = 256 sequences

__device__ __forceinline__ float cvt(float v){ return v; }
__device__ __forceinline__ float cvt(bf16 v){ return __bfloat162float(v); }
__device__ __forceinline__ short bfbits(float f){
  bf16 h = __float2bfloat16(f); return *reinterpret_cast<short*>(&h);
}
__device__ __forceinline__ float bfu(unsigned short v){ return __uint_as_float(((unsigned)v) << 16); }

// gelu(tanh approx) == x * sigmoid(2u), u = k0(x+0.044715x^3).
__device__ __forceinline__ float gelu_f(float x){
  const float k0 = 0.7978845608028654f; // sqrt(2/pi)
  float u = k0*(x + 0.044715f*x*x*x);
  return x / (1.f + __expf(-2.f*u));
}

// lgkm-only barrier: ds ops drained, global loads stay IN FLIGHT across it.
__device__ __forceinline__ void barrier_lgkm(){
  asm volatile("s_waitcnt lgkmcnt(0)" ::: "memory");
  __builtin_amdgcn_s_barrier();
  asm volatile("" ::: "memory");
}

// ---- pos-embed table: PE[n][d], n<192 ------------------------------------
__global__ __launch_bounds__(256) void pe_kernel(float* __restrict__ PE){
  int n = blockIdx.x, d = threadIdx.x;
  float e = (float)(2*(d>>1)) / 256.f;
  float ang = (float)n * powf(10000.f, -e);
  PE[n*DMODEL + d] = (d & 1) ? cosf(ang) : sinf(ang);
}

// ---- weight convert+transpose into segment: dst[n*dstStride+kOff+k] ------
__global__ __launch_bounds__(256) void w2b_kernel(
    const float* __restrict__ src, bf16* __restrict__ dst,
    int K, int N, int KL, int dstStride, int kOff, const float* __restrict__ scale)
{
  int idx = blockIdx.x*256 + threadIdx.x;
  if (idx >= N*KL) return;
  int n = idx / KL, k = idx - n*KL;
  float v = 0.f;
  if (k < K){
    v = src[(size_t)k*N + n];
    if (scale) v *= scale[k];
  }
  dst[(size_t)n*dstStride + kOff + k] = __float2bfloat16(v);
}

// ---- u[n] = sum_k bf16(lnS[k]*W[k,n]);  wB[n] = sum_k lnB[k]*W[k,n]+bias[n]
__global__ __launch_bounds__(256) void ucalc_kernel(
    const float* __restrict__ W, const float* __restrict__ lnS,
    const float* __restrict__ lnB, const float* __restrict__ bias,
    float* __restrict__ u, float* __restrict__ wB, int K, int N)
{
  __shared__ float pu[4], pb[4];
  const int n = blockIdx.x;
  const int k = threadIdx.x;
  float su = 0.f, sb = 0.f;
  if (k < K){
    float w = W[(size_t)k*N + n];
    su = cvt(__float2bfloat16(lnS[k]*w));   // match MFMA's rounded W'
    sb = lnB[k]*w;
  }
  #pragma unroll
  for (int off = 32; off; off >>= 1){
    su += __shfl_xor(su, off, 64);
    sb += __shfl_xor(sb, off, 64);
  }
  int lane = k & 63, wv = k >> 6;
  if (lane == 0){ pu[wv] = su; pb[wv] = sb; }
  __syncthreads();
  if (k == 0){
    u[n]  = pu[0]+pu[1]+pu[2]+pu[3];
    wB[n] = pb[0]+pb[1]+pb[2]+pb[3] + bias[n];
  }
}

// ---- pts -> bf16 [T][64] zero-padded --------------------------------------
__global__ __launch_bounds__(256) void pts2b_kernel(
    const float* __restrict__ src, bf16* __restrict__ dst)
{
  int idx = blockIdx.x*256 + threadIdx.x;   // T*64
  int t = idx >> 6, k = idx & 63;
  dst[idx] = __float2bfloat16(k < 63 ? src[(size_t)t*63 + k] : 0.f);
}

// ---- views -> bf16 [1024][32] zero-padded ---------------------------------
__global__ __launch_bounds__(256) void views2b_kernel(
    const float* __restrict__ src, bf16* __restrict__ dst)
{
  int idx = blockIdx.x*256 + threadIdx.x;   // 1024*32
  int t = idx >> 5, k = idx & 31;
  dst[idx] = __float2bfloat16(k < 27 ? src[(size_t)t*27 + k] : 0.f);
}

// ---- wave-per-token: x = ln(x)*s+b + PE[n]; writes raw stats (s1=Σy,s2=Σy²)
__global__ __launch_bounds__(256) void ln_pe_kernel(
    bf16* __restrict__ X, const float* __restrict__ s, const float* __restrict__ b,
    const float* __restrict__ PE, float* __restrict__ s1o, float* __restrict__ s2o)
{
  const int lane = threadIdx.x & 63, w = threadIdx.x >> 6;
  const size_t t = (size_t)blockIdx.x * 4 + w;
  const int n = (int)(t % NSEQ);
  const int c = lane * 4;

  ushort4 u = *reinterpret_cast<const ushort4*>(X + t*DMODEL + c);
  float x0 = bfu(u.x), x1 = bfu(u.y), x2 = bfu(u.z), x3 = bfu(u.w);

  float sx = x0 + x1 + x2 + x3;
  float sq = x0*x0 + x1*x1 + x2*x2 + x3*x3;
  #pragma unroll
  for (int off = 32; off; off >>= 1){
    sx += __shfl_xor(sx, off, 64);
    sq += __shfl_xor(sq, off, 64);
  }
  float mean = sx * (1.f/256.f);
  float var  = sq * (1.f/256.f) - mean*mean;
  float rstd = rsqrtf(var + 1e-6f);

  float4 sv = *reinterpret_cast<const float4*>(s + c);
  float4 bv = *reinterpret_cast<const float4*>(b + c);
  float4 pv = *reinterpret_cast<const float4*>(PE + n*DMODEL + c);

  float y0 = (x0 - mean)*rstd*sv.x + bv.x + pv.x;
  float y1 = (x1 - mean)*rstd*sv.y + bv.y + pv.y;
  float y2 = (x2 - mean)*rstd*sv.z + bv.z + pv.z;
  float y3 = (x3 - mean)*rstd*sv.w + bv.w + pv.w;

  ushort4 o;
  o.x = (unsigned short)bfbits(y0);
  o.y = (unsigned short)bfbits(y1);
  o.z = (unsigned short)bfbits(y2);
  o.w = (unsigned short)bfbits(y3);
  *reinterpret_cast<ushort4*>(X + t*DMODEL + c) = o;

  float sy  = y0 + y1 + y2 + y3;
  float syq = y0*y0 + y1*y1 + y2*y2 + y3*y3;
  #pragma unroll
  for (int off = 32; off; off >>= 1){
    sy  += __shfl_xor(sy,  off, 64);
    syq += __shfl_xor(syq, off, 64);
  }
  if (lane == 0){ s1o[t] = sy; s2o[t] = syq; }
}

// ---- MFMA GEMM: C = A @ W, 128x128 tile, 4 waves (R8 = verified optimum) --
// See journal in earlier rounds: VGPR budget is the binding constraint.
template<int MODE, bool LNF, bool ADD, bool GELU, bool STATS>
__global__ __launch_bounds__(256) void gemm_mfma(
    const bf16* __restrict__ A1, int lda1,
    const bf16* __restrict__ A2, int lda2, int SB, int aOff,
    const float* __restrict__ s1i, const float* __restrict__ s2i,
    const float* __restrict__ uvec,
    const bf16* __restrict__ WT, int Kpad, const float* __restrict__ bias,
    bf16* __restrict__ C, int ldc, size_t segStride, int cOff, int rollShift,
    float* __restrict__ s1o, float* __restrict__ s2o)
{
  __shared__ short buf[17408];    // As0|As1 (2x5120) ∪ Cs (17408) = 34816 B
  short* As0 = buf;
  short* As1 = buf + 5120;
  short* Cs  = buf;
  __shared__ float sScale[128], sAlpha[128];

  const int tid = threadIdx.x;
  const int lane = tid & 63, wid = tid >> 6;
  const int wm = wid >> 1, wn = wid & 1;
  const int col16 = lane & 15, quad = lane >> 4;
  const int sm = tid >> 1, half = tid & 1;   // staging: row, k-half
  const int m0 = blockIdx.y * 128, n0 = blockIdx.x * 128;

  f32x4 acc[4][4];
  #pragma unroll
  for (int i = 0; i < 4; i++)
    #pragma unroll
    for (int j = 0; j < 4; j++) acc[i][j] = (f32x4){0.f,0.f,0.f,0.f};

  // staging source row (rolled)
  int row = m0 + sm;
  if (MODE == 0 && rollShift){
    int bb = row / NSEQ;
    int n  = row - bb*NSEQ;
    n += rollShift; if (n >= NSEQ) n -= NSEQ;
    row = bb*NSEQ + n;
  }
  const size_t arow = (size_t)aOff + row;
  const size_t arow2 = (MODE == 3) ? (arow / NSEQ) : arow;

  // ---- LN-fold per-row scale/alpha (from rolled source row) ----
  if (LNF && tid < 128){
    int r2 = m0 + tid;
    if (rollShift){
      int bb = r2 / NSEQ, n = r2 - bb*NSEQ;
      n += rollShift; if (n >= NSEQ) n -= NSEQ;
      r2 = bb*NSEQ + n;
    }
    size_t r = (size_t)aOff + r2;
    float m1 = s1i[r] * (1.f/256.f);
    float m2 = s2i[r] * (1.f/256.f);
    float rs = rsqrtf(m2 - m1*m1 + 1e-6f);
    sScale[tid] = rs;
    sAlpha[tid] = -m1*rs;
  }

  auto loadA = [&](int k0, uint4& u0, uint4& u1){
    const int gk = k0 + half*16;
    const bf16* src;
    if (MODE == 0) src = A1 + arow*(size_t)lda1 + gk;
    else src = (gk < SB) ? (A1 + arow*(size_t)lda1 + gk)
                         : (A2 + arow2*(size_t)lda2 + (gk - SB));
    u0 = *(const uint4*)(src);
    u1 = *(const uint4*)(src + 8);
  };
  auto writeA = [&](short* dst, const uint4& u0, const uint4& u1){
    *(uint4*)&dst[sm*40 + half*16]     = u0;
    *(uint4*)&dst[sm*40 + half*16 + 8] = u1;
  };

  // ---- prologue: tile 0 -> As0, tile 1 issued ----
  uint4 p0, p1;
  loadA(0, p0, p1);
  writeA(As0, p0, p1);
  if (Kpad > 32) loadA(32, p0, p1);
  barrier_lgkm();

  // ---- pipelined K-loop: ONE lgkm barrier per step ----
  int cur = 0;
  for (int k0 = 0; k0 < Kpad; k0 += 32){
    const short* Asc = cur ? As1 : As0;
    short8 afr[4];
    #pragma unroll
    for (int mi = 0; mi < 4; mi++)
      afr[mi] = *(const short8*)&Asc[(wm*64 + mi*16 + col16)*40 + quad*8];
    short8 bfr[4];
    #pragma unroll
    for (int ni = 0; ni < 4; ni++)
      bfr[ni] = *(const short8*)((const short*)WT
                 + (size_t)(n0 + wn*64 + ni*16 + col16)*Kpad + k0 + quad*8);
    #pragma unroll
    for (int mi = 0; mi < 4; mi++)
      #pragma unroll
      for (int ni = 0; ni < 4; ni++)
        acc[mi][ni] = __builtin_amdgcn_mfma_f32_16x16x32_bf16(
            afr[mi], bfr[ni], acc[mi][ni], 0, 0, 0);
    if (k0 + 32 < Kpad){
      short* Asn = cur ? As0 : As1;
      writeA(Asn, p0, p1);                    // waits vmcnt for tile t+1 only
      if (k0 + 64 < Kpad) loadA(k0+64, p0, p1);  // issue tile t+2
    }
    barrier_lgkm();
    cur ^= 1;
  }

  // ---- epilogue phase 1: acc -> affine/bias (+gelu) -> Cs bf16 ----
  #pragma unroll
  for (int ni = 0; ni < 4; ni++){
    int ncol = wn*64 + ni*16 + col16;
    float bv = bias[n0 + ncol];
    float uv = LNF ? uvec[n0 + ncol] : 0.f;
    #pragma unroll
    for (int mi = 0; mi < 4; mi++){
      f32x4 a = acc[mi][ni];
      #pragma unroll
      for (int r = 0; r < 4; r++){
        int lrow = wm*64 + mi*16 + quad*4 + r;
        float val;
        if (LNF) val = sScale[lrow]*a[r] + sAlpha[lrow]*uv + bv;
        else     val = a[r] + bv;
        if (GELU) val = gelu_f(val);
        Cs[lrow*136 + ncol] = bfbits(val);
      }
    }
  }
  __syncthreads();

  // ---- epilogue phase 2: coalesced 16B stores (+ADD) (+STATS) ----
  const int seg = n0 >> 8;
  const int nb  = n0 & 255;
  const int orow = tid >> 4;         // 0..15
  const int ocol = (tid & 15) * 8;   // 0..120
  #pragma unroll
  for (int p = 0; p < 8; p++){
    int lrow = p*16 + orow;
    size_t mrow = (size_t)cOff + m0 + lrow;
    short8 v = *(const short8*)&Cs[lrow*136 + ocol];
    bf16* dst = C + (size_t)seg*segStride + mrow*ldc + nb + ocol;
    float rowSum = 0.f, rowSq = 0.f;
    if (ADD){
      short8 c = *(const short8*)dst;
      short8 o;
      #pragma unroll
      for (int e = 0; e < 8; e++){
        bf16 va, ca;
        *reinterpret_cast<short*>(&va) = v[e];
        *reinterpret_cast<short*>(&ca) = c[e];
        float f = cvt(va) + cvt(ca);
        o[e] = bfbits(f);
        if (STATS){ rowSum += f; rowSq += f*f; }
      }
      *(short8*)dst = o;
    } else {
      if (STATS){
        #pragma unroll
        for (int e = 0; e < 8; e++){
          bf16 va; *reinterpret_cast<short*>(&va) = v[e];
          float f = cvt(va);
          rowSum += f; rowSq += f*f;
        }
      }
      *(short8*)dst = v;
    }
    if (STATS){
      #pragma unroll
      for (int mk = 1; mk <= 8; mk <<= 1){
        rowSum += __shfl_xor(rowSum, mk, 64);
        rowSq  += __shfl_xor(rowSq,  mk, 64);
      }
      if ((tid & 15) == 0){
        atomicAdd(&s1o[mrow], rowSum);
        atomicAdd(&s2o[mrow], rowSq);
      }
    }
  }
}

// ---- FUSED MLP+SKIP: z = gelu(concat(pts, x+mlp(x)) @ Wsk + bsk) ----------
// Stage 1: t = gelu(ln2(x)@W1'+wB1)  (pipelined, As dbuf unioned in sT)
// Stage 2: y = t@W2 + b2 + x  (residual via coalesced re-read; y -> sT,
//          NEVER written to HBM -- saves the 200 MB xr round-trip the old
//          separate skip pass paid)
// Stage 3: z = gelu(concat(pts,y)@Wsk+bsk), K=320: k<64 A-frags direct from
//          L3-hot pts_b, k>=64 ds_read from sT.  z -> Z (x2) with
//          BLOCK-LOCAL LN stats (block owns all 256 cols -> plain stores,
//          no atomics, no s1A memset).
// LDS 34.3 KB (R13 union discipline).  VGPR gate <= ~120 (R9/R10 journal).
__global__ __launch_bounds__(256) void mlp_skip_fused(
    const bf16* __restrict__ X,          // xr (post-attn)
    const bf16* __restrict__ PTS,        // pts_b [T][64]
    const float* __restrict__ s1i, const float* __restrict__ s2i,
    const float* __restrict__ uvec,      // u (col sums of W1')
    const bf16* __restrict__ W1T,        // [256][256] (n,k), pre-scaled
    const float* __restrict__ wB1,       // lnB.W1 + b1
    const bf16* __restrict__ W2T,        // [256][256] (n,k)
    const float* __restrict__ b2,
    const bf16* __restrict__ WSK,        // [256][320] (n,k)
    const float* __restrict__ bsk,
    bf16* __restrict__ Z,                // x2
    float* __restrict__ s1o, float* __restrict__ s2o)
{
  __shared__ short sT[64*264];    // 33792 B: As dbuf ∪ t ∪ y ∪ Cs
  short* As0 = sT;
  short* As1 = sT + 2560;
  short* Cs  = sT;
  __shared__ float sScale[64], sAlpha[64];

  const int tid = threadIdx.x;
  const int lane = tid & 63, wid = tid >> 6;   // wave = 64-col block
  const int col16 = lane & 15, quad = lane >> 4;
  const int qr = tid >> 2, qc = tid & 3;       // staging: row 0-63, 8-chunk
  const int m0 = blockIdx.x * 64;
  const int orow = tid >> 5;         // store layout: 8 rows/pass
  const int oc   = (tid & 31) * 8;   // 32 threads per row

  // ---- LN-fold per-row factors ----
  if (tid < 64){
    size_t r = (size_t)m0 + tid;
    float m1 = s1i[r] * (1.f/256.f);
    float m2 = s2i[r] * (1.f/256.f);
    float rs = rsqrtf(m2 - m1*m1 + 1e-6f);
    sScale[tid] = rs;
    sAlpha[tid] = -m1*rs;
  }

  const size_t arow = (size_t)m0 + qr;
  auto loadA = [&](int k0, uint4& u){
    u = *(const uint4*)(X + arow*DMODEL + k0 + qc*8);
  };
  auto writeA = [&](short* dst, const uint4& u){
    *(uint4*)&dst[qr*40 + qc*8] = u;
  };

  f32x4 acc[4][4];
  #pragma unroll
  for (int i = 0; i < 4; i++)
    #pragma unroll
    for (int j = 0; j < 4; j++) acc[i][j] = (f32x4){0.f,0.f,0.f,0.f};

  // ---- stage 1: t = LNF(x) @ W1'  (pipelined) ----
  uint4 p;
  loadA(0, p); writeA(As0, p);
  loadA(32, p);
  barrier_lgkm();
  int cur = 0;
  for (int k0 = 0; k0 < 256; k0 += 32){
    const short* Asc = cur ? As1 : As0;
    short8 afr[4];
    #pragma unroll
    for (int mi = 0; mi < 4; mi++)
      afr[mi] = *(const short8*)&Asc[(mi*16 + col16)*40 + quad*8];
    short8 bfr[4];
    #pragma unroll
    for (int ni = 0; ni < 4; ni++)
      bfr[ni] = *(const short8*)((const short*)W1T
                 + (size_t)(wid*64 + ni*16 + col16)*256 + k0 + quad*8);
    #pragma unroll
    for (int mi = 0; mi < 4; mi++)
      #pragma unroll
      for (int ni = 0; ni < 4; ni++)
        acc[mi][ni] = __builtin_amdgcn_mfma_f32_16x16x32_bf16(
            afr[mi], bfr[ni], acc[mi][ni], 0, 0, 0);
    if (k0 + 32 < 256){
      short* Asn = cur ? As0 : As1;
      writeA(Asn, p);
      if (k0 + 64 < 256) loadA(k0 + 64, p);
    }
    barrier_lgkm();
    cur ^= 1;
  }
  // As region dead; safe for all threads to write sT below.

  // ---- affine + gelu -> sT (t) ----
  #pragma unroll
  for (int ni = 0; ni < 4; ni++){
    int ncol = wid*64 + ni*16 + col16;
    float uv = uvec[ncol];
    float bv = wB1[ncol];
    #pragma unroll
    for (int mi = 0; mi < 4; mi++){
      f32x4 a = acc[mi][ni];
      #pragma unroll
      for (int r = 0; r < 4; r++){
        int lrow = mi*16 + quad*4 + r;
        float val = sScale[lrow]*a[r] + sAlpha[lrow]*uv + bv;
        sT[lrow*264 + ncol] = bfbits(gelu_f(val));
      }
    }
  }
  __syncthreads();

  // ---- stage 2: y = t @ W2 (barrier-free; sT read-only) ----
  f32x4 acc2[4][4];
  #pragma unroll
  for (int i = 0; i < 4; i++)
    #pragma unroll
    for (int j = 0; j < 4; j++) acc2[i][j] = (f32x4){0.f,0.f,0.f,0.f};
  for (int k0 = 0; k0 < 256; k0 += 32){
    short8 afr[4];
    #pragma unroll
    for (int mi = 0; mi < 4; mi++)
      afr[mi] = *(const short8*)&sT[(mi*16 + col16)*264 + k0 + quad*8];
    short8 bfr[4];
    #pragma unroll
    for (int ni = 0; ni < 4; ni++)
      bfr[ni] = *(const short8*)((const short*)W2T
                 + (size_t)(wid*64 + ni*16 + col16)*256 + k0 + quad*8);
    #pragma unroll
    for (int mi = 0; mi < 4; mi++)
      #pragma unroll
      for (int ni = 0; ni < 4; ni++)
        acc2[mi][ni] = __builtin_amdgcn_mfma_f32_16x16x32_bf16(
            afr[mi], bfr[ni], acc2[mi][ni], 0, 0, 0);
  }
  __syncthreads();   // t reads done -> sT reusable

  // ---- stage-2 epilogue: (acc2 + b2) -> sT fragment layout ----
  #pragma unroll
  for (int ni = 0; ni < 4; ni++){
    int ncol = wid*64 + ni*16 + col16;
    float bv = b2[ncol];
    #pragma unroll
    for (int mi = 0; mi < 4; mi++){
      f32x4 a = acc2[mi][ni];
      #pragma unroll
      for (int r = 0; r < 4; r++){
        int lrow = mi*16 + quad*4 + r;
        sT[lrow*264 + ncol] = bfbits(a[r] + bv);
      }
    }
  }
  __syncthreads();

  // ---- residual add (coalesced X re-read): y = mlpout + x -> sT ----
  #pragma unroll
  for (int pp = 0; pp < 8; pp++){
    int lrow = pp*8 + orow;
    short8 xv = *(const short8*)(X + ((size_t)m0 + lrow)*DMODEL + oc);
    short8 tv = *(const short8*)&sT[lrow*264 + oc];
    short8 o;
    #pragma unroll
    for (int e = 0; e < 8; e++)
      o[e] = bfbits(bfu((unsigned short)xv[e]) + bfu((unsigned short)tv[e]));
    *(short8*)&sT[lrow*264 + oc] = o;
  }
  __syncthreads();

  // ---- stage 3: z = concat(pts, y) @ Wsk  (K=320) ----
  const bf16* pp4[4];
  #pragma unroll
  for (int mi = 0; mi < 4; mi++)
    pp4[mi] = PTS + (size_t)(m0 + mi*16 + col16)*64 + quad*8;

  f32x4 acc3[4][4];
  #pragma unroll
  for (int i = 0; i < 4; i++)
    #pragma unroll
    for (int j = 0; j < 4; j++) acc3[i][j] = (f32x4){0.f,0.f,0.f,0.f};
  for (int k0 = 0; k0 < 320; k0 += 32){
    short8 afr[4];
    if (k0 < 64){
      #pragma unroll
      for (int mi = 0; mi < 4; mi++)
        afr[mi] = *(const short8*)(pp4[mi] + k0);
    } else {
      #pragma unroll
      for (int mi = 0; mi < 4; mi++)
        afr[mi] = *(const short8*)&sT[(mi*16 + col16)*264 + (k0 - 64) + quad*8];
    }
    short8 bfr[4];
    #pragma unroll
    for (int ni = 0; ni < 4; ni++)
      bfr[ni] = *(const short8*)((const short*)WSK
                 + (size_t)(wid*64 + ni*16 + col16)*320 + k0 + quad*8);
    #pragma unroll
    for (int mi = 0; mi < 4; mi++)
      #pragma unroll
      for (int ni = 0; ni < 4; ni++)
        acc3[mi][ni] = __builtin_amdgcn_mfma_f32_16x16x32_bf16(
            afr[mi], bfr[ni], acc3[mi][ni], 0, 0, 0);
  }
  __syncthreads();   // y reads done -> sT reusable as Cs

  // ---- stage-3 epilogue: gelu(acc3 + bsk) -> Cs ----
  #pragma unroll
  for (int ni = 0; ni < 4; ni++){
    int ncol = wid*64 + ni*16 + col16;
    float bv = bsk[ncol];
    #pragma unroll
    for (int mi = 0; mi < 4; mi++){
      f32x4 a = acc3[mi][ni];
      #pragma unroll
      for (int r = 0; r < 4; r++){
        int lrow = mi*16 + quad*4 + r;
        Cs[lrow*264 + ncol] = bfbits(gelu_f(a[r] + bv));
      }
    }
  }
  __syncthreads();

  // ---- coalesced store + BLOCK-LOCAL stats (32 lanes per row) ----
  #pragma unroll
  for (int pp = 0; pp < 8; pp++){
    int lrow = pp*8 + orow;
    size_t mrow = (size_t)m0 + lrow;
    short8 v = *(const short8*)&Cs[lrow*264 + oc];
    float rowSum = 0.f, rowSq = 0.f;
    #pragma unroll
    for (int e = 0; e < 8; e++){
      float f = bfu((unsigned short)v[e]);
      rowSum += f; rowSq += f*f;
    }
    *(short8*)(Z + mrow*DMODEL + oc) = v;
    #pragma unroll
    for (int mk = 1; mk <= 16; mk <<= 1){
      rowSum += __shfl_xor(rowSum, mk, 64);
      rowSq  += __shfl_xor(rowSq,  mk, 64);
    }
    if ((tid & 31) == 0){
      s1o[mrow] = rowSum;
      s2o[mrow] = rowSq;
    }
  }
}

// ---- windowed attention: 16 tokens (2 windows) per block, vectorized ------
__global__ __launch_bounds__(256) void attn_lite(
    bf16* __restrict__ Qg, const bf16* __restrict__ Kg, const bf16* __restrict__ Vg)
{
  __shared__ short Qs[16*264], Ks[16*264], Vs[16*264];  // 25.3 KB
  __shared__ float sc[2*8*8*8];                         // [win][qi][h][k] 4 KB
  const int tid = threadIdx.x;
  const size_t base = (size_t)blockIdx.x * 16 * 256;

  // ---- load Q,K,V tiles (16x256 bf16), fully coalesced short8 ----
  #pragma unroll
  for (int it = 0; it < 2; it++){
    int c = it*256 + tid;          // 512 short8-chunks
    int row = c >> 5, cb = (c & 31) * 8;
    size_t g = base + (size_t)row*256 + cb;
    *(uint4*)&Qs[row*264 + cb] = *(const uint4*)(Qg + g);
    *(uint4*)&Ks[row*264 + cb] = *(const uint4*)(Kg + g);
    *(uint4*)&Vs[row*264 + cb] = *(const uint4*)(Vg + g);
  }
  __syncthreads();

  // ---- scores + in-register softmax: thread < 128 owns (win,h,qi) ----
  const float scale = 0.17677669529663687f; // 1/sqrt(32)
  if (tid < 128){
    int win = tid >> 6, h = (tid >> 3) & 7, qi = tid & 7;
    int qrow = win*8 + qi;
    short8 qv[4];
    #pragma unroll
    for (int j = 0; j < 4; j++)
      qv[j] = *(const short8*)&Qs[qrow*264 + h*32 + j*8];
    float s[8];
    #pragma unroll
    for (int k = 0; k < 8; k++){
      int krow = win*8 + k;
      float a = 0.f;
      #pragma unroll
      for (int j = 0; j < 4; j++){
        short8 kv = *(const short8*)&Ks[krow*264 + h*32 + j*8];
        #pragma unroll
        for (int e = 0; e < 8; e++)
          a += bfu((unsigned short)qv[j][e]) * bfu((unsigned short)kv[e]);
      }
      s[k] = a * scale;
    }
    float mx = s[0];
    #pragma unroll
    for (int k = 1; k < 8; k++) mx = fmaxf(mx, s[k]);
    float sum = 0.f;
    #pragma unroll
    for (int k = 0; k < 8; k++){ s[k] = __expf(s[k] - mx); sum += s[k]; }
    float inv = 1.f / sum;
    #pragma unroll
    for (int k = 0; k < 8; k++)
      sc[((win*8 + qi)*8 + h)*8 + k] = s[k] * inv;
  }
  __syncthreads();

  // ---- PV: thread = column c; O -> Qs (dead after score phase) ----
  {
    const int c = tid, h = c >> 5;
    #pragma unroll
    for (int j = 0; j < 16; j++){
      int win = j >> 3, qi = j & 7;
      const float* pr = &sc[((win*8 + qi)*8 + h)*8];
      float o = 0.f;
      #pragma unroll
      for (int k = 0; k < 8; k++)
        o += pr[k] * bfu((unsigned short)Vs[(win*8 + k)*264 + c]);
      Qs[j*264 + c] = bfbits(o);
    }
  }
  __syncthreads();

  // ---- coalesced store-back ----
  #pragma unroll
  for (int it = 0; it < 2; it++){
    int c = it*256 + tid;
    int row = c >> 5, cb = (c & 31) * 8;
    *(uint4*)(Qg + base + (size_t)row*256 + cb) = *(uint4*)&Qs[row*264 + cb];
  }
}

// ---- alpha head with fused ln_f (raw sums): one wave per token ------------
__global__ __launch_bounds__(256) void alpha_kernel(
    const bf16* __restrict__ X, const float* __restrict__ s1,
    const float* __restrict__ s2, const float* __restrict__ s,
    const float* __restrict__ b, const float* __restrict__ wa,
    const float* __restrict__ ba, float* __restrict__ out)
{
  int lane = threadIdx.x & 63, w = threadIdx.x >> 6;
  size_t t = (size_t)blockIdx.x * 4 + w;
  float m = s1[t] * (1.f/256.f);
  float q = s2[t] * (1.f/256.f);
  float r = rsqrtf(q - m*m + 1e-6f);
  float acc = 0.f;
  #pragma unroll
  for (int j = 0; j < 4; j++){
    int c = lane + 64*j;
    float y = (cvt(X[t*DMODEL + c]) - m) * r * s[c] + b[c];
    acc += y * wa[c];
  }
  #pragma unroll
  for (int off = 32; off; off >>= 1) acc += __shfl_down(acc, off, 64);
  if (lane == 0) out[t] = acc + ba[0];
}

// ---- rgb2: t1 stored with ld=256 (cols 0..127), @ (128,3) + b (f32 out) ---
__global__ __launch_bounds__(256) void rgb2_kernel(
    const bf16* __restrict__ T1, const float* __restrict__ w2,
    const float* __restrict__ b2, float* __restrict__ out)
{
  int lane = threadIdx.x & 63, w = threadIdx.x >> 6;
  size_t t = (size_t)blockIdx.x * 4 + w;
  float h0 = cvt(T1[t*256 + lane]);
  float h1 = cvt(T1[t*256 + 64 + lane]);
  float a0 = h0*w2[lane*3+0] + h1*w2[(lane+64)*3+0];
  float a1 = h0*w2[lane*3+1] + h1*w2[(lane+64)*3+1];
  float a2 = h0*w2[lane*3+2] + h1*w2[(lane+64)*3+2];
  #pragma unroll
  for (int off = 32; off; off >>= 1){
    a0 += __shfl_down(a0, off, 64);
    a1 += __shfl_down(a1, off, 64);
    a2 += __shfl_down(a2, off, 64);
  }
  if (lane == 0){
    out[t*3+0] = a0 + b2[0];
    out[t*3+1] = a1 + b2[1];
    out[t*3+2] = a2 + b2[2];
  }
}

extern "C" void kernel_launch(void* const* d_in, const int* in_sizes, int n_in,
                              void* d_out, int out_size, void* d_ws, size_t ws_size,
                              hipStream_t stream)
{
  (void)in_sizes; (void)n_in; (void)out_size;
  const float* pts     = (const float*)d_in[0];
  const float* views   = (const float*)d_in[1];
  const float* w_in    = (const float*)d_in[2];
  const float* b_in    = (const float*)d_in[3];
  const float* ln_in_s = (const float*)d_in[4];
  const float* ln_in_b = (const float*)d_in[5];
  const float* ln1_s   = (const float*)d_in[6];
  const float* ln1_b   = (const float*)d_in[7];
  const float* wq      = (const float*)d_in[8];
  const float* bq      = (const float*)d_in[9];
  const float* wk      = (const float*)d_in[10];
  const float* bk      = (const float*)d_in[11];
  const float* wv      = (const float*)d_in[12];
  const float* bv      = (const float*)d_in[13];
  const float* wo      = (const float*)d_in[14];
  const float* bo      = (const float*)d_in[15];
  const float* ln2_s   = (const float*)d_in[16];
  const float* ln2_b   = (const float*)d_in[17];
  const float* w_mlp1  = (const float*)d_in[18];
  const float* b_mlp1  = (const float*)d_in[19];
  const float* w_mlp2  = (const float*)d_in[20];
  const float* b_mlp2  = (const float*)d_in[21];
  const float* w_skip  = (const float*)d_in[22];
  const float* b_skip  = (const float*)d_in[23];
  const float* ln_f_s  = (const float*)d_in[24];
  const float* ln_f_b  = (const float*)d_in[25];
  const float* w_alpha = (const float*)d_in[26];
  const float* b_alpha = (const float*)d_in[27];
  const float* w_feat  = (const float*)d_in[28];
  const float* b_feat  = (const float*)d_in[29];
  const float* w_rgb1  = (const float*)d_in[30];
  const float* b_rgb1  = (const float*)d_in[31];
  const float* w_rgb2  = (const float*)d_in[32];
  const float* b_rgb2  = (const float*)d_in[33];

  const size_t SZ = (size_t)T_TOK * DMODEL * 2;        // 100,663,296 B
  const size_t WT_ELEMS = 16384 + 2*(196608 + 3*65536 + 81920) + 65536 + 36864;
  const size_t UV_FLOATS = 2*768*2 + 2*256*2 + 2*256;  // u/wB buffers = 4608
  const size_t NEED = 2*SZ + (size_t)4*T_TOK*4 + NSEQ*DMODEL*4 + UV_FLOATS*4
                    + WT_ELEMS*2 + (size_t)T_TOK*64*2 + 1024*32*2;
  if (ws_size < NEED) return;

  char* wsp = (char*)d_ws;
  bf16* xr = (bf16*)(wsp);
  bf16* x2 = (bf16*)(wsp + SZ);
  float* s1A = (float*)(wsp + 2*SZ);
  float* s2A = s1A + T_TOK;
  float* s1B = s2A + T_TOK;
  float* s2B = s1B + T_TOK;
  float* PE  = s2B + T_TOK;                  // 192*256 floats
  float* uvp = PE + NSEQ*DMODEL;
  float* uqkv[2], *wBqkv[2], *um1[2], *wBm1[2];
  {
    float* q = uvp;
    for (int i = 0; i < 2; i++){ uqkv[i] = q; q += 768; }
    for (int i = 0; i < 2; i++){ wBqkv[i] = q; q += 768; }
    for (int i = 0; i < 2; i++){ um1[i] = q; q += 256; }
    for (int i = 0; i < 2; i++){ wBm1[i] = q; q += 256; }
  }
  float* ufeat  = uvp + 2*768*2 + 2*256*2;
  float* wBfeat = ufeat + 256;
  bf16* wtp = (bf16*)(uvp + UV_FLOATS);

  bf16* wt_in = wtp;                         // 256 x 64
  bf16* wt_qkv[2], *wt_o[2], *wt_m1[2], *wt_m2[2], *wt_sk[2];
  bf16* p = wt_in + 16384;
  for (int i = 0; i < 2; i++){
    wt_qkv[i] = p; p += 196608;              // 768 x 256
    wt_o[i]   = p; p += 65536;
    wt_m1[i]  = p; p += 65536;
    wt_m2[i]  = p; p += 65536;
    wt_sk[i]  = p; p += 81920;               // 256 x 320
  }
  bf16* wt_feat = p; p += 65536;
  bf16* wt_rgb1 = p; p += 36864;             // 128 x 288
  bf16* pts_b   = p; p += (size_t)T_TOK*64;  // T x 64
  bf16* views_b = p; p += 1024*32;

  float* out_rgb   = (float*)d_out;
  float* out_alpha = out_rgb + (size_t)T_TOK * 3;

  dim3 blk(256);
  dim3 g256(2, T_TOK/128);       // full-T, Nc=256
  dim3 gQKV(6, CHUNKM/128);      // chunk, Nc=768
  dim3 gC(2, CHUNKM/128);        // chunk, Nc=256
  dim3 g128(1, T_TOK/128);       // full-T, Nc=128
  dim3 gLN(T_TOK/4);             // wave-per-token LN+PE
  dim3 gMLP(T_TOK/64);           // fused MLP+skip, 64-row tiles
  dim3 gStat(T_TOK/4);
  dim3 gAttn(CHUNKM/16);         // 16 tokens (2 windows) per block

  const float* NF = nullptr;
  const bf16*  NB = nullptr;
  float* NFW = nullptr;

  // ---- setup: PE table, pre-convert inputs & weights to bf16, u/wB ----
  pe_kernel<<<dim3(NSEQ), blk, 0, stream>>>(PE);
  pts2b_kernel<<<dim3(T_TOK*64/256), blk, 0, stream>>>(pts, pts_b);
  views2b_kernel<<<dim3(1024*32/256), blk, 0, stream>>>(views, views_b);
  #define W2B(src, dst, K_, N_, KL_, ST_, KO_, SC_) \
    w2b_kernel<<<dim3(((N_)*(KL_)+255)/256), blk, 0, stream>>>(src, dst, K_, N_, KL_, ST_, KO_, SC_)
  W2B(w_in, wt_in, 63, 256, 64, 64, 0, NF);
  for (int i = 0; i < 2; i++){
    const float* s1 = ln1_s + i*256;
    const float* b1 = ln1_b + i*256;
    W2B(wq + (size_t)i*65536, wt_qkv[i],            256, 256, 256, 256, 0, s1);
    W2B(wk + (size_t)i*65536, wt_qkv[i] + 65536,    256, 256, 256, 256, 0, s1);
    W2B(wv + (size_t)i*65536, wt_qkv[i] + 131072,   256, 256, 256, 256, 0, s1);
    ucalc_kernel<<<dim3(256), blk, 0, stream>>>(wq + (size_t)i*65536, s1, b1,
        bq + i*256, uqkv[i],       wBqkv[i],       256, 256);
    ucalc_kernel<<<dim3(256), blk, 0, stream>>>(wk + (size_t)i*65536, s1, b1,
        bk + i*256, uqkv[i] + 256, wBqkv[i] + 256, 256, 256);
    ucalc_kernel<<<dim3(256), blk, 0, stream>>>(wv + (size_t)i*65536, s1, b1,
        bv + i*256, uqkv[i] + 512, wBqkv[i] + 512, 256, 256);
    W2B(wo + (size_t)i*65536, wt_o[i],  256, 256, 256, 256, 0, NF);
    W2B(w_mlp1 + (size_t)i*65536, wt_m1[i], 256, 256, 256, 256, 0, ln2_s + i*256);
    ucalc_kernel<<<dim3(256), blk, 0, stream>>>(w_mlp1 + (size_t)i*65536,
        ln2_s + i*256, ln2_b + i*256, b_mlp1 + i*256, um1[i], wBm1[i], 256, 256);
    W2B(w_mlp2 + (size_t)i*65536, wt_m2[i], 256, 256, 256, 256, 0, NF);
    W2B(w_skip + (size_t)i*81664,            wt_sk[i], 63, 256, 64, 320, 0, NF);
    W2B(w_skip + (size_t)i*81664 + 63*256,   wt_sk[i], 256, 256, 256, 320, 64, NF);
  }
  W2B(w_feat, wt_feat, 256, 256, 256, 256, 0, ln_f_s);
  ucalc_kernel<<<dim3(256), blk, 0, stream>>>(w_feat, ln_f_s, ln_f_b, b_feat,
      ufeat, wBfeat, 256, 256);
  W2B(w_rgb1,                wt_rgb1, 256, 128, 256, 288, 0, NF);
  W2B(w_rgb1 + 256*128,      wt_rgb1, 27, 128, 32, 288, 256, NF);
  #undef W2B

  // x = pts @ w_in + b_in -> xr ; x = ln(x) + pe (in place, stats -> A)
  gemm_mfma<0,false,false,false,false><<<g256, blk, 0, stream>>>(pts_b, 64,
      NB, 0, 0, 0, NF, NF, NF, wt_in, 64, b_in,
      xr, 256, 0, 0, 0, NFW, NFW);
  ln_pe_kernel<<<gLN, blk, 0, stream>>>(xr, ln_in_s, ln_in_b, PE, s1A, s2A);

  for (int i = 0; i < 2; i++){
    const int shift = (i == 1) ? 4 : 0;
    const int shiftBack = (i == 1) ? (NSEQ - 4) : 0;

    // zero ln2-stats accumulators (wo STATS still uses atomics)
    hipMemsetAsync(s1B, 0, (size_t)2*T_TOK*4, stream);

    // attention, chunked: Q/K/V buffers live inside x2 (3 x 24 MB)
    bf16* qb = x2;
    bf16* kb = x2 + (size_t)CHUNKM * 256;
    bf16* vb = x2 + (size_t)2 * CHUNKM * 256;
    for (int cch = 0; cch < CHUNKS; cch++){
      int base = cch * CHUNKM;
      // fused q|k|v = ln1(roll(x_chunk)) @ wqkv' + wB  (LN folded)
      gemm_mfma<0,true,false,false,false><<<gQKV, blk, 0, stream>>>(xr, 256,
          NB, 0, 0, base, s1A, s2A, uqkv[i], wt_qkv[i], 256, wBqkv[i],
          x2, 256, (size_t)CHUNKM*256, 0, shift, NFW, NFW);
      attn_lite<<<gAttn, blk, 0, stream>>>(qb, kb, vb);
      // x_chunk += roll_back(O) @ wo + bo   (stats -> B)
      gemm_mfma<0,false,true,false,true><<<gC, blk, 0, stream>>>(qb, 256,
          NB, 0, 0, 0, NF, NF, NF, wt_o[i], 256, bo + i*256,
          xr, 256, 0, base, shiftBack, s1B, s2B);
    }

    // FUSED mlp+skip: x2 = gelu(concat(pts, xr + mlp(xr)) @ wsk + bsk)
    // (ln2 folded via stats B; ln1 stats for next layer -> A, block-local)
    mlp_skip_fused<<<gMLP, blk, 0, stream>>>(xr, pts_b, s1B, s2B, um1[i],
        wt_m1[i], wBm1[i], wt_m2[i], b_mlp2 + i*256,
        wt_sk[i], b_skip + i*256, x2, s1A, s2A);
    bf16* tmp = xr; xr = x2; x2 = tmp;
  }

  // head (ln_f from stats A)
  alpha_kernel<<<gStat, blk, 0, stream>>>(xr, s1A, s2A, ln_f_s, ln_f_b,
      w_alpha, b_alpha, out_alpha);
  // feature = ln_f(x) @ w_feat + b_feat -> x2  (LN folded)
  gemm_mfma<0,true,false,false,false><<<g256, blk, 0, stream>>>(xr, 256,
      NB, 0, 0, 0, s1A, s2A, ufeat, wt_feat, 256, wBfeat,
      x2, 256, 0, 0, 0, NFW, NFW);
  // t1 = gelu(concat(feature, views) @ w_rgb1 + b_rgb1) -> xr cols 0..127
  gemm_mfma<3,false,false,true,false><<<g128, blk, 0, stream>>>(x2, 256,
      views_b, 32, 256, 0, NF, NF, NF, wt_rgb1, 288, b_rgb1,
      xr, 256, 0, 0, 0, NFW, NFW);
  rgb2_kernel<<<gStat, blk, 0, stream>>>(xr, w_rgb2, b_rgb2, out_rgb);
}